// Round 1
// baseline (2276.441 us; speedup 1.0000x reference)
//
#include <hip/hip_runtime.h>
#include <cstdint>
#include <cstddef>

#define NPTS 8192
#define BATCH 16
#define MS 128
#define KNB 64

// ---------------------------------------------------------------- FPS
// One block per batch. Stages pos into 96KB dynamic LDS, then 128 sequential
// farthest-point iterations with wave-butterfly argmax (first-occurrence ties).
__global__ __launch_bounds__(1024) void fps_kernel(const float* __restrict__ pos,
                                                   float* __restrict__ sp) {
#pragma clang fp contract(off)
  extern __shared__ float smem[];
  float* px = smem;
  float* py = smem + NPTS;
  float* pz = smem + 2 * NPTS;
  const int b = blockIdx.x;
  const float* P = pos + (size_t)b * NPTS * 3;
  const int t = threadIdx.x;
  for (int i = t; i < NPTS; i += 1024) {
    px[i] = P[i * 3 + 0];
    py[i] = P[i * 3 + 1];
    pz[i] = P[i * 3 + 2];
  }
  float md[8];
#pragma unroll
  for (int j = 0; j < 8; ++j) md[j] = 1e10f;
  __shared__ int s_last;
  __shared__ float wv[16];
  __shared__ int wi[16];
  if (t == 0) s_last = 0;
  __syncthreads();
  for (int it = 0; it < MS; ++it) {
    const int last = s_last;
    const float lx = px[last], ly = py[last], lz = pz[last];
    if (t == 0) {
      sp[((size_t)b * MS + it) * 3 + 0] = lx;
      sp[((size_t)b * MS + it) * 3 + 1] = ly;
      sp[((size_t)b * MS + it) * 3 + 2] = lz;
    }
    float bv = -1.0f;
    int bi = 0;
#pragma unroll
    for (int j = 0; j < 8; ++j) {
      const int i = j * 1024 + t;
      const float dx = px[i] - lx;
      const float dy = py[i] - ly;
      const float dz = pz[i] - lz;
      const float d = dx * dx + dy * dy + dz * dz;  // contract off: mul,mul,mul,add,add
      float m = md[j];
      m = (d < m) ? d : m;
      md[j] = m;
      if (m > bv) { bv = m; bi = i; }  // ascending i within thread -> first occurrence
    }
    // wave butterfly reduce: max value, tie -> smaller index
    for (int s = 1; s < 64; s <<= 1) {
      const float ov = __shfl_xor(bv, s);
      const int oi = __shfl_xor(bi, s);
      if (ov > bv || (ov == bv && oi < bi)) { bv = ov; bi = oi; }
    }
    if ((t & 63) == 0) { wv[t >> 6] = bv; wi[t >> 6] = bi; }
    __syncthreads();
    if (t == 0) {
      float Bv = wv[0];
      int Bi = wi[0];
      for (int w = 1; w < 16; ++w)
        if (wv[w] > Bv || (wv[w] == Bv && wi[w] < Bi)) { Bv = wv[w]; Bi = wi[w]; }
      s_last = Bi;
    }
    __syncthreads();
  }
}

// ---------------------------------------------------------------- kNN top-64
// One block per (b, sample). sq distances in LDS; 64 rounds of block argmin
// (first-occurrence ties) == lax.top_k set semantics. Emits gf0 tile + sq vals.
__global__ __launch_bounds__(256) void knn_kernel(const float* __restrict__ pos,
                                                  const float* __restrict__ xf,
                                                  const float* __restrict__ sp,
                                                  float* __restrict__ gf0,
                                                  float* __restrict__ sqsel) {
#pragma clang fp contract(off)
  __shared__ float sqv[NPTS];
  __shared__ float wv[4];
  __shared__ int wi[4];
  __shared__ int sel_i[KNB];
  __shared__ float sel_v[KNB];
  const int bm = blockIdx.x;
  const int b = bm >> 7;
  const float* P = pos + (size_t)b * NPTS * 3;
  const float sx = sp[bm * 3 + 0], sy = sp[bm * 3 + 1], sz = sp[bm * 3 + 2];
  const float nsp = sx * sx + sy * sy + sz * sz;
  const int t = threadIdx.x;
  for (int j = 0; j < 32; ++j) {
    const int i = j * 256 + t;
    const float qx = P[i * 3 + 0], qy = P[i * 3 + 1], qz = P[i * 3 + 2];
    const float npos = qx * qx + qy * qy + qz * qz;
    const float dt = sx * qx + sy * qy + sz * qz;
    float sq = (nsp + npos) - 2.0f * dt;  // matches ||a||^2+||b||^2-2ab order
    sq = fmaxf(sq, 0.0f);
    sqv[i] = sq;
  }
  __syncthreads();
  for (int round = 0; round < KNB; ++round) {
    float bv = 3.402823466e+38f;
    int bi = NPTS;
    for (int j = 0; j < 32; ++j) {
      const int i = j * 256 + t;
      const float v = sqv[i];
      if (v < bv) { bv = v; bi = i; }
    }
    for (int s = 1; s < 64; s <<= 1) {
      const float ov = __shfl_xor(bv, s);
      const int oi = __shfl_xor(bi, s);
      if (ov < bv || (ov == bv && oi < bi)) { bv = ov; bi = oi; }
    }
    if ((t & 63) == 0) { wv[t >> 6] = bv; wi[t >> 6] = bi; }
    __syncthreads();
    if (t == 0) {
      float Bv = wv[0];
      int Bi = wi[0];
      for (int w = 1; w < 4; ++w)
        if (wv[w] < Bv || (wv[w] == Bv && wi[w] < Bi)) { Bv = wv[w]; Bi = wi[w]; }
      sel_i[round] = Bi;
      sel_v[round] = Bv;
      sqv[Bi] = 3.402823466e+38f;  // mark consumed
    }
    __syncthreads();
  }
  if (t < KNB) {
    const int i = sel_i[t];
    const float* X = xf + (size_t)b * NPTS * 3;
    const size_t base = ((size_t)bm * KNB + t) * 6;
    gf0[base + 0] = P[i * 3 + 0] - sx;
    gf0[base + 1] = P[i * 3 + 1] - sy;
    gf0[base + 2] = P[i * 3 + 2] - sz;
    gf0[base + 3] = X[i * 3 + 0];
    gf0[base + 4] = X[i * 3 + 1];
    gf0[base + 5] = X[i * 3 + 2];
    sqsel[(size_t)bm * KNB + t] = sel_v[t];
  }
}

// ---------------------------------------------------------------- stage-0 conv chain
// One block per (b, sample) 64x6 tile. Recomputes the conv chain to the target
// depth each pass (BN needs global stats between layers; FLOPs are tiny).
// MODE 1: y1 stats   MODE 2: y2 stats   MODE 3: y3 stats   MODE 4: masked max -> x1
template <int MODE>
__global__ __launch_bounds__(256) void chain_kernel(
    const float* __restrict__ gf0,
    const float* __restrict__ W0, const float* __restrict__ B0,
    const float* __restrict__ W1, const float* __restrict__ B1,
    const float* __restrict__ W2, const float* __restrict__ B2,
    const float* __restrict__ sc1, const float* __restrict__ sh1,
    const float* __restrict__ sc2, const float* __restrict__ sh2,
    const float* __restrict__ sc3, const float* __restrict__ sh3,
    const float* __restrict__ sqsel,
    float* __restrict__ partials, float* __restrict__ x1) {
  __shared__ float tA[64 * 65];  // +1 pad: kills stride-64 bank conflicts on row reads
  __shared__ float tB[64 * 65];
  __shared__ float wbuf[64 * 64];
  __shared__ float in6[64 * 8];
  __shared__ float sqs[64];
  const int blk = blockIdx.x;
  const int t = threadIdx.x;
  {
    const float* G = gf0 + (size_t)blk * 64 * 6;
    for (int i = t; i < 384; i += 256) in6[(i / 6) * 8 + (i % 6)] = G[i];
    for (int i = t; i < 384; i += 256) wbuf[i] = W0[i];
    if (MODE == 4 && t < 64) sqs[t] = sqsel[(size_t)blk * 64 + t];
  }
  __syncthreads();
  const int r = t >> 2;
  const int c0 = (t & 3) * 16;
  float acc[16];
  // L1: 6 -> 64
#pragma unroll
  for (int j = 0; j < 16; ++j) acc[j] = B0[c0 + j];
  for (int cin = 0; cin < 6; ++cin) {
    const float a = in6[r * 8 + cin];
#pragma unroll
    for (int j = 0; j < 16; ++j) acc[j] = fmaf(a, wbuf[cin * 64 + c0 + j], acc[j]);
  }
  if (MODE == 1) {
#pragma unroll
    for (int j = 0; j < 16; ++j) tA[r * 65 + c0 + j] = acc[j];
    __syncthreads();
    if (t < 64) {
      float s = 0.f, q = 0.f;
      for (int r2 = 0; r2 < 64; ++r2) { const float v = tA[r2 * 65 + t]; s += v; q += v * v; }
      partials[((size_t)blk * 64 + t) * 2 + 0] = s;
      partials[((size_t)blk * 64 + t) * 2 + 1] = q;
    }
    return;
  }
#pragma unroll
  for (int j = 0; j < 16; ++j) {
    const int c = c0 + j;
    tA[r * 65 + c] = fmaxf(fmaf(acc[j], sc1[c], sh1[c]), 0.f);
  }
  __syncthreads();
  for (int i = t; i < 4096; i += 256) wbuf[i] = W1[i];
  __syncthreads();
  // L2: 64 -> 64
#pragma unroll
  for (int j = 0; j < 16; ++j) acc[j] = B1[c0 + j];
  for (int cin = 0; cin < 64; ++cin) {
    const float a = tA[r * 65 + cin];
    const float4* w4 = reinterpret_cast<const float4*>(&wbuf[cin * 64 + c0]);
#pragma unroll
    for (int k = 0; k < 4; ++k) {
      const float4 w = w4[k];
      acc[k * 4 + 0] = fmaf(a, w.x, acc[k * 4 + 0]);
      acc[k * 4 + 1] = fmaf(a, w.y, acc[k * 4 + 1]);
      acc[k * 4 + 2] = fmaf(a, w.z, acc[k * 4 + 2]);
      acc[k * 4 + 3] = fmaf(a, w.w, acc[k * 4 + 3]);
    }
  }
  if (MODE == 2) {
#pragma unroll
    for (int j = 0; j < 16; ++j) tB[r * 65 + c0 + j] = acc[j];
    __syncthreads();
    if (t < 64) {
      float s = 0.f, q = 0.f;
      for (int r2 = 0; r2 < 64; ++r2) { const float v = tB[r2 * 65 + t]; s += v; q += v * v; }
      partials[((size_t)blk * 64 + t) * 2 + 0] = s;
      partials[((size_t)blk * 64 + t) * 2 + 1] = q;
    }
    return;
  }
#pragma unroll
  for (int j = 0; j < 16; ++j) {
    const int c = c0 + j;
    tB[r * 65 + c] = fmaxf(fmaf(acc[j], sc2[c], sh2[c]), 0.f);
  }
  // L3: 64 -> 128, processed in channel halves (wbuf holds 64x64 weight half)
  for (int hc = 0; hc < 2; ++hc) {
    __syncthreads();
    for (int i = t; i < 4096; i += 256) {
      const int cin = i >> 6, cc = i & 63;
      wbuf[i] = W2[cin * 128 + hc * 64 + cc];
    }
    __syncthreads();
    float st_s = 0.f, st_q = 0.f, mx = -1e8f;
    for (int rh = 0; rh < 2; ++rh) {
      const int rr = rh * 32 + (t >> 3);
      const int cc0 = (t & 7) * 8;
      float a3[8];
#pragma unroll
      for (int j = 0; j < 8; ++j) a3[j] = B2[hc * 64 + cc0 + j];
      for (int cin = 0; cin < 64; ++cin) {
        const float a = tB[rr * 65 + cin];
        const float4* w4 = reinterpret_cast<const float4*>(&wbuf[cin * 64 + cc0]);
#pragma unroll
        for (int k = 0; k < 2; ++k) {
          const float4 w = w4[k];
          a3[k * 4 + 0] = fmaf(a, w.x, a3[k * 4 + 0]);
          a3[k * 4 + 1] = fmaf(a, w.y, a3[k * 4 + 1]);
          a3[k * 4 + 2] = fmaf(a, w.z, a3[k * 4 + 2]);
          a3[k * 4 + 3] = fmaf(a, w.w, a3[k * 4 + 3]);
        }
      }
      __syncthreads();
#pragma unroll
      for (int j = 0; j < 8; ++j) tA[(t >> 3) * 65 + cc0 + j] = a3[j];
      __syncthreads();
      if (t < 64) {
        if (MODE == 3) {
          for (int q2 = 0; q2 < 32; ++q2) { const float v = tA[q2 * 65 + t]; st_s += v; st_q += v * v; }
        } else {
          const float scv = sc3[hc * 64 + t], shv = sh3[hc * 64 + t];
          for (int q2 = 0; q2 < 32; ++q2) {
            const int kidx = rh * 32 + q2;
            const float y = tA[q2 * 65 + t];
            const float act = fmaxf(fmaf(y, scv, shv), 0.f);
            const float v = (sqs[kidx] <= 0.16f) ? act : -1e8f;
            mx = fmaxf(mx, v);
          }
        }
      }
      __syncthreads();
    }
    if (t < 64) {
      if (MODE == 3) {
        partials[((size_t)blk * 128 + hc * 64 + t) * 2 + 0] = st_s;
        partials[((size_t)blk * 128 + hc * 64 + t) * 2 + 1] = st_q;
      } else if (MODE == 4) {
        x1[(size_t)blk * 128 + hc * 64 + t] = mx;
      }
    }
  }
}

// Deterministic final reduce of per-block stats partials -> BN scale/shift.
__global__ void reduce_stats(const float* __restrict__ partials, int nblk, int C, float invN,
                             const float* __restrict__ g, const float* __restrict__ be,
                             float* __restrict__ sc, float* __restrict__ sh) {
  const int c = threadIdx.x;
  if (c >= C) return;
  double s = 0.0, q = 0.0;
  for (int k = 0; k < nblk; ++k) {
    s += (double)partials[((size_t)k * C + c) * 2 + 0];
    q += (double)partials[((size_t)k * C + c) * 2 + 1];
  }
  const double mean = s * (double)invN;
  double var = q * (double)invN - mean * mean;
  if (var < 0.0) var = 0.0;
  const float scl = (float)((double)g[c] / sqrt(var + 1e-5));
  sc[c] = scl;
  sh[c] = be[c] - (float)mean * scl;
}

// ---------------------------------------------------------------- stage 1 (2048 rows)
__global__ __launch_bounds__(128) void s1_kernel(const float* __restrict__ sp,
                                                 const float* __restrict__ x1,
                                                 const float* __restrict__ W,
                                                 const float* __restrict__ bia,
                                                 float* __restrict__ y1) {
  __shared__ float row[132];
  const int rowid = blockIdx.x;
  const int t = threadIdx.x;
  if (t < 3) row[t] = sp[(size_t)rowid * 3 + t];
  row[3 + t] = x1[(size_t)rowid * 128 + t];
  __syncthreads();
  float acc = bia[t];
  for (int cin = 0; cin < 131; ++cin) acc = fmaf(row[cin], W[(size_t)cin * 128 + t], acc);
  y1[(size_t)rowid * 128 + t] = acc;
}

__global__ __launch_bounds__(128) void s2_kernel(const float* __restrict__ y1,
                                                 const float* __restrict__ sc, const float* __restrict__ sh,
                                                 const float* __restrict__ W, const float* __restrict__ bia,
                                                 float* __restrict__ y2) {
  __shared__ float row[128];
  const int rowid = blockIdx.x;
  const int t = threadIdx.x;
  row[t] = fmaxf(fmaf(y1[(size_t)rowid * 128 + t], sc[t], sh[t]), 0.f);
  __syncthreads();
  float acc = bia[t];
  for (int cin = 0; cin < 128; ++cin) acc = fmaf(row[cin], W[(size_t)cin * 128 + t], acc);
  y2[(size_t)rowid * 128 + t] = acc;
}

__global__ __launch_bounds__(256) void s3_kernel(const float* __restrict__ y2,
                                                 const float* __restrict__ sc, const float* __restrict__ sh,
                                                 const float* __restrict__ W, const float* __restrict__ bia,
                                                 float* __restrict__ y3) {
  __shared__ float row[128];
  const int rowid = blockIdx.x;
  const int t = threadIdx.x;
  if (t < 128) row[t] = fmaxf(fmaf(y2[(size_t)rowid * 128 + t], sc[t], sh[t]), 0.f);
  __syncthreads();
  for (int h = 0; h < 2; ++h) {
    const int c = h * 256 + t;
    float acc = bia[c];
    for (int cin = 0; cin < 128; ++cin) acc = fmaf(row[cin], W[(size_t)cin * 512 + c], acc);
    y3[(size_t)rowid * 512 + c] = acc;
  }
}

// Deterministic per-channel stats over rows (block per channel, tree reduce).
__global__ __launch_bounds__(256) void s_stats(const float* __restrict__ y, int C, int rows,
                                               const float* __restrict__ g, const float* __restrict__ be,
                                               float* __restrict__ sc, float* __restrict__ sh) {
  const int c = blockIdx.x;
  const int t = threadIdx.x;
  double s = 0.0, q = 0.0;
  for (int r2 = t; r2 < rows; r2 += 256) {
    const double v = (double)y[(size_t)r2 * C + c];
    s += v;
    q += v * v;
  }
  __shared__ double ss[256], qq[256];
  ss[t] = s;
  qq[t] = q;
  __syncthreads();
  for (int st = 128; st > 0; st >>= 1) {
    if (t < st) { ss[t] += ss[t + st]; qq[t] += qq[t + st]; }
    __syncthreads();
  }
  if (t == 0) {
    const double mean = ss[0] / rows;
    double var = qq[0] / rows - mean * mean;
    if (var < 0.0) var = 0.0;
    const float scl = (float)((double)g[c] / sqrt(var + 1e-5));
    sc[c] = scl;
    sh[c] = be[c] - (float)mean * scl;
  }
}

__global__ __launch_bounds__(256) void final_kernel(const float* __restrict__ y3,
                                                    const float* __restrict__ sc, const float* __restrict__ sh,
                                                    float* __restrict__ out) {
  const int gid = blockIdx.x * 256 + threadIdx.x;  // 8192 = 16 batches x 512 ch
  const int b = gid >> 9;
  const int c = gid & 511;
  const float scv = sc[c], shv = sh[c];
  float mx = -3.402823466e+38f;
  for (int m = 0; m < 128; ++m) {
    const float v = fmaxf(fmaf(y3[((size_t)(b * 128 + m)) * 512 + c], scv, shv), 0.f);
    mx = fmaxf(mx, v);
  }
  out[gid] = mx;
  if (gid < 48) out[8192 + gid] = 0.f;  // pos_out zeros
}

extern "C" void kernel_launch(void* const* d_in, const int* in_sizes, int n_in,
                              void* d_out, int out_size, void* d_ws, size_t ws_size,
                              hipStream_t stream) {
  const float* x    = (const float*)d_in[0];
  const float* pos  = (const float*)d_in[1];
  const float* W00  = (const float*)d_in[2];
  const float* b00  = (const float*)d_in[3];
  const float* g00  = (const float*)d_in[4];
  const float* be00 = (const float*)d_in[5];
  const float* W01  = (const float*)d_in[6];
  const float* b01  = (const float*)d_in[7];
  const float* g01  = (const float*)d_in[8];
  const float* be01 = (const float*)d_in[9];
  const float* W02  = (const float*)d_in[10];
  const float* b02  = (const float*)d_in[11];
  const float* g02  = (const float*)d_in[12];
  const float* be02 = (const float*)d_in[13];
  const float* W10  = (const float*)d_in[14];
  const float* b10  = (const float*)d_in[15];
  const float* g10  = (const float*)d_in[16];
  const float* be10 = (const float*)d_in[17];
  const float* W11  = (const float*)d_in[18];
  const float* b11  = (const float*)d_in[19];
  const float* g11  = (const float*)d_in[20];
  const float* be11 = (const float*)d_in[21];
  const float* W12  = (const float*)d_in[22];
  const float* b12  = (const float*)d_in[23];
  const float* g12  = (const float*)d_in[24];
  const float* be12 = (const float*)d_in[25];

  float* w = (float*)d_ws;
  float* sp    = w;                  // 16*128*3          = 6144
  float* gf0   = sp + 6144;          // 16*128*64*6       = 786432
  float* sqsel = gf0 + 786432;       // 16*128*64         = 131072
  float* x1    = sqsel + 131072;     // 16*128*128        = 262144
  float* parts = x1 + 262144;        // 2048*128*2        = 524288
  float* st    = parts + 524288;     // stats area        = 2048
  float* sc1 = st + 0,    *sh1 = st + 64;
  float* sc2 = st + 128,  *sh2 = st + 192;
  float* sc3 = st + 256,  *sh3 = st + 384;
  float* t1sc = st + 512, *t1sh = st + 640;
  float* t2sc = st + 768, *t2sh = st + 896;
  float* t3sc = st + 1024, *t3sh = st + 1536;
  float* y1s = st + 2048;            // 2048*128 = 262144
  float* y2s = y1s + 262144;         // 2048*128 = 262144
  float* y3s = y2s + 262144;         // 2048*512 = 1048576
  // total ws use: ~3.29M floats (~13.2 MB)

  fps_kernel<<<BATCH, 1024, 3 * NPTS * sizeof(float), stream>>>(pos, sp);
  knn_kernel<<<BATCH * MS, 256, 0, stream>>>(pos, x, sp, gf0, sqsel);

  const float invN0 = 1.0f / (float)(BATCH * MS * KNB);  // 1/131072
  chain_kernel<1><<<BATCH * MS, 256, 0, stream>>>(gf0, W00, b00, W01, b01, W02, b02,
                                                  sc1, sh1, sc2, sh2, sc3, sh3, sqsel, parts, x1);
  reduce_stats<<<1, 64, 0, stream>>>(parts, BATCH * MS, 64, invN0, g00, be00, sc1, sh1);
  chain_kernel<2><<<BATCH * MS, 256, 0, stream>>>(gf0, W00, b00, W01, b01, W02, b02,
                                                  sc1, sh1, sc2, sh2, sc3, sh3, sqsel, parts, x1);
  reduce_stats<<<1, 64, 0, stream>>>(parts, BATCH * MS, 64, invN0, g01, be01, sc2, sh2);
  chain_kernel<3><<<BATCH * MS, 256, 0, stream>>>(gf0, W00, b00, W01, b01, W02, b02,
                                                  sc1, sh1, sc2, sh2, sc3, sh3, sqsel, parts, x1);
  reduce_stats<<<1, 128, 0, stream>>>(parts, BATCH * MS, 128, invN0, g02, be02, sc3, sh3);
  chain_kernel<4><<<BATCH * MS, 256, 0, stream>>>(gf0, W00, b00, W01, b01, W02, b02,
                                                  sc1, sh1, sc2, sh2, sc3, sh3, sqsel, parts, x1);

  s1_kernel<<<BATCH * MS, 128, 0, stream>>>(sp, x1, W10, b10, y1s);
  s_stats<<<128, 256, 0, stream>>>(y1s, 128, BATCH * MS, g10, be10, t1sc, t1sh);
  s2_kernel<<<BATCH * MS, 128, 0, stream>>>(y1s, t1sc, t1sh, W11, b11, y2s);
  s_stats<<<128, 256, 0, stream>>>(y2s, 128, BATCH * MS, g11, be11, t2sc, t2sh);
  s3_kernel<<<BATCH * MS, 256, 0, stream>>>(y2s, t2sc, t2sh, W12, b12, y3s);
  s_stats<<<512, 256, 0, stream>>>(y3s, 512, BATCH * MS, g12, be12, t3sc, t3sh);
  final_kernel<<<32, 256, 0, stream>>>(y3s, t3sc, t3sh, (float*)d_out);
}

// Round 2
// 753.301 us; speedup vs baseline: 3.0220x; 3.0220x over previous
//
#include <hip/hip_runtime.h>
#include <cstdint>
#include <cstddef>

#define NPTS 8192
#define BATCH 16
#define MS 128
#define KNB 64
#define NBLK (BATCH * MS)   // 2048

// ---------------------------------------------------------------- FPS
// One block per batch. Stages pos into 96KB dynamic LDS, then 128 sequential
// farthest-point iterations with wave-butterfly argmax (first-occurrence ties).
__global__ __launch_bounds__(1024) void fps_kernel(const float* __restrict__ pos,
                                                   float* __restrict__ sp) {
#pragma clang fp contract(off)
  extern __shared__ float smem[];
  float* px = smem;
  float* py = smem + NPTS;
  float* pz = smem + 2 * NPTS;
  const int b = blockIdx.x;
  const float* P = pos + (size_t)b * NPTS * 3;
  const int t = threadIdx.x;
  for (int i = t; i < NPTS; i += 1024) {
    px[i] = P[i * 3 + 0];
    py[i] = P[i * 3 + 1];
    pz[i] = P[i * 3 + 2];
  }
  float md[8];
#pragma unroll
  for (int j = 0; j < 8; ++j) md[j] = 1e10f;
  __shared__ int s_last;
  __shared__ float wv[16];
  __shared__ int wi[16];
  if (t == 0) s_last = 0;
  __syncthreads();
  for (int it = 0; it < MS; ++it) {
    const int last = s_last;
    const float lx = px[last], ly = py[last], lz = pz[last];
    if (t == 0) {
      sp[((size_t)b * MS + it) * 3 + 0] = lx;
      sp[((size_t)b * MS + it) * 3 + 1] = ly;
      sp[((size_t)b * MS + it) * 3 + 2] = lz;
    }
    float bv = -1.0f;
    int bi = 0;
#pragma unroll
    for (int j = 0; j < 8; ++j) {
      const int i = j * 1024 + t;
      const float dx = px[i] - lx;
      const float dy = py[i] - ly;
      const float dz = pz[i] - lz;
      const float d = dx * dx + dy * dy + dz * dz;  // contract off: mul,mul,mul,add,add
      float m = md[j];
      m = (d < m) ? d : m;
      md[j] = m;
      if (m > bv) { bv = m; bi = i; }  // ascending i within thread -> first occurrence
    }
    for (int s = 1; s < 64; s <<= 1) {
      const float ov = __shfl_xor(bv, s);
      const int oi = __shfl_xor(bi, s);
      if (ov > bv || (ov == bv && oi < bi)) { bv = ov; bi = oi; }
    }
    if ((t & 63) == 0) { wv[t >> 6] = bv; wi[t >> 6] = bi; }
    __syncthreads();
    if (t == 0) {
      float Bv = wv[0];
      int Bi = wi[0];
      for (int w = 1; w < 16; ++w)
        if (wv[w] > Bv || (wv[w] == Bv && wi[w] < Bi)) { Bv = wv[w]; Bi = wi[w]; }
      s_last = Bi;
    }
    __syncthreads();
  }
}

// ---------------------------------------------------------------- kNN top-64
// Tournament selection. Key = (float_bits << 32) | idx packs (value, index)
// lexicographic order (monotone for non-negative floats; ties -> smaller idx),
// which is exactly lax.top_k's stable selection set. Per round only the
// winner's owner column (32 elems, one wave) is rescanned.
static __device__ __forceinline__ unsigned long long shfl_xor_u64(unsigned long long v, int m) {
  unsigned int lo = (unsigned int)v, hi = (unsigned int)(v >> 32);
  lo = (unsigned int)__shfl_xor((int)lo, m);
  hi = (unsigned int)__shfl_xor((int)hi, m);
  return ((unsigned long long)hi << 32) | lo;
}

__global__ __launch_bounds__(256) void knn_kernel(const float* __restrict__ pos,
                                                  const float* __restrict__ xf,
                                                  const float* __restrict__ sp,
                                                  float* __restrict__ gf0,
                                                  float* __restrict__ sqsel) {
#pragma clang fp contract(off)
  __shared__ float sqv[NPTS];
  __shared__ unsigned long long cand[256];
  __shared__ unsigned long long wkey[4];
  __shared__ int sel_i[KNB];
  __shared__ float sel_v[KNB];
  __shared__ int s_widx;
  const int bm = blockIdx.x;
  const int b = bm >> 7;
  const float* P = pos + (size_t)b * NPTS * 3;
  const float sx = sp[bm * 3 + 0], sy = sp[bm * 3 + 1], sz = sp[bm * 3 + 2];
  const float nsp = sx * sx + sy * sy + sz * sz;
  const int t = threadIdx.x;
  for (int j = 0; j < 32; ++j) {
    const int i = j * 256 + t;
    const float qx = P[i * 3 + 0], qy = P[i * 3 + 1], qz = P[i * 3 + 2];
    const float npos = qx * qx + qy * qy + qz * qz;
    const float dt = sx * qx + sy * qy + sz * qz;
    float sq = (nsp + npos) - 2.0f * dt;  // matches ||a||^2+||b||^2-2ab order
    sq = fmaxf(sq, 0.0f);
    sqv[i] = sq;
  }
  __syncthreads();
  // per-thread local min key over its 32-element column
  {
    unsigned long long k0 = ~0ULL;
    for (int j = 0; j < 32; ++j) {
      const int i = j * 256 + t;
      const unsigned long long key =
          ((unsigned long long)__float_as_uint(sqv[i]) << 32) | (unsigned int)i;
      if (key < k0) k0 = key;
    }
    cand[t] = k0;
  }
  __syncthreads();
  for (int round = 0; round < KNB; ++round) {
    unsigned long long k0 = cand[t];
    for (int s = 1; s < 64; s <<= 1) {
      const unsigned long long o = shfl_xor_u64(k0, s);
      if (o < k0) k0 = o;
    }
    if ((t & 63) == 0) wkey[t >> 6] = k0;
    __syncthreads();
    if (t == 0) {
      unsigned long long B = wkey[0];
      for (int w = 1; w < 4; ++w)
        if (wkey[w] < B) B = wkey[w];
      const int idx = (int)(B & 0xffffffffu);
      sel_i[round] = idx;
      sel_v[round] = __uint_as_float((unsigned int)(B >> 32));
      s_widx = idx;
      sqv[idx] = __uint_as_float(0x7f800000u);  // +inf: consumed
    }
    __syncthreads();
    const int owner = s_widx & 255;
    if ((t >> 6) == (owner >> 6)) {
      const int lane = t & 63;
      unsigned long long key = ~0ULL;
      if (lane < 32) {
        const int i = lane * 256 + owner;
        key = ((unsigned long long)__float_as_uint(sqv[i]) << 32) | (unsigned int)i;
      }
      for (int s = 1; s < 64; s <<= 1) {
        const unsigned long long o = shfl_xor_u64(key, s);
        if (o < key) key = o;
      }
      if (lane == 0) cand[owner] = key;
    }
    __syncthreads();
  }
  if (t < KNB) {
    const int i = sel_i[t];
    const float* X = xf + (size_t)b * NPTS * 3;
    const size_t base = ((size_t)bm * KNB + t) * 6;
    gf0[base + 0] = P[i * 3 + 0] - sx;
    gf0[base + 1] = P[i * 3 + 1] - sy;
    gf0[base + 2] = P[i * 3 + 2] - sz;
    gf0[base + 3] = X[i * 3 + 0];
    gf0[base + 4] = X[i * 3 + 1];
    gf0[base + 5] = X[i * 3 + 2];
    sqsel[(size_t)bm * KNB + t] = sel_v[t];
  }
}

// ---------------------------------------------------------------- stage-0 conv chain
// One block per (b, sample) 64x6 tile. Recomputes the conv chain to the target
// depth each pass (BN needs global stats between layers; FLOPs are tiny).
// MODE 1: y1 stats   MODE 2: y2 stats   MODE 3: y3 stats   MODE 4: masked max -> x1
// Stats partials are written [channel][block] (coalesced for p_stats).
template <int MODE>
__global__ __launch_bounds__(256) void chain_kernel(
    const float* __restrict__ gf0,
    const float* __restrict__ W0, const float* __restrict__ B0,
    const float* __restrict__ W1, const float* __restrict__ B1,
    const float* __restrict__ W2, const float* __restrict__ B2,
    const float* __restrict__ sc1, const float* __restrict__ sh1,
    const float* __restrict__ sc2, const float* __restrict__ sh2,
    const float* __restrict__ sc3, const float* __restrict__ sh3,
    const float* __restrict__ sqsel,
    float* __restrict__ psum, float* __restrict__ psq, float* __restrict__ x1) {
  __shared__ float tA[64 * 65];  // +1 pad: kills stride-64 bank conflicts on row reads
  __shared__ float tB[64 * 65];
  __shared__ float wbuf[64 * 64];
  __shared__ float in6[64 * 8];
  __shared__ float sqs[64];
  const int blk = blockIdx.x;
  const int t = threadIdx.x;
  {
    const float* G = gf0 + (size_t)blk * 64 * 6;
    for (int i = t; i < 384; i += 256) in6[(i / 6) * 8 + (i % 6)] = G[i];
    for (int i = t; i < 384; i += 256) wbuf[i] = W0[i];
    if (MODE == 4 && t < 64) sqs[t] = sqsel[(size_t)blk * 64 + t];
  }
  __syncthreads();
  const int r = t >> 2;
  const int c0 = (t & 3) * 16;
  float acc[16];
  // L1: 6 -> 64
#pragma unroll
  for (int j = 0; j < 16; ++j) acc[j] = B0[c0 + j];
  for (int cin = 0; cin < 6; ++cin) {
    const float a = in6[r * 8 + cin];
#pragma unroll
    for (int j = 0; j < 16; ++j) acc[j] = fmaf(a, wbuf[cin * 64 + c0 + j], acc[j]);
  }
  if (MODE == 1) {
#pragma unroll
    for (int j = 0; j < 16; ++j) tA[r * 65 + c0 + j] = acc[j];
    __syncthreads();
    if (t < 64) {
      float s = 0.f, q = 0.f;
      for (int r2 = 0; r2 < 64; ++r2) { const float v = tA[r2 * 65 + t]; s += v; q += v * v; }
      psum[(size_t)t * NBLK + blk] = s;
      psq[(size_t)t * NBLK + blk] = q;
    }
    return;
  }
#pragma unroll
  for (int j = 0; j < 16; ++j) {
    const int c = c0 + j;
    tA[r * 65 + c] = fmaxf(fmaf(acc[j], sc1[c], sh1[c]), 0.f);
  }
  __syncthreads();
  for (int i = t; i < 4096; i += 256) wbuf[i] = W1[i];
  __syncthreads();
  // L2: 64 -> 64
#pragma unroll
  for (int j = 0; j < 16; ++j) acc[j] = B1[c0 + j];
  for (int cin = 0; cin < 64; ++cin) {
    const float a = tA[r * 65 + cin];
    const float4* w4 = reinterpret_cast<const float4*>(&wbuf[cin * 64 + c0]);
#pragma unroll
    for (int k = 0; k < 4; ++k) {
      const float4 w = w4[k];
      acc[k * 4 + 0] = fmaf(a, w.x, acc[k * 4 + 0]);
      acc[k * 4 + 1] = fmaf(a, w.y, acc[k * 4 + 1]);
      acc[k * 4 + 2] = fmaf(a, w.z, acc[k * 4 + 2]);
      acc[k * 4 + 3] = fmaf(a, w.w, acc[k * 4 + 3]);
    }
  }
  if (MODE == 2) {
#pragma unroll
    for (int j = 0; j < 16; ++j) tB[r * 65 + c0 + j] = acc[j];
    __syncthreads();
    if (t < 64) {
      float s = 0.f, q = 0.f;
      for (int r2 = 0; r2 < 64; ++r2) { const float v = tB[r2 * 65 + t]; s += v; q += v * v; }
      psum[(size_t)t * NBLK + blk] = s;
      psq[(size_t)t * NBLK + blk] = q;
    }
    return;
  }
#pragma unroll
  for (int j = 0; j < 16; ++j) {
    const int c = c0 + j;
    tB[r * 65 + c] = fmaxf(fmaf(acc[j], sc2[c], sh2[c]), 0.f);
  }
  // L3: 64 -> 128, processed in channel halves (wbuf holds 64x64 weight half)
  for (int hc = 0; hc < 2; ++hc) {
    __syncthreads();
    for (int i = t; i < 4096; i += 256) {
      const int cin = i >> 6, cc = i & 63;
      wbuf[i] = W2[cin * 128 + hc * 64 + cc];
    }
    __syncthreads();
    float st_s = 0.f, st_q = 0.f, mx = -1e8f;
    for (int rh = 0; rh < 2; ++rh) {
      const int rr = rh * 32 + (t >> 3);
      const int cc0 = (t & 7) * 8;
      float a3[8];
#pragma unroll
      for (int j = 0; j < 8; ++j) a3[j] = B2[hc * 64 + cc0 + j];
      for (int cin = 0; cin < 64; ++cin) {
        const float a = tB[rr * 65 + cin];
        const float4* w4 = reinterpret_cast<const float4*>(&wbuf[cin * 64 + cc0]);
#pragma unroll
        for (int k = 0; k < 2; ++k) {
          const float4 w = w4[k];
          a3[k * 4 + 0] = fmaf(a, w.x, a3[k * 4 + 0]);
          a3[k * 4 + 1] = fmaf(a, w.y, a3[k * 4 + 1]);
          a3[k * 4 + 2] = fmaf(a, w.z, a3[k * 4 + 2]);
          a3[k * 4 + 3] = fmaf(a, w.w, a3[k * 4 + 3]);
        }
      }
      __syncthreads();
#pragma unroll
      for (int j = 0; j < 8; ++j) tA[(t >> 3) * 65 + cc0 + j] = a3[j];
      __syncthreads();
      if (t < 64) {
        if (MODE == 3) {
          for (int q2 = 0; q2 < 32; ++q2) { const float v = tA[q2 * 65 + t]; st_s += v; st_q += v * v; }
        } else {
          const float scv = sc3[hc * 64 + t], shv = sh3[hc * 64 + t];
          for (int q2 = 0; q2 < 32; ++q2) {
            const int kidx = rh * 32 + q2;
            const float y = tA[q2 * 65 + t];
            const float act = fmaxf(fmaf(y, scv, shv), 0.f);
            const float v = (sqs[kidx] <= 0.16f) ? act : -1e8f;
            mx = fmaxf(mx, v);
          }
        }
      }
      __syncthreads();
    }
    if (t < 64) {
      if (MODE == 3) {
        psum[(size_t)(hc * 64 + t) * NBLK + blk] = st_s;
        psq[(size_t)(hc * 64 + t) * NBLK + blk] = st_q;
      } else if (MODE == 4) {
        x1[(size_t)blk * 128 + hc * 64 + t] = mx;
      }
    }
  }
}

// Parallel deterministic stats reduce: one block per channel, coalesced reads,
// f64 LDS tree. Replaces the serial <<<1,C>>> reduce (was ~525us each).
__global__ __launch_bounds__(256) void p_stats(const float* __restrict__ psum,
                                               const float* __restrict__ psq,
                                               float invN,
                                               const float* __restrict__ g,
                                               const float* __restrict__ be,
                                               float* __restrict__ sc,
                                               float* __restrict__ sh) {
  const int c = blockIdx.x;
  const int t = threadIdx.x;
  double s = 0.0, q = 0.0;
  for (int k = t; k < NBLK; k += 256) {
    s += (double)psum[(size_t)c * NBLK + k];
    q += (double)psq[(size_t)c * NBLK + k];
  }
  __shared__ double ss[256], qq[256];
  ss[t] = s;
  qq[t] = q;
  __syncthreads();
  for (int st = 128; st > 0; st >>= 1) {
    if (t < st) { ss[t] += ss[t + st]; qq[t] += qq[t + st]; }
    __syncthreads();
  }
  if (t == 0) {
    const double mean = ss[0] * (double)invN;
    double var = qq[0] * (double)invN - mean * mean;
    if (var < 0.0) var = 0.0;
    const float scl = (float)((double)g[c] / sqrt(var + 1e-5));
    sc[c] = scl;
    sh[c] = be[c] - (float)mean * scl;
  }
}

// ---------------------------------------------------------------- stage 1 (2048 rows)
__global__ __launch_bounds__(128) void s1_kernel(const float* __restrict__ sp,
                                                 const float* __restrict__ x1,
                                                 const float* __restrict__ W,
                                                 const float* __restrict__ bia,
                                                 float* __restrict__ y1) {
  __shared__ float row[132];
  const int rowid = blockIdx.x;
  const int t = threadIdx.x;
  if (t < 3) row[t] = sp[(size_t)rowid * 3 + t];
  row[3 + t] = x1[(size_t)rowid * 128 + t];
  __syncthreads();
  float acc = bia[t];
  for (int cin = 0; cin < 131; ++cin) acc = fmaf(row[cin], W[(size_t)cin * 128 + t], acc);
  y1[(size_t)rowid * 128 + t] = acc;
}

__global__ __launch_bounds__(128) void s2_kernel(const float* __restrict__ y1,
                                                 const float* __restrict__ sc, const float* __restrict__ sh,
                                                 const float* __restrict__ W, const float* __restrict__ bia,
                                                 float* __restrict__ y2) {
  __shared__ float row[128];
  const int rowid = blockIdx.x;
  const int t = threadIdx.x;
  row[t] = fmaxf(fmaf(y1[(size_t)rowid * 128 + t], sc[t], sh[t]), 0.f);
  __syncthreads();
  float acc = bia[t];
  for (int cin = 0; cin < 128; ++cin) acc = fmaf(row[cin], W[(size_t)cin * 128 + t], acc);
  y2[(size_t)rowid * 128 + t] = acc;
}

__global__ __launch_bounds__(256) void s3_kernel(const float* __restrict__ y2,
                                                 const float* __restrict__ sc, const float* __restrict__ sh,
                                                 const float* __restrict__ W, const float* __restrict__ bia,
                                                 float* __restrict__ y3) {
  __shared__ float row[128];
  const int rowid = blockIdx.x;
  const int t = threadIdx.x;
  if (t < 128) row[t] = fmaxf(fmaf(y2[(size_t)rowid * 128 + t], sc[t], sh[t]), 0.f);
  __syncthreads();
  for (int h = 0; h < 2; ++h) {
    const int c = h * 256 + t;
    float acc = bia[c];
    for (int cin = 0; cin < 128; ++cin) acc = fmaf(row[cin], W[(size_t)cin * 512 + c], acc);
    y3[(size_t)rowid * 512 + c] = acc;
  }
}

// Deterministic per-channel stats over rows (block per channel, tree reduce).
__global__ __launch_bounds__(256) void s_stats(const float* __restrict__ y, int C, int rows,
                                               const float* __restrict__ g, const float* __restrict__ be,
                                               float* __restrict__ sc, float* __restrict__ sh) {
  const int c = blockIdx.x;
  const int t = threadIdx.x;
  double s = 0.0, q = 0.0;
  for (int r2 = t; r2 < rows; r2 += 256) {
    const double v = (double)y[(size_t)r2 * C + c];
    s += v;
    q += v * v;
  }
  __shared__ double ss[256], qq[256];
  ss[t] = s;
  qq[t] = q;
  __syncthreads();
  for (int st = 128; st > 0; st >>= 1) {
    if (t < st) { ss[t] += ss[t + st]; qq[t] += qq[t + st]; }
    __syncthreads();
  }
  if (t == 0) {
    const double mean = ss[0] / rows;
    double var = qq[0] / rows - mean * mean;
    if (var < 0.0) var = 0.0;
    const float scl = (float)((double)g[c] / sqrt(var + 1e-5));
    sc[c] = scl;
    sh[c] = be[c] - (float)mean * scl;
  }
}

__global__ __launch_bounds__(256) void final_kernel(const float* __restrict__ y3,
                                                    const float* __restrict__ sc, const float* __restrict__ sh,
                                                    float* __restrict__ out) {
  const int gid = blockIdx.x * 256 + threadIdx.x;  // 8192 = 16 batches x 512 ch
  const int b = gid >> 9;
  const int c = gid & 511;
  const float scv = sc[c], shv = sh[c];
  float mx = -3.402823466e+38f;
  for (int m = 0; m < 128; ++m) {
    const float v = fmaxf(fmaf(y3[((size_t)(b * 128 + m)) * 512 + c], scv, shv), 0.f);
    mx = fmaxf(mx, v);
  }
  out[gid] = mx;
  if (gid < 48) out[8192 + gid] = 0.f;  // pos_out zeros
}

extern "C" void kernel_launch(void* const* d_in, const int* in_sizes, int n_in,
                              void* d_out, int out_size, void* d_ws, size_t ws_size,
                              hipStream_t stream) {
  const float* x    = (const float*)d_in[0];
  const float* pos  = (const float*)d_in[1];
  const float* W00  = (const float*)d_in[2];
  const float* b00  = (const float*)d_in[3];
  const float* g00  = (const float*)d_in[4];
  const float* be00 = (const float*)d_in[5];
  const float* W01  = (const float*)d_in[6];
  const float* b01  = (const float*)d_in[7];
  const float* g01  = (const float*)d_in[8];
  const float* be01 = (const float*)d_in[9];
  const float* W02  = (const float*)d_in[10];
  const float* b02  = (const float*)d_in[11];
  const float* g02  = (const float*)d_in[12];
  const float* be02 = (const float*)d_in[13];
  const float* W10  = (const float*)d_in[14];
  const float* b10  = (const float*)d_in[15];
  const float* g10  = (const float*)d_in[16];
  const float* be10 = (const float*)d_in[17];
  const float* W11  = (const float*)d_in[18];
  const float* b11  = (const float*)d_in[19];
  const float* g11  = (const float*)d_in[20];
  const float* be11 = (const float*)d_in[21];
  const float* W12  = (const float*)d_in[22];
  const float* b12  = (const float*)d_in[23];
  const float* g12  = (const float*)d_in[24];
  const float* be12 = (const float*)d_in[25];

  float* w = (float*)d_ws;
  float* sp    = w;                  // 16*128*3          = 6144
  float* gf0   = sp + 6144;          // 16*128*64*6       = 786432
  float* sqsel = gf0 + 786432;       // 16*128*64         = 131072
  float* x1    = sqsel + 131072;     // 16*128*128        = 262144
  float* parts = x1 + 262144;        // 128*2048*2        = 524288
  float* psum  = parts;              // [c][blk]
  float* psq   = parts + 128 * NBLK; // [c][blk]
  float* st    = parts + 524288;     // stats area        = 2048
  float* sc1 = st + 0,    *sh1 = st + 64;
  float* sc2 = st + 128,  *sh2 = st + 192;
  float* sc3 = st + 256,  *sh3 = st + 384;
  float* t1sc = st + 512, *t1sh = st + 640;
  float* t2sc = st + 768, *t2sh = st + 896;
  float* t3sc = st + 1024, *t3sh = st + 1536;
  float* y1s = st + 2048;            // 2048*128 = 262144
  float* y2s = y1s + 262144;         // 2048*128 = 262144
  float* y3s = y2s + 262144;         // 2048*512 = 1048576
  // total ws use: ~3.29M floats (~13.2 MB)

  fps_kernel<<<BATCH, 1024, 3 * NPTS * sizeof(float), stream>>>(pos, sp);
  knn_kernel<<<BATCH * MS, 256, 0, stream>>>(pos, x, sp, gf0, sqsel);

  const float invN0 = 1.0f / (float)(NBLK * KNB);  // 1/131072
  chain_kernel<1><<<NBLK, 256, 0, stream>>>(gf0, W00, b00, W01, b01, W02, b02,
                                            sc1, sh1, sc2, sh2, sc3, sh3, sqsel, psum, psq, x1);
  p_stats<<<64, 256, 0, stream>>>(psum, psq, invN0, g00, be00, sc1, sh1);
  chain_kernel<2><<<NBLK, 256, 0, stream>>>(gf0, W00, b00, W01, b01, W02, b02,
                                            sc1, sh1, sc2, sh2, sc3, sh3, sqsel, psum, psq, x1);
  p_stats<<<64, 256, 0, stream>>>(psum, psq, invN0, g01, be01, sc2, sh2);
  chain_kernel<3><<<NBLK, 256, 0, stream>>>(gf0, W00, b00, W01, b01, W02, b02,
                                            sc1, sh1, sc2, sh2, sc3, sh3, sqsel, psum, psq, x1);
  p_stats<<<128, 256, 0, stream>>>(psum, psq, invN0, g02, be02, sc3, sh3);
  chain_kernel<4><<<NBLK, 256, 0, stream>>>(gf0, W00, b00, W01, b01, W02, b02,
                                            sc1, sh1, sc2, sh2, sc3, sh3, sqsel, psum, psq, x1);

  s1_kernel<<<NBLK, 128, 0, stream>>>(sp, x1, W10, b10, y1s);
  s_stats<<<128, 256, 0, stream>>>(y1s, 128, NBLK, g10, be10, t1sc, t1sh);
  s2_kernel<<<NBLK, 128, 0, stream>>>(y1s, t1sc, t1sh, W11, b11, y2s);
  s_stats<<<128, 256, 0, stream>>>(y2s, 128, NBLK, g11, be11, t2sc, t2sh);
  s3_kernel<<<NBLK, 256, 0, stream>>>(y2s, t2sc, t2sh, W12, b12, y3s);
  s_stats<<<512, 256, 0, stream>>>(y3s, 512, NBLK, g12, be12, t3sc, t3sh);
  final_kernel<<<32, 256, 0, stream>>>(y3s, t3sc, t3sh, (float*)d_out);
}

// Round 3
// 623.977 us; speedup vs baseline: 3.6483x; 1.2073x over previous
//
#include <hip/hip_runtime.h>
#include <cstdint>
#include <cstddef>

#define NPTS 8192
#define BATCH 16
#define MS 128
#define KNB 64
#define NBLK (BATCH * MS)   // 2048

static __device__ __forceinline__ unsigned long long shfl_xor_u64(unsigned long long v, int m) {
  unsigned int lo = (unsigned int)v, hi = (unsigned int)(v >> 32);
  lo = (unsigned int)__shfl_xor((int)lo, m);
  hi = (unsigned int)__shfl_xor((int)hi, m);
  return ((unsigned long long)hi << 32) | lo;
}

// ---------------------------------------------------------------- FPS
// One block per batch. Points live in REGISTERS (8/thread); per iteration the
// only LDS traffic is the 16-candidate exchange (key + coords, double-buffered
// by parity -> ONE barrier per iteration). Key = (bits(maxd)<<32) | ~idx :
// monotone for non-negative floats, ties -> smaller index (first occurrence),
// identical selection semantics to the verified serial version.
__global__ __launch_bounds__(1024) void fps_kernel(const float* __restrict__ pos,
                                                   float* __restrict__ sp) {
#pragma clang fp contract(off)
  __shared__ unsigned long long wkey[32];  // [parity][wave]
  __shared__ float4 wxyz[32];
  const int b = blockIdx.x;
  const float* P = pos + (size_t)b * NPTS * 3;
  const int t = threadIdx.x;
  const int wave = t >> 6;
  const int lane = t & 63;
  float X[8], Y[8], Z[8], md[8];
#pragma unroll
  for (int j = 0; j < 8; ++j) {
    const int i = j * 1024 + t;
    X[j] = P[i * 3 + 0];
    Y[j] = P[i * 3 + 1];
    Z[j] = P[i * 3 + 2];
    md[j] = 1e10f;
  }
  // initial last = point 0 (read directly from global; cached, one-time)
  float lx = P[0], ly = P[1], lz = P[2];
  for (int it = 0; it < MS; ++it) {
    const int par = (it & 1) * 16;
    if (t == 0) {
      sp[((size_t)b * MS + it) * 3 + 0] = lx;
      sp[((size_t)b * MS + it) * 3 + 1] = ly;
      sp[((size_t)b * MS + it) * 3 + 2] = lz;
    }
    float bv = -1.0f;
    int bi = 0;
#pragma unroll
    for (int j = 0; j < 8; ++j) {
      const float dx = X[j] - lx;
      const float dy = Y[j] - ly;
      const float dz = Z[j] - lz;
      const float d = dx * dx + dy * dy + dz * dz;  // contract off: same order as ref
      float m = md[j];
      m = (d < m) ? d : m;
      md[j] = m;
      if (m > bv) { bv = m; bi = j * 1024 + t; }  // ascending i -> first occurrence
    }
    unsigned long long key =
        ((unsigned long long)__float_as_uint(bv) << 32) | (unsigned int)(~(unsigned int)bi);
    for (int s = 1; s < 64; s <<= 1) {
      const unsigned long long o = shfl_xor_u64(key, s);
      if (o > key) key = o;
    }
    // wave winner: owner lane (has coords in regs) publishes key + coords
    {
      const unsigned int gi = ~(unsigned int)key;
      if (lane == (int)(gi & 63)) {
        const int j = gi >> 10;
        wkey[par + wave] = key;
        wxyz[par + wave] = make_float4(X[j], Y[j], Z[j], 0.f);
      }
    }
    __syncthreads();
    // stage 2: all lanes read the 16 slots (broadcast addresses), 4-step butterfly
    unsigned long long k2 = wkey[par + (lane & 15)];
    for (int s = 1; s < 16; s <<= 1) {
      const unsigned long long o = shfl_xor_u64(k2, s);
      if (o > k2) k2 = o;
    }
    const unsigned int g = ~(unsigned int)k2;
    const int slot = (int)((g & 1023) >> 6);
    const float4 c = wxyz[par + slot];  // same address across lanes -> LDS broadcast
    lx = c.x;
    ly = c.y;
    lz = c.z;
  }
}

// ---------------------------------------------------------------- kNN top-64
// Tournament selection. Key = (float_bits << 32) | idx packs (value, index)
// lexicographic order (monotone for non-negative floats; ties -> smaller idx),
// which is exactly lax.top_k's stable selection set. Per round only the
// winner's owner column (32 elems, one wave) is rescanned.
__global__ __launch_bounds__(256) void knn_kernel(const float* __restrict__ pos,
                                                  const float* __restrict__ xf,
                                                  const float* __restrict__ sp,
                                                  float* __restrict__ gf0,
                                                  float* __restrict__ sqsel) {
#pragma clang fp contract(off)
  __shared__ float sqv[NPTS];
  __shared__ unsigned long long cand[256];
  __shared__ unsigned long long wkey[4];
  __shared__ int sel_i[KNB];
  __shared__ float sel_v[KNB];
  __shared__ int s_widx;
  const int bm = blockIdx.x;
  const int b = bm >> 7;
  const float* P = pos + (size_t)b * NPTS * 3;
  const float sx = sp[bm * 3 + 0], sy = sp[bm * 3 + 1], sz = sp[bm * 3 + 2];
  const float nsp = sx * sx + sy * sy + sz * sz;
  const int t = threadIdx.x;
  for (int j = 0; j < 32; ++j) {
    const int i = j * 256 + t;
    const float qx = P[i * 3 + 0], qy = P[i * 3 + 1], qz = P[i * 3 + 2];
    const float npos = qx * qx + qy * qy + qz * qz;
    const float dt = sx * qx + sy * qy + sz * qz;
    float sq = (nsp + npos) - 2.0f * dt;  // matches ||a||^2+||b||^2-2ab order
    sq = fmaxf(sq, 0.0f);
    sqv[i] = sq;
  }
  __syncthreads();
  // per-thread local min key over its 32-element column
  {
    unsigned long long k0 = ~0ULL;
    for (int j = 0; j < 32; ++j) {
      const int i = j * 256 + t;
      const unsigned long long key =
          ((unsigned long long)__float_as_uint(sqv[i]) << 32) | (unsigned int)i;
      if (key < k0) k0 = key;
    }
    cand[t] = k0;
  }
  __syncthreads();
  for (int round = 0; round < KNB; ++round) {
    unsigned long long k0 = cand[t];
    for (int s = 1; s < 64; s <<= 1) {
      const unsigned long long o = shfl_xor_u64(k0, s);
      if (o < k0) k0 = o;
    }
    if ((t & 63) == 0) wkey[t >> 6] = k0;
    __syncthreads();
    if (t == 0) {
      unsigned long long B = wkey[0];
      for (int w = 1; w < 4; ++w)
        if (wkey[w] < B) B = wkey[w];
      const int idx = (int)(B & 0xffffffffu);
      sel_i[round] = idx;
      sel_v[round] = __uint_as_float((unsigned int)(B >> 32));
      s_widx = idx;
      sqv[idx] = __uint_as_float(0x7f800000u);  // +inf: consumed
    }
    __syncthreads();
    const int owner = s_widx & 255;
    if ((t >> 6) == (owner >> 6)) {
      const int lane = t & 63;
      unsigned long long key = ~0ULL;
      if (lane < 32) {
        const int i = lane * 256 + owner;
        key = ((unsigned long long)__float_as_uint(sqv[i]) << 32) | (unsigned int)i;
      }
      for (int s = 1; s < 64; s <<= 1) {
        const unsigned long long o = shfl_xor_u64(key, s);
        if (o < key) key = o;
      }
      if (lane == 0) cand[owner] = key;
    }
    __syncthreads();
  }
  if (t < KNB) {
    const int i = sel_i[t];
    const float* X = xf + (size_t)b * NPTS * 3;
    const size_t base = ((size_t)bm * KNB + t) * 6;
    gf0[base + 0] = P[i * 3 + 0] - sx;
    gf0[base + 1] = P[i * 3 + 1] - sy;
    gf0[base + 2] = P[i * 3 + 2] - sz;
    gf0[base + 3] = X[i * 3 + 0];
    gf0[base + 4] = X[i * 3 + 1];
    gf0[base + 5] = X[i * 3 + 2];
    sqsel[(size_t)bm * KNB + t] = sel_v[t];
  }
}

// ---------------------------------------------------------------- stage-0 conv chain
// One block per (b, sample) 64x6 tile. Recomputes the conv chain to the target
// depth each pass (BN needs global stats between layers; FLOPs are tiny).
// MODE 1: y1 stats   MODE 2: y2 stats   MODE 3: y3 stats   MODE 4: masked max -> x1
// Stats partials are written [channel][block] (coalesced for p_stats).
template <int MODE>
__global__ __launch_bounds__(256) void chain_kernel(
    const float* __restrict__ gf0,
    const float* __restrict__ W0, const float* __restrict__ B0,
    const float* __restrict__ W1, const float* __restrict__ B1,
    const float* __restrict__ W2, const float* __restrict__ B2,
    const float* __restrict__ sc1, const float* __restrict__ sh1,
    const float* __restrict__ sc2, const float* __restrict__ sh2,
    const float* __restrict__ sc3, const float* __restrict__ sh3,
    const float* __restrict__ sqsel,
    float* __restrict__ psum, float* __restrict__ psq, float* __restrict__ x1) {
  __shared__ float tA[64 * 65];  // +1 pad: kills stride-64 bank conflicts on row reads
  __shared__ float tB[64 * 65];
  __shared__ float wbuf[64 * 64];
  __shared__ float in6[64 * 8];
  __shared__ float sqs[64];
  const int blk = blockIdx.x;
  const int t = threadIdx.x;
  {
    const float* G = gf0 + (size_t)blk * 64 * 6;
    for (int i = t; i < 384; i += 256) in6[(i / 6) * 8 + (i % 6)] = G[i];
    for (int i = t; i < 384; i += 256) wbuf[i] = W0[i];
    if (MODE == 4 && t < 64) sqs[t] = sqsel[(size_t)blk * 64 + t];
  }
  __syncthreads();
  const int r = t >> 2;
  const int c0 = (t & 3) * 16;
  float acc[16];
  // L1: 6 -> 64
#pragma unroll
  for (int j = 0; j < 16; ++j) acc[j] = B0[c0 + j];
  for (int cin = 0; cin < 6; ++cin) {
    const float a = in6[r * 8 + cin];
#pragma unroll
    for (int j = 0; j < 16; ++j) acc[j] = fmaf(a, wbuf[cin * 64 + c0 + j], acc[j]);
  }
  if (MODE == 1) {
#pragma unroll
    for (int j = 0; j < 16; ++j) tA[r * 65 + c0 + j] = acc[j];
    __syncthreads();
    if (t < 64) {
      float s = 0.f, q = 0.f;
      for (int r2 = 0; r2 < 64; ++r2) { const float v = tA[r2 * 65 + t]; s += v; q += v * v; }
      psum[(size_t)t * NBLK + blk] = s;
      psq[(size_t)t * NBLK + blk] = q;
    }
    return;
  }
#pragma unroll
  for (int j = 0; j < 16; ++j) {
    const int c = c0 + j;
    tA[r * 65 + c] = fmaxf(fmaf(acc[j], sc1[c], sh1[c]), 0.f);
  }
  __syncthreads();
  for (int i = t; i < 4096; i += 256) wbuf[i] = W1[i];
  __syncthreads();
  // L2: 64 -> 64
#pragma unroll
  for (int j = 0; j < 16; ++j) acc[j] = B1[c0 + j];
  for (int cin = 0; cin < 64; ++cin) {
    const float a = tA[r * 65 + cin];
    const float4* w4 = reinterpret_cast<const float4*>(&wbuf[cin * 64 + c0]);
#pragma unroll
    for (int k = 0; k < 4; ++k) {
      const float4 w = w4[k];
      acc[k * 4 + 0] = fmaf(a, w.x, acc[k * 4 + 0]);
      acc[k * 4 + 1] = fmaf(a, w.y, acc[k * 4 + 1]);
      acc[k * 4 + 2] = fmaf(a, w.z, acc[k * 4 + 2]);
      acc[k * 4 + 3] = fmaf(a, w.w, acc[k * 4 + 3]);
    }
  }
  if (MODE == 2) {
#pragma unroll
    for (int j = 0; j < 16; ++j) tB[r * 65 + c0 + j] = acc[j];
    __syncthreads();
    if (t < 64) {
      float s = 0.f, q = 0.f;
      for (int r2 = 0; r2 < 64; ++r2) { const float v = tB[r2 * 65 + t]; s += v; q += v * v; }
      psum[(size_t)t * NBLK + blk] = s;
      psq[(size_t)t * NBLK + blk] = q;
    }
    return;
  }
#pragma unroll
  for (int j = 0; j < 16; ++j) {
    const int c = c0 + j;
    tB[r * 65 + c] = fmaxf(fmaf(acc[j], sc2[c], sh2[c]), 0.f);
  }
  // L3: 64 -> 128, processed in channel halves (wbuf holds 64x64 weight half)
  for (int hc = 0; hc < 2; ++hc) {
    __syncthreads();
    for (int i = t; i < 4096; i += 256) {
      const int cin = i >> 6, cc = i & 63;
      wbuf[i] = W2[cin * 128 + hc * 64 + cc];
    }
    __syncthreads();
    float st_s = 0.f, st_q = 0.f, mx = -1e8f;
    for (int rh = 0; rh < 2; ++rh) {
      const int rr = rh * 32 + (t >> 3);
      const int cc0 = (t & 7) * 8;
      float a3[8];
#pragma unroll
      for (int j = 0; j < 8; ++j) a3[j] = B2[hc * 64 + cc0 + j];
      for (int cin = 0; cin < 64; ++cin) {
        const float a = tB[rr * 65 + cin];
        const float4* w4 = reinterpret_cast<const float4*>(&wbuf[cin * 64 + cc0]);
#pragma unroll
        for (int k = 0; k < 2; ++k) {
          const float4 w = w4[k];
          a3[k * 4 + 0] = fmaf(a, w.x, a3[k * 4 + 0]);
          a3[k * 4 + 1] = fmaf(a, w.y, a3[k * 4 + 1]);
          a3[k * 4 + 2] = fmaf(a, w.z, a3[k * 4 + 2]);
          a3[k * 4 + 3] = fmaf(a, w.w, a3[k * 4 + 3]);
        }
      }
      __syncthreads();
#pragma unroll
      for (int j = 0; j < 8; ++j) tA[(t >> 3) * 65 + cc0 + j] = a3[j];
      __syncthreads();
      if (t < 64) {
        if (MODE == 3) {
          for (int q2 = 0; q2 < 32; ++q2) { const float v = tA[q2 * 65 + t]; st_s += v; st_q += v * v; }
        } else {
          const float scv = sc3[hc * 64 + t], shv = sh3[hc * 64 + t];
          for (int q2 = 0; q2 < 32; ++q2) {
            const int kidx = rh * 32 + q2;
            const float y = tA[q2 * 65 + t];
            const float act = fmaxf(fmaf(y, scv, shv), 0.f);
            const float v = (sqs[kidx] <= 0.16f) ? act : -1e8f;
            mx = fmaxf(mx, v);
          }
        }
      }
      __syncthreads();
    }
    if (t < 64) {
      if (MODE == 3) {
        psum[(size_t)(hc * 64 + t) * NBLK + blk] = st_s;
        psq[(size_t)(hc * 64 + t) * NBLK + blk] = st_q;
      } else if (MODE == 4) {
        x1[(size_t)blk * 128 + hc * 64 + t] = mx;
      }
    }
  }
}

// Parallel deterministic stats reduce: one block per channel, coalesced reads,
// f64 LDS tree.
__global__ __launch_bounds__(256) void p_stats(const float* __restrict__ psum,
                                               const float* __restrict__ psq,
                                               float invN,
                                               const float* __restrict__ g,
                                               const float* __restrict__ be,
                                               float* __restrict__ sc,
                                               float* __restrict__ sh) {
  const int c = blockIdx.x;
  const int t = threadIdx.x;
  double s = 0.0, q = 0.0;
  for (int k = t; k < NBLK; k += 256) {
    s += (double)psum[(size_t)c * NBLK + k];
    q += (double)psq[(size_t)c * NBLK + k];
  }
  __shared__ double ss[256], qq[256];
  ss[t] = s;
  qq[t] = q;
  __syncthreads();
  for (int st = 128; st > 0; st >>= 1) {
    if (t < st) { ss[t] += ss[t + st]; qq[t] += qq[t + st]; }
    __syncthreads();
  }
  if (t == 0) {
    const double mean = ss[0] * (double)invN;
    double var = qq[0] * (double)invN - mean * mean;
    if (var < 0.0) var = 0.0;
    const float scl = (float)((double)g[c] / sqrt(var + 1e-5));
    sc[c] = scl;
    sh[c] = be[c] - (float)mean * scl;
  }
}

// ---------------------------------------------------------------- stage 1 (2048 rows)
__global__ __launch_bounds__(128) void s1_kernel(const float* __restrict__ sp,
                                                 const float* __restrict__ x1,
                                                 const float* __restrict__ W,
                                                 const float* __restrict__ bia,
                                                 float* __restrict__ y1) {
  __shared__ float row[132];
  const int rowid = blockIdx.x;
  const int t = threadIdx.x;
  if (t < 3) row[t] = sp[(size_t)rowid * 3 + t];
  row[3 + t] = x1[(size_t)rowid * 128 + t];
  __syncthreads();
  float acc = bia[t];
  for (int cin = 0; cin < 131; ++cin) acc = fmaf(row[cin], W[(size_t)cin * 128 + t], acc);
  y1[(size_t)rowid * 128 + t] = acc;
}

__global__ __launch_bounds__(128) void s2_kernel(const float* __restrict__ y1,
                                                 const float* __restrict__ sc, const float* __restrict__ sh,
                                                 const float* __restrict__ W, const float* __restrict__ bia,
                                                 float* __restrict__ y2) {
  __shared__ float row[128];
  const int rowid = blockIdx.x;
  const int t = threadIdx.x;
  row[t] = fmaxf(fmaf(y1[(size_t)rowid * 128 + t], sc[t], sh[t]), 0.f);
  __syncthreads();
  float acc = bia[t];
  for (int cin = 0; cin < 128; ++cin) acc = fmaf(row[cin], W[(size_t)cin * 128 + t], acc);
  y2[(size_t)rowid * 128 + t] = acc;
}

__global__ __launch_bounds__(256) void s3_kernel(const float* __restrict__ y2,
                                                 const float* __restrict__ sc, const float* __restrict__ sh,
                                                 const float* __restrict__ W, const float* __restrict__ bia,
                                                 float* __restrict__ y3) {
  __shared__ float row[128];
  const int rowid = blockIdx.x;
  const int t = threadIdx.x;
  if (t < 128) row[t] = fmaxf(fmaf(y2[(size_t)rowid * 128 + t], sc[t], sh[t]), 0.f);
  __syncthreads();
  for (int h = 0; h < 2; ++h) {
    const int c = h * 256 + t;
    float acc = bia[c];
    for (int cin = 0; cin < 128; ++cin) acc = fmaf(row[cin], W[(size_t)cin * 512 + c], acc);
    y3[(size_t)rowid * 512 + c] = acc;
  }
}

// Deterministic per-channel stats over rows (block per channel, tree reduce).
__global__ __launch_bounds__(256) void s_stats(const float* __restrict__ y, int C, int rows,
                                               const float* __restrict__ g, const float* __restrict__ be,
                                               float* __restrict__ sc, float* __restrict__ sh) {
  const int c = blockIdx.x;
  const int t = threadIdx.x;
  double s = 0.0, q = 0.0;
  for (int r2 = t; r2 < rows; r2 += 256) {
    const double v = (double)y[(size_t)r2 * C + c];
    s += v;
    q += v * v;
  }
  __shared__ double ss[256], qq[256];
  ss[t] = s;
  qq[t] = q;
  __syncthreads();
  for (int st = 128; st > 0; st >>= 1) {
    if (t < st) { ss[t] += ss[t + st]; qq[t] += qq[t + st]; }
    __syncthreads();
  }
  if (t == 0) {
    const double mean = ss[0] / rows;
    double var = qq[0] / rows - mean * mean;
    if (var < 0.0) var = 0.0;
    const float scl = (float)((double)g[c] / sqrt(var + 1e-5));
    sc[c] = scl;
    sh[c] = be[c] - (float)mean * scl;
  }
}

__global__ __launch_bounds__(256) void final_kernel(const float* __restrict__ y3,
                                                    const float* __restrict__ sc, const float* __restrict__ sh,
                                                    float* __restrict__ out) {
  const int gid = blockIdx.x * 256 + threadIdx.x;  // 8192 = 16 batches x 512 ch
  const int b = gid >> 9;
  const int c = gid & 511;
  const float scv = sc[c], shv = sh[c];
  float mx = -3.402823466e+38f;
  for (int m = 0; m < 128; ++m) {
    const float v = fmaxf(fmaf(y3[((size_t)(b * 128 + m)) * 512 + c], scv, shv), 0.f);
    mx = fmaxf(mx, v);
  }
  out[gid] = mx;
  if (gid < 48) out[8192 + gid] = 0.f;  // pos_out zeros
}

extern "C" void kernel_launch(void* const* d_in, const int* in_sizes, int n_in,
                              void* d_out, int out_size, void* d_ws, size_t ws_size,
                              hipStream_t stream) {
  const float* x    = (const float*)d_in[0];
  const float* pos  = (const float*)d_in[1];
  const float* W00  = (const float*)d_in[2];
  const float* b00  = (const float*)d_in[3];
  const float* g00  = (const float*)d_in[4];
  const float* be00 = (const float*)d_in[5];
  const float* W01  = (const float*)d_in[6];
  const float* b01  = (const float*)d_in[7];
  const float* g01  = (const float*)d_in[8];
  const float* be01 = (const float*)d_in[9];
  const float* W02  = (const float*)d_in[10];
  const float* b02  = (const float*)d_in[11];
  const float* g02  = (const float*)d_in[12];
  const float* be02 = (const float*)d_in[13];
  const float* W10  = (const float*)d_in[14];
  const float* b10  = (const float*)d_in[15];
  const float* g10  = (const float*)d_in[16];
  const float* be10 = (const float*)d_in[17];
  const float* W11  = (const float*)d_in[18];
  const float* b11  = (const float*)d_in[19];
  const float* g11  = (const float*)d_in[20];
  const float* be11 = (const float*)d_in[21];
  const float* W12  = (const float*)d_in[22];
  const float* b12  = (const float*)d_in[23];
  const float* g12  = (const float*)d_in[24];
  const float* be12 = (const float*)d_in[25];

  float* w = (float*)d_ws;
  float* sp    = w;                  // 16*128*3          = 6144
  float* gf0   = sp + 6144;          // 16*128*64*6       = 786432
  float* sqsel = gf0 + 786432;       // 16*128*64         = 131072
  float* x1    = sqsel + 131072;     // 16*128*128        = 262144
  float* parts = x1 + 262144;        // 128*2048*2        = 524288
  float* psum  = parts;              // [c][blk]
  float* psq   = parts + 128 * NBLK; // [c][blk]
  float* st    = parts + 524288;     // stats area        = 2048
  float* sc1 = st + 0,    *sh1 = st + 64;
  float* sc2 = st + 128,  *sh2 = st + 192;
  float* sc3 = st + 256,  *sh3 = st + 384;
  float* t1sc = st + 512, *t1sh = st + 640;
  float* t2sc = st + 768, *t2sh = st + 896;
  float* t3sc = st + 1024, *t3sh = st + 1536;
  float* y1s = st + 2048;            // 2048*128 = 262144
  float* y2s = y1s + 262144;         // 2048*128 = 262144
  float* y3s = y2s + 262144;         // 2048*512 = 1048576
  // total ws use: ~3.29M floats (~13.2 MB)

  fps_kernel<<<BATCH, 1024, 0, stream>>>(pos, sp);
  knn_kernel<<<BATCH * MS, 256, 0, stream>>>(pos, x, sp, gf0, sqsel);

  const float invN0 = 1.0f / (float)(NBLK * KNB);  // 1/131072
  chain_kernel<1><<<NBLK, 256, 0, stream>>>(gf0, W00, b00, W01, b01, W02, b02,
                                            sc1, sh1, sc2, sh2, sc3, sh3, sqsel, psum, psq, x1);
  p_stats<<<64, 256, 0, stream>>>(psum, psq, invN0, g00, be00, sc1, sh1);
  chain_kernel<2><<<NBLK, 256, 0, stream>>>(gf0, W00, b00, W01, b01, W02, b02,
                                            sc1, sh1, sc2, sh2, sc3, sh3, sqsel, psum, psq, x1);
  p_stats<<<64, 256, 0, stream>>>(psum, psq, invN0, g01, be01, sc2, sh2);
  chain_kernel<3><<<NBLK, 256, 0, stream>>>(gf0, W00, b00, W01, b01, W02, b02,
                                            sc1, sh1, sc2, sh2, sc3, sh3, sqsel, psum, psq, x1);
  p_stats<<<128, 256, 0, stream>>>(psum, psq, invN0, g02, be02, sc3, sh3);
  chain_kernel<4><<<NBLK, 256, 0, stream>>>(gf0, W00, b00, W01, b01, W02, b02,
                                            sc1, sh1, sc2, sh2, sc3, sh3, sqsel, psum, psq, x1);

  s1_kernel<<<NBLK, 128, 0, stream>>>(sp, x1, W10, b10, y1s);
  s_stats<<<128, 256, 0, stream>>>(y1s, 128, NBLK, g10, be10, t1sc, t1sh);
  s2_kernel<<<NBLK, 128, 0, stream>>>(y1s, t1sc, t1sh, W11, b11, y2s);
  s_stats<<<128, 256, 0, stream>>>(y2s, 128, NBLK, g11, be11, t2sc, t2sh);
  s3_kernel<<<NBLK, 256, 0, stream>>>(y2s, t2sc, t2sh, W12, b12, y3s);
  s_stats<<<512, 256, 0, stream>>>(y3s, 512, NBLK, g12, be12, t3sc, t3sh);
  final_kernel<<<32, 256, 0, stream>>>(y3s, t3sc, t3sh, (float*)d_out);
}

// Round 4
// 577.589 us; speedup vs baseline: 3.9413x; 1.0803x over previous
//
#include <hip/hip_runtime.h>
#include <cstdint>
#include <cstddef>

#define NPTS 8192
#define BATCH 16
#define MS 128
#define KNB 64
#define NBLK (BATCH * MS)   // 2048

static __device__ __forceinline__ unsigned long long shfl_xor_u64(unsigned long long v, int m) {
  unsigned int lo = (unsigned int)v, hi = (unsigned int)(v >> 32);
  lo = (unsigned int)__shfl_xor((int)lo, m);
  hi = (unsigned int)__shfl_xor((int)hi, m);
  return ((unsigned long long)hi << 32) | lo;
}

// ---------------------------------------------------------------- FPS
// One block per batch. Points in registers for the distance loop; LDS copy for
// coordinate broadcast. Hot loop is value-only (10 VALU ops/pt); argmax index
// is recovered post-hoc: threads whose wave/block max matches exactly rescan
// their 8 md[] and atomicMin the smallest flat index into sidx[it] (LDS,
// per-iteration slot; order-independent => deterministic; ties -> smallest
// index == jnp.argmax first-occurrence). Distance arithmetic bit-identical to
// the verified version => identical selections.
__global__ __launch_bounds__(1024) void fps_kernel(const float* __restrict__ pos,
                                                   float* __restrict__ sp) {
#pragma clang fp contract(off)
  __shared__ float px[NPTS], py[NPTS], pz[NPTS];
  __shared__ float wmax[32];  // [parity][wave]
  __shared__ int sidx[MS];
  const int b = blockIdx.x;
  const float* P = pos + (size_t)b * NPTS * 3;
  const int t = threadIdx.x;
  const int wave = t >> 6;
  const int lane = t & 63;
  float X[8], Y[8], Z[8], md[8];
#pragma unroll
  for (int j = 0; j < 8; ++j) {
    const int i = j * 1024 + t;
    const float a = P[i * 3 + 0];
    const float c = P[i * 3 + 1];
    const float d = P[i * 3 + 2];
    px[i] = a; py[i] = c; pz[i] = d;
    X[j] = a; Y[j] = c; Z[j] = d;
    md[j] = 1e10f;
  }
  if (t < MS) sidx[t] = 0x7fffffff;
  float lx = P[0], ly = P[1], lz = P[2];
  __syncthreads();
  for (int it = 0; it < MS; ++it) {
    if (t == 0) {
      sp[((size_t)b * MS + it) * 3 + 0] = lx;
      sp[((size_t)b * MS + it) * 3 + 1] = ly;
      sp[((size_t)b * MS + it) * 3 + 2] = lz;
    }
    float bv = -1.0f;
#pragma unroll
    for (int j = 0; j < 8; ++j) {
      const float dx = X[j] - lx;
      const float dy = Y[j] - ly;
      const float dz = Z[j] - lz;
      const float d = dx * dx + dy * dy + dz * dz;  // contract off: same order as ref
      float m = md[j];
      m = (d < m) ? d : m;
      md[j] = m;
      bv = (m > bv) ? m : bv;
    }
    // wave max (f32 butterfly)
    float wv = bv;
    for (int s = 1; s < 64; s <<= 1) {
      const float o = __shfl_xor(wv, s);
      wv = (o > wv) ? o : wv;
    }
    const int par = (it & 1) * 16;
    if (lane == 0) wmax[par + wave] = wv;
    __syncthreads();
    // block max: all lanes fold the 16 wave maxima
    float M = wmax[par + (lane & 15)];
    for (int s = 1; s < 16; s <<= 1) {
      const float o = __shfl_xor(M, s);
      M = (o > M) ? o : M;
    }
    // winner threads resolve smallest flat index
    if (bv == M) {
      int best = 0x7fffffff;
#pragma unroll
      for (int j = 7; j >= 0; --j)
        if (md[j] == M) best = j * 1024 + t;
      atomicMin(&sidx[it], best);
    }
    __syncthreads();
    const int s = sidx[it];
    lx = px[s];
    ly = py[s];
    lz = pz[s];
  }
}

// ---------------------------------------------------------------- kNN top-64
// Tournament selection. Key = (float_bits << 32) | idx packs (value, index)
// lexicographic order (monotone for non-negative floats; ties -> smaller idx),
// which is exactly lax.top_k's stable selection set. Per round only the
// winner's owner column (32 elems, one wave) is rescanned.
__global__ __launch_bounds__(256) void knn_kernel(const float* __restrict__ pos,
                                                  const float* __restrict__ xf,
                                                  const float* __restrict__ sp,
                                                  float* __restrict__ gf0,
                                                  float* __restrict__ sqsel) {
#pragma clang fp contract(off)
  __shared__ float sqv[NPTS];
  __shared__ unsigned long long cand[256];
  __shared__ unsigned long long wkey[4];
  __shared__ int sel_i[KNB];
  __shared__ float sel_v[KNB];
  __shared__ int s_widx;
  const int bm = blockIdx.x;
  const int b = bm >> 7;
  const float* P = pos + (size_t)b * NPTS * 3;
  const float sx = sp[bm * 3 + 0], sy = sp[bm * 3 + 1], sz = sp[bm * 3 + 2];
  const float nsp = sx * sx + sy * sy + sz * sz;
  const int t = threadIdx.x;
  for (int j = 0; j < 32; ++j) {
    const int i = j * 256 + t;
    const float qx = P[i * 3 + 0], qy = P[i * 3 + 1], qz = P[i * 3 + 2];
    const float npos = qx * qx + qy * qy + qz * qz;
    const float dt = sx * qx + sy * qy + sz * qz;
    float sq = (nsp + npos) - 2.0f * dt;  // matches ||a||^2+||b||^2-2ab order
    sq = fmaxf(sq, 0.0f);
    sqv[i] = sq;
  }
  __syncthreads();
  // per-thread local min key over its 32-element column
  {
    unsigned long long k0 = ~0ULL;
    for (int j = 0; j < 32; ++j) {
      const int i = j * 256 + t;
      const unsigned long long key =
          ((unsigned long long)__float_as_uint(sqv[i]) << 32) | (unsigned int)i;
      if (key < k0) k0 = key;
    }
    cand[t] = k0;
  }
  __syncthreads();
  for (int round = 0; round < KNB; ++round) {
    unsigned long long k0 = cand[t];
    for (int s = 1; s < 64; s <<= 1) {
      const unsigned long long o = shfl_xor_u64(k0, s);
      if (o < k0) k0 = o;
    }
    if ((t & 63) == 0) wkey[t >> 6] = k0;
    __syncthreads();
    if (t == 0) {
      unsigned long long B = wkey[0];
      for (int w = 1; w < 4; ++w)
        if (wkey[w] < B) B = wkey[w];
      const int idx = (int)(B & 0xffffffffu);
      sel_i[round] = idx;
      sel_v[round] = __uint_as_float((unsigned int)(B >> 32));
      s_widx = idx;
      sqv[idx] = __uint_as_float(0x7f800000u);  // +inf: consumed
    }
    __syncthreads();
    const int owner = s_widx & 255;
    if ((t >> 6) == (owner >> 6)) {
      const int lane = t & 63;
      unsigned long long key = ~0ULL;
      if (lane < 32) {
        const int i = lane * 256 + owner;
        key = ((unsigned long long)__float_as_uint(sqv[i]) << 32) | (unsigned int)i;
      }
      for (int s = 1; s < 64; s <<= 1) {
        const unsigned long long o = shfl_xor_u64(key, s);
        if (o < key) key = o;
      }
      if (lane == 0) cand[owner] = key;
    }
    __syncthreads();
  }
  if (t < KNB) {
    const int i = sel_i[t];
    const float* X = xf + (size_t)b * NPTS * 3;
    const size_t base = ((size_t)bm * KNB + t) * 6;
    gf0[base + 0] = P[i * 3 + 0] - sx;
    gf0[base + 1] = P[i * 3 + 1] - sy;
    gf0[base + 2] = P[i * 3 + 2] - sz;
    gf0[base + 3] = X[i * 3 + 0];
    gf0[base + 4] = X[i * 3 + 1];
    gf0[base + 5] = X[i * 3 + 2];
    sqsel[(size_t)bm * KNB + t] = sel_v[t];
  }
}

// ---------------------------------------------------------------- stage-0 conv chain
// One block per (b, sample) 64x6 tile. Recomputes the conv chain to the target
// depth each pass (BN needs global stats between layers; FLOPs are tiny).
// MODE 1: y1 stats   MODE 2: y2 stats   MODE 3: y3 stats   MODE 4: masked max -> x1
// Stats partials are written [channel][block] (coalesced for p_stats).
template <int MODE>
__global__ __launch_bounds__(256) void chain_kernel(
    const float* __restrict__ gf0,
    const float* __restrict__ W0, const float* __restrict__ B0,
    const float* __restrict__ W1, const float* __restrict__ B1,
    const float* __restrict__ W2, const float* __restrict__ B2,
    const float* __restrict__ sc1, const float* __restrict__ sh1,
    const float* __restrict__ sc2, const float* __restrict__ sh2,
    const float* __restrict__ sc3, const float* __restrict__ sh3,
    const float* __restrict__ sqsel,
    float* __restrict__ psum, float* __restrict__ psq, float* __restrict__ x1) {
  __shared__ float tA[64 * 65];  // +1 pad: kills stride-64 bank conflicts on row reads
  __shared__ float tB[64 * 65];
  __shared__ float wbuf[64 * 64];
  __shared__ float in6[64 * 8];
  __shared__ float sqs[64];
  const int blk = blockIdx.x;
  const int t = threadIdx.x;
  {
    const float* G = gf0 + (size_t)blk * 64 * 6;
    for (int i = t; i < 384; i += 256) in6[(i / 6) * 8 + (i % 6)] = G[i];
    for (int i = t; i < 384; i += 256) wbuf[i] = W0[i];
    if (MODE == 4 && t < 64) sqs[t] = sqsel[(size_t)blk * 64 + t];
  }
  __syncthreads();
  const int r = t >> 2;
  const int c0 = (t & 3) * 16;
  float acc[16];
  // L1: 6 -> 64
#pragma unroll
  for (int j = 0; j < 16; ++j) acc[j] = B0[c0 + j];
  for (int cin = 0; cin < 6; ++cin) {
    const float a = in6[r * 8 + cin];
#pragma unroll
    for (int j = 0; j < 16; ++j) acc[j] = fmaf(a, wbuf[cin * 64 + c0 + j], acc[j]);
  }
  if (MODE == 1) {
#pragma unroll
    for (int j = 0; j < 16; ++j) tA[r * 65 + c0 + j] = acc[j];
    __syncthreads();
    if (t < 64) {
      float s = 0.f, q = 0.f;
      for (int r2 = 0; r2 < 64; ++r2) { const float v = tA[r2 * 65 + t]; s += v; q += v * v; }
      psum[(size_t)t * NBLK + blk] = s;
      psq[(size_t)t * NBLK + blk] = q;
    }
    return;
  }
#pragma unroll
  for (int j = 0; j < 16; ++j) {
    const int c = c0 + j;
    tA[r * 65 + c] = fmaxf(fmaf(acc[j], sc1[c], sh1[c]), 0.f);
  }
  __syncthreads();
  for (int i = t; i < 4096; i += 256) wbuf[i] = W1[i];
  __syncthreads();
  // L2: 64 -> 64
#pragma unroll
  for (int j = 0; j < 16; ++j) acc[j] = B1[c0 + j];
  for (int cin = 0; cin < 64; ++cin) {
    const float a = tA[r * 65 + cin];
    const float4* w4 = reinterpret_cast<const float4*>(&wbuf[cin * 64 + c0]);
#pragma unroll
    for (int k = 0; k < 4; ++k) {
      const float4 w = w4[k];
      acc[k * 4 + 0] = fmaf(a, w.x, acc[k * 4 + 0]);
      acc[k * 4 + 1] = fmaf(a, w.y, acc[k * 4 + 1]);
      acc[k * 4 + 2] = fmaf(a, w.z, acc[k * 4 + 2]);
      acc[k * 4 + 3] = fmaf(a, w.w, acc[k * 4 + 3]);
    }
  }
  if (MODE == 2) {
#pragma unroll
    for (int j = 0; j < 16; ++j) tB[r * 65 + c0 + j] = acc[j];
    __syncthreads();
    if (t < 64) {
      float s = 0.f, q = 0.f;
      for (int r2 = 0; r2 < 64; ++r2) { const float v = tB[r2 * 65 + t]; s += v; q += v * v; }
      psum[(size_t)t * NBLK + blk] = s;
      psq[(size_t)t * NBLK + blk] = q;
    }
    return;
  }
#pragma unroll
  for (int j = 0; j < 16; ++j) {
    const int c = c0 + j;
    tB[r * 65 + c] = fmaxf(fmaf(acc[j], sc2[c], sh2[c]), 0.f);
  }
  // L3: 64 -> 128, processed in channel halves (wbuf holds 64x64 weight half)
  for (int hc = 0; hc < 2; ++hc) {
    __syncthreads();
    for (int i = t; i < 4096; i += 256) {
      const int cin = i >> 6, cc = i & 63;
      wbuf[i] = W2[cin * 128 + hc * 64 + cc];
    }
    __syncthreads();
    float st_s = 0.f, st_q = 0.f, mx = -1e8f;
    for (int rh = 0; rh < 2; ++rh) {
      const int rr = rh * 32 + (t >> 3);
      const int cc0 = (t & 7) * 8;
      float a3[8];
#pragma unroll
      for (int j = 0; j < 8; ++j) a3[j] = B2[hc * 64 + cc0 + j];
      for (int cin = 0; cin < 64; ++cin) {
        const float a = tB[rr * 65 + cin];
        const float4* w4 = reinterpret_cast<const float4*>(&wbuf[cin * 64 + cc0]);
#pragma unroll
        for (int k = 0; k < 2; ++k) {
          const float4 w = w4[k];
          a3[k * 4 + 0] = fmaf(a, w.x, a3[k * 4 + 0]);
          a3[k * 4 + 1] = fmaf(a, w.y, a3[k * 4 + 1]);
          a3[k * 4 + 2] = fmaf(a, w.z, a3[k * 4 + 2]);
          a3[k * 4 + 3] = fmaf(a, w.w, a3[k * 4 + 3]);
        }
      }
      __syncthreads();
#pragma unroll
      for (int j = 0; j < 8; ++j) tA[(t >> 3) * 65 + cc0 + j] = a3[j];
      __syncthreads();
      if (t < 64) {
        if (MODE == 3) {
          for (int q2 = 0; q2 < 32; ++q2) { const float v = tA[q2 * 65 + t]; st_s += v; st_q += v * v; }
        } else {
          const float scv = sc3[hc * 64 + t], shv = sh3[hc * 64 + t];
          for (int q2 = 0; q2 < 32; ++q2) {
            const int kidx = rh * 32 + q2;
            const float y = tA[q2 * 65 + t];
            const float act = fmaxf(fmaf(y, scv, shv), 0.f);
            const float v = (sqs[kidx] <= 0.16f) ? act : -1e8f;
            mx = fmaxf(mx, v);
          }
        }
      }
      __syncthreads();
    }
    if (t < 64) {
      if (MODE == 3) {
        psum[(size_t)(hc * 64 + t) * NBLK + blk] = st_s;
        psq[(size_t)(hc * 64 + t) * NBLK + blk] = st_q;
      } else if (MODE == 4) {
        x1[(size_t)blk * 128 + hc * 64 + t] = mx;
      }
    }
  }
}

// Parallel deterministic stats reduce: one block per channel, coalesced reads,
// f64 LDS tree.
__global__ __launch_bounds__(256) void p_stats(const float* __restrict__ psum,
                                               const float* __restrict__ psq,
                                               float invN,
                                               const float* __restrict__ g,
                                               const float* __restrict__ be,
                                               float* __restrict__ sc,
                                               float* __restrict__ sh) {
  const int c = blockIdx.x;
  const int t = threadIdx.x;
  double s = 0.0, q = 0.0;
  for (int k = t; k < NBLK; k += 256) {
    s += (double)psum[(size_t)c * NBLK + k];
    q += (double)psq[(size_t)c * NBLK + k];
  }
  __shared__ double ss[256], qq[256];
  ss[t] = s;
  qq[t] = q;
  __syncthreads();
  for (int st = 128; st > 0; st >>= 1) {
    if (t < st) { ss[t] += ss[t + st]; qq[t] += qq[t + st]; }
    __syncthreads();
  }
  if (t == 0) {
    const double mean = ss[0] * (double)invN;
    double var = qq[0] * (double)invN - mean * mean;
    if (var < 0.0) var = 0.0;
    const float scl = (float)((double)g[c] / sqrt(var + 1e-5));
    sc[c] = scl;
    sh[c] = be[c] - (float)mean * scl;
  }
}

// ---------------------------------------------------------------- stage 1 (2048 rows)
__global__ __launch_bounds__(128) void s1_kernel(const float* __restrict__ sp,
                                                 const float* __restrict__ x1,
                                                 const float* __restrict__ W,
                                                 const float* __restrict__ bia,
                                                 float* __restrict__ y1) {
  __shared__ float row[132];
  const int rowid = blockIdx.x;
  const int t = threadIdx.x;
  if (t < 3) row[t] = sp[(size_t)rowid * 3 + t];
  row[3 + t] = x1[(size_t)rowid * 128 + t];
  __syncthreads();
  float acc = bia[t];
  for (int cin = 0; cin < 131; ++cin) acc = fmaf(row[cin], W[(size_t)cin * 128 + t], acc);
  y1[(size_t)rowid * 128 + t] = acc;
}

__global__ __launch_bounds__(128) void s2_kernel(const float* __restrict__ y1,
                                                 const float* __restrict__ sc, const float* __restrict__ sh,
                                                 const float* __restrict__ W, const float* __restrict__ bia,
                                                 float* __restrict__ y2) {
  __shared__ float row[128];
  const int rowid = blockIdx.x;
  const int t = threadIdx.x;
  row[t] = fmaxf(fmaf(y1[(size_t)rowid * 128 + t], sc[t], sh[t]), 0.f);
  __syncthreads();
  float acc = bia[t];
  for (int cin = 0; cin < 128; ++cin) acc = fmaf(row[cin], W[(size_t)cin * 128 + t], acc);
  y2[(size_t)rowid * 128 + t] = acc;
}

__global__ __launch_bounds__(256) void s3_kernel(const float* __restrict__ y2,
                                                 const float* __restrict__ sc, const float* __restrict__ sh,
                                                 const float* __restrict__ W, const float* __restrict__ bia,
                                                 float* __restrict__ y3) {
  __shared__ float row[128];
  const int rowid = blockIdx.x;
  const int t = threadIdx.x;
  if (t < 128) row[t] = fmaxf(fmaf(y2[(size_t)rowid * 128 + t], sc[t], sh[t]), 0.f);
  __syncthreads();
  for (int h = 0; h < 2; ++h) {
    const int c = h * 256 + t;
    float acc = bia[c];
    for (int cin = 0; cin < 128; ++cin) acc = fmaf(row[cin], W[(size_t)cin * 512 + c], acc);
    y3[(size_t)rowid * 512 + c] = acc;
  }
}

// Deterministic per-channel stats over rows (block per channel, tree reduce).
__global__ __launch_bounds__(256) void s_stats(const float* __restrict__ y, int C, int rows,
                                               const float* __restrict__ g, const float* __restrict__ be,
                                               float* __restrict__ sc, float* __restrict__ sh) {
  const int c = blockIdx.x;
  const int t = threadIdx.x;
  double s = 0.0, q = 0.0;
  for (int r2 = t; r2 < rows; r2 += 256) {
    const double v = (double)y[(size_t)r2 * C + c];
    s += v;
    q += v * v;
  }
  __shared__ double ss[256], qq[256];
  ss[t] = s;
  qq[t] = q;
  __syncthreads();
  for (int st = 128; st > 0; st >>= 1) {
    if (t < st) { ss[t] += ss[t + st]; qq[t] += qq[t + st]; }
    __syncthreads();
  }
  if (t == 0) {
    const double mean = ss[0] / rows;
    double var = qq[0] / rows - mean * mean;
    if (var < 0.0) var = 0.0;
    const float scl = (float)((double)g[c] / sqrt(var + 1e-5));
    sc[c] = scl;
    sh[c] = be[c] - (float)mean * scl;
  }
}

__global__ __launch_bounds__(256) void final_kernel(const float* __restrict__ y3,
                                                    const float* __restrict__ sc, const float* __restrict__ sh,
                                                    float* __restrict__ out) {
  const int gid = blockIdx.x * 256 + threadIdx.x;  // 8192 = 16 batches x 512 ch
  const int b = gid >> 9;
  const int c = gid & 511;
  const float scv = sc[c], shv = sh[c];
  float mx = -3.402823466e+38f;
  for (int m = 0; m < 128; ++m) {
    const float v = fmaxf(fmaf(y3[((size_t)(b * 128 + m)) * 512 + c], scv, shv), 0.f);
    mx = fmaxf(mx, v);
  }
  out[gid] = mx;
  if (gid < 48) out[8192 + gid] = 0.f;  // pos_out zeros
}

extern "C" void kernel_launch(void* const* d_in, const int* in_sizes, int n_in,
                              void* d_out, int out_size, void* d_ws, size_t ws_size,
                              hipStream_t stream) {
  const float* x    = (const float*)d_in[0];
  const float* pos  = (const float*)d_in[1];
  const float* W00  = (const float*)d_in[2];
  const float* b00  = (const float*)d_in[3];
  const float* g00  = (const float*)d_in[4];
  const float* be00 = (const float*)d_in[5];
  const float* W01  = (const float*)d_in[6];
  const float* b01  = (const float*)d_in[7];
  const float* g01  = (const float*)d_in[8];
  const float* be01 = (const float*)d_in[9];
  const float* W02  = (const float*)d_in[10];
  const float* b02  = (const float*)d_in[11];
  const float* g02  = (const float*)d_in[12];
  const float* be02 = (const float*)d_in[13];
  const float* W10  = (const float*)d_in[14];
  const float* b10  = (const float*)d_in[15];
  const float* g10  = (const float*)d_in[16];
  const float* be10 = (const float*)d_in[17];
  const float* W11  = (const float*)d_in[18];
  const float* b11  = (const float*)d_in[19];
  const float* g11  = (const float*)d_in[20];
  const float* be11 = (const float*)d_in[21];
  const float* W12  = (const float*)d_in[22];
  const float* b12  = (const float*)d_in[23];
  const float* g12  = (const float*)d_in[24];
  const float* be12 = (const float*)d_in[25];

  float* w = (float*)d_ws;
  float* sp    = w;                  // 16*128*3          = 6144
  float* gf0   = sp + 6144;          // 16*128*64*6       = 786432
  float* sqsel = gf0 + 786432;       // 16*128*64         = 131072
  float* x1    = sqsel + 131072;     // 16*128*128        = 262144
  float* parts = x1 + 262144;        // 128*2048*2        = 524288
  float* psum  = parts;              // [c][blk]
  float* psq   = parts + 128 * NBLK; // [c][blk]
  float* st    = parts + 524288;     // stats area        = 2048
  float* sc1 = st + 0,    *sh1 = st + 64;
  float* sc2 = st + 128,  *sh2 = st + 192;
  float* sc3 = st + 256,  *sh3 = st + 384;
  float* t1sc = st + 512, *t1sh = st + 640;
  float* t2sc = st + 768, *t2sh = st + 896;
  float* t3sc = st + 1024, *t3sh = st + 1536;
  float* y1s = st + 2048;            // 2048*128 = 262144
  float* y2s = y1s + 262144;         // 2048*128 = 262144
  float* y3s = y2s + 262144;         // 2048*512 = 1048576
  // total ws use: ~3.29M floats (~13.2 MB)

  fps_kernel<<<BATCH, 1024, 0, stream>>>(pos, sp);
  knn_kernel<<<BATCH * MS, 256, 0, stream>>>(pos, x, sp, gf0, sqsel);

  const float invN0 = 1.0f / (float)(NBLK * KNB);  // 1/131072
  chain_kernel<1><<<NBLK, 256, 0, stream>>>(gf0, W00, b00, W01, b01, W02, b02,
                                            sc1, sh1, sc2, sh2, sc3, sh3, sqsel, psum, psq, x1);
  p_stats<<<64, 256, 0, stream>>>(psum, psq, invN0, g00, be00, sc1, sh1);
  chain_kernel<2><<<NBLK, 256, 0, stream>>>(gf0, W00, b00, W01, b01, W02, b02,
                                            sc1, sh1, sc2, sh2, sc3, sh3, sqsel, psum, psq, x1);
  p_stats<<<64, 256, 0, stream>>>(psum, psq, invN0, g01, be01, sc2, sh2);
  chain_kernel<3><<<NBLK, 256, 0, stream>>>(gf0, W00, b00, W01, b01, W02, b02,
                                            sc1, sh1, sc2, sh2, sc3, sh3, sqsel, psum, psq, x1);
  p_stats<<<128, 256, 0, stream>>>(psum, psq, invN0, g02, be02, sc3, sh3);
  chain_kernel<4><<<NBLK, 256, 0, stream>>>(gf0, W00, b00, W01, b01, W02, b02,
                                            sc1, sh1, sc2, sh2, sc3, sh3, sqsel, psum, psq, x1);

  s1_kernel<<<NBLK, 128, 0, stream>>>(sp, x1, W10, b10, y1s);
  s_stats<<<128, 256, 0, stream>>>(y1s, 128, NBLK, g10, be10, t1sc, t1sh);
  s2_kernel<<<NBLK, 128, 0, stream>>>(y1s, t1sc, t1sh, W11, b11, y2s);
  s_stats<<<128, 256, 0, stream>>>(y2s, 128, NBLK, g11, be11, t2sc, t2sh);
  s3_kernel<<<NBLK, 256, 0, stream>>>(y2s, t2sc, t2sh, W12, b12, y3s);
  s_stats<<<512, 256, 0, stream>>>(y3s, 512, NBLK, g12, be12, t3sc, t3sh);
  final_kernel<<<32, 256, 0, stream>>>(y3s, t3sc, t3sh, (float*)d_out);
}

// Round 5
// 568.945 us; speedup vs baseline: 4.0012x; 1.0152x over previous
//
#include <hip/hip_runtime.h>
#include <cstdint>
#include <cstddef>

#define NPTS 8192
#define BATCH 16
#define MS 128
#define KNB 64
#define NBLK (BATCH * MS)   // 2048

static __device__ __forceinline__ unsigned long long shfl_xor_u64(unsigned long long v, int m) {
  unsigned int lo = (unsigned int)v, hi = (unsigned int)(v >> 32);
  lo = (unsigned int)__shfl_xor((int)lo, m);
  hi = (unsigned int)__shfl_xor((int)hi, m);
  return ((unsigned long long)hi << 32) | lo;
}

// ---------------------------------------------------------------- FPS
// One block per batch, 512 threads x 16 pts. Hot loop is value-only and
// bit-identical to the verified version. Winner index resolved IN-WAVE
// (f32 max butterfly -> ties rescan md[] for smallest flat idx -> u32 min
// butterfly); each wave publishes one packed u64 key (bits(wv)<<32)|~idx to a
// parity-double-buffered 8-slot LDS array. ONE barrier per iteration; all
// threads fold 8 keys (3-step u64 max butterfly: value ties -> smaller idx ==
// first occurrence) and broadcast-read winner coords from the LDS point copy.
__global__ __launch_bounds__(512) void fps_kernel(const float* __restrict__ pos,
                                                  float* __restrict__ sp) {
#pragma clang fp contract(off)
  __shared__ float px[NPTS], py[NPTS], pz[NPTS];
  __shared__ unsigned long long wkey[16];  // [parity][8 waves]
  const int b = blockIdx.x;
  const float* P = pos + (size_t)b * NPTS * 3;
  const int t = threadIdx.x;
  const int wave = t >> 6;
  const int lane = t & 63;
  float X[16], Y[16], Z[16], md[16];
#pragma unroll
  for (int j = 0; j < 16; ++j) {
    const int i = j * 512 + t;
    const float a = P[i * 3 + 0];
    const float c = P[i * 3 + 1];
    const float d = P[i * 3 + 2];
    px[i] = a; py[i] = c; pz[i] = d;
    X[j] = a; Y[j] = c; Z[j] = d;
    md[j] = 1e10f;
  }
  float lx = P[0], ly = P[1], lz = P[2];
  __syncthreads();
  for (int it = 0; it < MS; ++it) {
    if (t == 0) {
      sp[((size_t)b * MS + it) * 3 + 0] = lx;
      sp[((size_t)b * MS + it) * 3 + 1] = ly;
      sp[((size_t)b * MS + it) * 3 + 2] = lz;
    }
    float bv = -1.0f;
#pragma unroll
    for (int j = 0; j < 16; ++j) {
      const float dx = X[j] - lx;
      const float dy = Y[j] - ly;
      const float dz = Z[j] - lz;
      const float d = dx * dx + dy * dy + dz * dz;  // contract off: same order as ref
      float m = md[j];
      m = (d < m) ? d : m;
      md[j] = m;
      bv = (m > bv) ? m : bv;
    }
    // wave value max (f32 butterfly)
    float wv = bv;
    for (int s = 1; s < 64; s <<= 1) {
      const float o = __shfl_xor(wv, s);
      wv = (o > wv) ? o : wv;
    }
    // in-wave winner index: smallest flat idx among ties of wv
    unsigned int best = 0xffffffffu;
    if (bv == wv) {
#pragma unroll
      for (int j = 15; j >= 0; --j)
        if (md[j] == wv) best = (unsigned int)(j * 512 + t);
    }
    for (int s = 1; s < 64; s <<= 1) {
      const unsigned int o = (unsigned int)__shfl_xor((int)best, s);
      best = (o < best) ? o : best;
    }
    const int par = (it & 1) * 8;
    if (lane == 0)
      wkey[par + wave] = ((unsigned long long)__float_as_uint(wv) << 32) | (unsigned int)(~best);
    __syncthreads();
    // block fold over 8 wave keys (3-step butterfly), then coord broadcast
    unsigned long long k = wkey[par + (lane & 7)];
    for (int s = 1; s < 8; s <<= 1) {
      const unsigned long long o = shfl_xor_u64(k, s);
      if (o > k) k = o;
    }
    const unsigned int idx = ~(unsigned int)k;
    lx = px[idx];
    ly = py[idx];
    lz = pz[idx];
  }
}

// ---------------------------------------------------------------- kNN top-64
// Tournament selection. Key = (float_bits << 32) | idx packs (value, index)
// lexicographic order (monotone for non-negative floats; ties -> smaller idx),
// which is exactly lax.top_k's stable selection set. Per round only the
// winner's owner column (32 elems, one wave) is rescanned.
__global__ __launch_bounds__(256) void knn_kernel(const float* __restrict__ pos,
                                                  const float* __restrict__ xf,
                                                  const float* __restrict__ sp,
                                                  float* __restrict__ gf0,
                                                  float* __restrict__ sqsel) {
#pragma clang fp contract(off)
  __shared__ float sqv[NPTS];
  __shared__ unsigned long long cand[256];
  __shared__ unsigned long long wkey[4];
  __shared__ int sel_i[KNB];
  __shared__ float sel_v[KNB];
  __shared__ int s_widx;
  const int bm = blockIdx.x;
  const int b = bm >> 7;
  const float* P = pos + (size_t)b * NPTS * 3;
  const float sx = sp[bm * 3 + 0], sy = sp[bm * 3 + 1], sz = sp[bm * 3 + 2];
  const float nsp = sx * sx + sy * sy + sz * sz;
  const int t = threadIdx.x;
  for (int j = 0; j < 32; ++j) {
    const int i = j * 256 + t;
    const float qx = P[i * 3 + 0], qy = P[i * 3 + 1], qz = P[i * 3 + 2];
    const float npos = qx * qx + qy * qy + qz * qz;
    const float dt = sx * qx + sy * qy + sz * qz;
    float sq = (nsp + npos) - 2.0f * dt;  // matches ||a||^2+||b||^2-2ab order
    sq = fmaxf(sq, 0.0f);
    sqv[i] = sq;
  }
  __syncthreads();
  // per-thread local min key over its 32-element column
  {
    unsigned long long k0 = ~0ULL;
    for (int j = 0; j < 32; ++j) {
      const int i = j * 256 + t;
      const unsigned long long key =
          ((unsigned long long)__float_as_uint(sqv[i]) << 32) | (unsigned int)i;
      if (key < k0) k0 = key;
    }
    cand[t] = k0;
  }
  __syncthreads();
  for (int round = 0; round < KNB; ++round) {
    unsigned long long k0 = cand[t];
    for (int s = 1; s < 64; s <<= 1) {
      const unsigned long long o = shfl_xor_u64(k0, s);
      if (o < k0) k0 = o;
    }
    if ((t & 63) == 0) wkey[t >> 6] = k0;
    __syncthreads();
    if (t == 0) {
      unsigned long long B = wkey[0];
      for (int w = 1; w < 4; ++w)
        if (wkey[w] < B) B = wkey[w];
      const int idx = (int)(B & 0xffffffffu);
      sel_i[round] = idx;
      sel_v[round] = __uint_as_float((unsigned int)(B >> 32));
      s_widx = idx;
      sqv[idx] = __uint_as_float(0x7f800000u);  // +inf: consumed
    }
    __syncthreads();
    const int owner = s_widx & 255;
    if ((t >> 6) == (owner >> 6)) {
      const int lane = t & 63;
      unsigned long long key = ~0ULL;
      if (lane < 32) {
        const int i = lane * 256 + owner;
        key = ((unsigned long long)__float_as_uint(sqv[i]) << 32) | (unsigned int)i;
      }
      for (int s = 1; s < 64; s <<= 1) {
        const unsigned long long o = shfl_xor_u64(key, s);
        if (o < key) key = o;
      }
      if (lane == 0) cand[owner] = key;
    }
    __syncthreads();
  }
  if (t < KNB) {
    const int i = sel_i[t];
    const float* X = xf + (size_t)b * NPTS * 3;
    const size_t base = ((size_t)bm * KNB + t) * 6;
    gf0[base + 0] = P[i * 3 + 0] - sx;
    gf0[base + 1] = P[i * 3 + 1] - sy;
    gf0[base + 2] = P[i * 3 + 2] - sz;
    gf0[base + 3] = X[i * 3 + 0];
    gf0[base + 4] = X[i * 3 + 1];
    gf0[base + 5] = X[i * 3 + 2];
    sqsel[(size_t)bm * KNB + t] = sel_v[t];
  }
}

// ---------------------------------------------------------------- stage-0 conv chain
// One block per (b, sample) 64x6 tile. Recomputes the conv chain to the target
// depth each pass (BN needs global stats between layers; FLOPs are tiny).
// MODE 1: y1 stats   MODE 2: y2 stats   MODE 3: y3 stats (+ optional z2 dump)
// MODE 4: masked max -> x1 (fallback when ws too small for the z2 cache).
// Stats partials are written [channel][block] (coalesced for p_stats).
template <int MODE>
__global__ __launch_bounds__(256) void chain_kernel(
    const float* __restrict__ gf0,
    const float* __restrict__ W0, const float* __restrict__ B0,
    const float* __restrict__ W1, const float* __restrict__ B1,
    const float* __restrict__ W2, const float* __restrict__ B2,
    const float* __restrict__ sc1, const float* __restrict__ sh1,
    const float* __restrict__ sc2, const float* __restrict__ sh2,
    const float* __restrict__ sc3, const float* __restrict__ sh3,
    const float* __restrict__ sqsel,
    float* __restrict__ psum, float* __restrict__ psq, float* __restrict__ x1,
    float* __restrict__ z2out) {
  __shared__ float tA[64 * 65];  // +1 pad: kills stride-64 bank conflicts on row reads
  __shared__ float tB[64 * 65];
  __shared__ float wbuf[64 * 64];
  __shared__ float in6[64 * 8];
  __shared__ float sqs[64];
  const int blk = blockIdx.x;
  const int t = threadIdx.x;
  {
    const float* G = gf0 + (size_t)blk * 64 * 6;
    for (int i = t; i < 384; i += 256) in6[(i / 6) * 8 + (i % 6)] = G[i];
    for (int i = t; i < 384; i += 256) wbuf[i] = W0[i];
    if (MODE == 4 && t < 64) sqs[t] = sqsel[(size_t)blk * 64 + t];
  }
  __syncthreads();
  const int r = t >> 2;
  const int c0 = (t & 3) * 16;
  float acc[16];
  // L1: 6 -> 64
#pragma unroll
  for (int j = 0; j < 16; ++j) acc[j] = B0[c0 + j];
  for (int cin = 0; cin < 6; ++cin) {
    const float a = in6[r * 8 + cin];
#pragma unroll
    for (int j = 0; j < 16; ++j) acc[j] = fmaf(a, wbuf[cin * 64 + c0 + j], acc[j]);
  }
  if (MODE == 1) {
#pragma unroll
    for (int j = 0; j < 16; ++j) tA[r * 65 + c0 + j] = acc[j];
    __syncthreads();
    if (t < 64) {
      float s = 0.f, q = 0.f;
      for (int r2 = 0; r2 < 64; ++r2) { const float v = tA[r2 * 65 + t]; s += v; q += v * v; }
      psum[(size_t)t * NBLK + blk] = s;
      psq[(size_t)t * NBLK + blk] = q;
    }
    return;
  }
#pragma unroll
  for (int j = 0; j < 16; ++j) {
    const int c = c0 + j;
    tA[r * 65 + c] = fmaxf(fmaf(acc[j], sc1[c], sh1[c]), 0.f);
  }
  __syncthreads();
  for (int i = t; i < 4096; i += 256) wbuf[i] = W1[i];
  __syncthreads();
  // L2: 64 -> 64
#pragma unroll
  for (int j = 0; j < 16; ++j) acc[j] = B1[c0 + j];
  for (int cin = 0; cin < 64; ++cin) {
    const float a = tA[r * 65 + cin];
    const float4* w4 = reinterpret_cast<const float4*>(&wbuf[cin * 64 + c0]);
#pragma unroll
    for (int k = 0; k < 4; ++k) {
      const float4 w = w4[k];
      acc[k * 4 + 0] = fmaf(a, w.x, acc[k * 4 + 0]);
      acc[k * 4 + 1] = fmaf(a, w.y, acc[k * 4 + 1]);
      acc[k * 4 + 2] = fmaf(a, w.z, acc[k * 4 + 2]);
      acc[k * 4 + 3] = fmaf(a, w.w, acc[k * 4 + 3]);
    }
  }
  if (MODE == 2) {
#pragma unroll
    for (int j = 0; j < 16; ++j) tB[r * 65 + c0 + j] = acc[j];
    __syncthreads();
    if (t < 64) {
      float s = 0.f, q = 0.f;
      for (int r2 = 0; r2 < 64; ++r2) { const float v = tB[r2 * 65 + t]; s += v; q += v * v; }
      psum[(size_t)t * NBLK + blk] = s;
      psq[(size_t)t * NBLK + blk] = q;
    }
    return;
  }
#pragma unroll
  for (int j = 0; j < 16; ++j) {
    const int c = c0 + j;
    tB[r * 65 + c] = fmaxf(fmaf(acc[j], sc2[c], sh2[c]), 0.f);
  }
  // L3: 64 -> 128, processed in channel halves (wbuf holds 64x64 weight half)
  for (int hc = 0; hc < 2; ++hc) {
    __syncthreads();
    for (int i = t; i < 4096; i += 256) {
      const int cin = i >> 6, cc = i & 63;
      wbuf[i] = W2[cin * 128 + hc * 64 + cc];
    }
    if (MODE == 3 && hc == 0 && z2out != nullptr) {
      // dump post-BN2 activations for the cached L3-only pass (chain4c)
      float* Zg = z2out + (size_t)blk * 4096;
      for (int i = t; i < 4096; i += 256) Zg[i] = tB[(i >> 6) * 65 + (i & 63)];
    }
    __syncthreads();
    float st_s = 0.f, st_q = 0.f, mx = -1e8f;
    for (int rh = 0; rh < 2; ++rh) {
      const int rr = rh * 32 + (t >> 3);
      const int cc0 = (t & 7) * 8;
      float a3[8];
#pragma unroll
      for (int j = 0; j < 8; ++j) a3[j] = B2[hc * 64 + cc0 + j];
      for (int cin = 0; cin < 64; ++cin) {
        const float a = tB[rr * 65 + cin];
        const float4* w4 = reinterpret_cast<const float4*>(&wbuf[cin * 64 + cc0]);
#pragma unroll
        for (int k = 0; k < 2; ++k) {
          const float4 w = w4[k];
          a3[k * 4 + 0] = fmaf(a, w.x, a3[k * 4 + 0]);
          a3[k * 4 + 1] = fmaf(a, w.y, a3[k * 4 + 1]);
          a3[k * 4 + 2] = fmaf(a, w.z, a3[k * 4 + 2]);
          a3[k * 4 + 3] = fmaf(a, w.w, a3[k * 4 + 3]);
        }
      }
      __syncthreads();
#pragma unroll
      for (int j = 0; j < 8; ++j) tA[(t >> 3) * 65 + cc0 + j] = a3[j];
      __syncthreads();
      if (t < 64) {
        if (MODE == 3) {
          for (int q2 = 0; q2 < 32; ++q2) { const float v = tA[q2 * 65 + t]; st_s += v; st_q += v * v; }
        } else {
          const float scv = sc3[hc * 64 + t], shv = sh3[hc * 64 + t];
          for (int q2 = 0; q2 < 32; ++q2) {
            const int kidx = rh * 32 + q2;
            const float y = tA[q2 * 65 + t];
            const float act = fmaxf(fmaf(y, scv, shv), 0.f);
            const float v = (sqs[kidx] <= 0.16f) ? act : -1e8f;
            mx = fmaxf(mx, v);
          }
        }
      }
      __syncthreads();
    }
    if (t < 64) {
      if (MODE == 3) {
        psum[(size_t)(hc * 64 + t) * NBLK + blk] = st_s;
        psq[(size_t)(hc * 64 + t) * NBLK + blk] = st_q;
      } else if (MODE == 4) {
        x1[(size_t)blk * 128 + hc * 64 + t] = mx;
      }
    }
  }
}

// Cached final pass: reads post-BN2 z2 (written by chain<3>), runs only
// L3 + BN3 + radius-masked max. Skips the L1+L2 recompute (~537M FMA).
__global__ __launch_bounds__(256) void chain4c_kernel(
    const float* __restrict__ z2, const float* __restrict__ W2, const float* __restrict__ B2,
    const float* __restrict__ sc3, const float* __restrict__ sh3,
    const float* __restrict__ sqsel, float* __restrict__ x1) {
  __shared__ float tA[64 * 65];
  __shared__ float tB[64 * 65];
  __shared__ float wbuf[64 * 64];
  __shared__ float sqs[64];
  const int blk = blockIdx.x;
  const int t = threadIdx.x;
  const float* Zg = z2 + (size_t)blk * 4096;
  for (int i = t; i < 4096; i += 256) tB[(i >> 6) * 65 + (i & 63)] = Zg[i];
  if (t < 64) sqs[t] = sqsel[(size_t)blk * 64 + t];
  for (int hc = 0; hc < 2; ++hc) {
    __syncthreads();
    for (int i = t; i < 4096; i += 256) {
      const int cin = i >> 6, cc = i & 63;
      wbuf[i] = W2[cin * 128 + hc * 64 + cc];
    }
    __syncthreads();
    float mx = -1e8f;
    for (int rh = 0; rh < 2; ++rh) {
      const int rr = rh * 32 + (t >> 3);
      const int cc0 = (t & 7) * 8;
      float a3[8];
#pragma unroll
      for (int j = 0; j < 8; ++j) a3[j] = B2[hc * 64 + cc0 + j];
      for (int cin = 0; cin < 64; ++cin) {
        const float a = tB[rr * 65 + cin];
        const float4* w4 = reinterpret_cast<const float4*>(&wbuf[cin * 64 + cc0]);
#pragma unroll
        for (int k = 0; k < 2; ++k) {
          const float4 w = w4[k];
          a3[k * 4 + 0] = fmaf(a, w.x, a3[k * 4 + 0]);
          a3[k * 4 + 1] = fmaf(a, w.y, a3[k * 4 + 1]);
          a3[k * 4 + 2] = fmaf(a, w.z, a3[k * 4 + 2]);
          a3[k * 4 + 3] = fmaf(a, w.w, a3[k * 4 + 3]);
        }
      }
      __syncthreads();
#pragma unroll
      for (int j = 0; j < 8; ++j) tA[(t >> 3) * 65 + cc0 + j] = a3[j];
      __syncthreads();
      if (t < 64) {
        const float scv = sc3[hc * 64 + t], shv = sh3[hc * 64 + t];
        for (int q2 = 0; q2 < 32; ++q2) {
          const int kidx = rh * 32 + q2;
          const float y = tA[q2 * 65 + t];
          const float act = fmaxf(fmaf(y, scv, shv), 0.f);
          const float v = (sqs[kidx] <= 0.16f) ? act : -1e8f;
          mx = fmaxf(mx, v);
        }
      }
      __syncthreads();
    }
    if (t < 64) x1[(size_t)blk * 128 + hc * 64 + t] = mx;
  }
}

// Parallel deterministic stats reduce: one block per channel, coalesced reads,
// f64 LDS tree.
__global__ __launch_bounds__(256) void p_stats(const float* __restrict__ psum,
                                               const float* __restrict__ psq,
                                               float invN,
                                               const float* __restrict__ g,
                                               const float* __restrict__ be,
                                               float* __restrict__ sc,
                                               float* __restrict__ sh) {
  const int c = blockIdx.x;
  const int t = threadIdx.x;
  double s = 0.0, q = 0.0;
  for (int k = t; k < NBLK; k += 256) {
    s += (double)psum[(size_t)c * NBLK + k];
    q += (double)psq[(size_t)c * NBLK + k];
  }
  __shared__ double ss[256], qq[256];
  ss[t] = s;
  qq[t] = q;
  __syncthreads();
  for (int st = 128; st > 0; st >>= 1) {
    if (t < st) { ss[t] += ss[t + st]; qq[t] += qq[t + st]; }
    __syncthreads();
  }
  if (t == 0) {
    const double mean = ss[0] * (double)invN;
    double var = qq[0] * (double)invN - mean * mean;
    if (var < 0.0) var = 0.0;
    const float scl = (float)((double)g[c] / sqrt(var + 1e-5));
    sc[c] = scl;
    sh[c] = be[c] - (float)mean * scl;
  }
}

// ---------------------------------------------------------------- stage 1 (2048 rows)
__global__ __launch_bounds__(128) void s1_kernel(const float* __restrict__ sp,
                                                 const float* __restrict__ x1,
                                                 const float* __restrict__ W,
                                                 const float* __restrict__ bia,
                                                 float* __restrict__ y1) {
  __shared__ float row[132];
  const int rowid = blockIdx.x;
  const int t = threadIdx.x;
  if (t < 3) row[t] = sp[(size_t)rowid * 3 + t];
  row[3 + t] = x1[(size_t)rowid * 128 + t];
  __syncthreads();
  float acc = bia[t];
  for (int cin = 0; cin < 131; ++cin) acc = fmaf(row[cin], W[(size_t)cin * 128 + t], acc);
  y1[(size_t)rowid * 128 + t] = acc;
}

__global__ __launch_bounds__(128) void s2_kernel(const float* __restrict__ y1,
                                                 const float* __restrict__ sc, const float* __restrict__ sh,
                                                 const float* __restrict__ W, const float* __restrict__ bia,
                                                 float* __restrict__ y2) {
  __shared__ float row[128];
  const int rowid = blockIdx.x;
  const int t = threadIdx.x;
  row[t] = fmaxf(fmaf(y1[(size_t)rowid * 128 + t], sc[t], sh[t]), 0.f);
  __syncthreads();
  float acc = bia[t];
  for (int cin = 0; cin < 128; ++cin) acc = fmaf(row[cin], W[(size_t)cin * 128 + t], acc);
  y2[(size_t)rowid * 128 + t] = acc;
}

__global__ __launch_bounds__(256) void s3_kernel(const float* __restrict__ y2,
                                                 const float* __restrict__ sc, const float* __restrict__ sh,
                                                 const float* __restrict__ W, const float* __restrict__ bia,
                                                 float* __restrict__ y3) {
  __shared__ float row[128];
  const int rowid = blockIdx.x;
  const int t = threadIdx.x;
  if (t < 128) row[t] = fmaxf(fmaf(y2[(size_t)rowid * 128 + t], sc[t], sh[t]), 0.f);
  __syncthreads();
  for (int h = 0; h < 2; ++h) {
    const int c = h * 256 + t;
    float acc = bia[c];
    for (int cin = 0; cin < 128; ++cin) acc = fmaf(row[cin], W[(size_t)cin * 512 + c], acc);
    y3[(size_t)rowid * 512 + c] = acc;
  }
}

// Deterministic per-channel stats over rows (block per channel, tree reduce).
__global__ __launch_bounds__(256) void s_stats(const float* __restrict__ y, int C, int rows,
                                               const float* __restrict__ g, const float* __restrict__ be,
                                               float* __restrict__ sc, float* __restrict__ sh) {
  const int c = blockIdx.x;
  const int t = threadIdx.x;
  double s = 0.0, q = 0.0;
  for (int r2 = t; r2 < rows; r2 += 256) {
    const double v = (double)y[(size_t)r2 * C + c];
    s += v;
    q += v * v;
  }
  __shared__ double ss[256], qq[256];
  ss[t] = s;
  qq[t] = q;
  __syncthreads();
  for (int st = 128; st > 0; st >>= 1) {
    if (t < st) { ss[t] += ss[t + st]; qq[t] += qq[t + st]; }
    __syncthreads();
  }
  if (t == 0) {
    const double mean = ss[0] / rows;
    double var = qq[0] / rows - mean * mean;
    if (var < 0.0) var = 0.0;
    const float scl = (float)((double)g[c] / sqrt(var + 1e-5));
    sc[c] = scl;
    sh[c] = be[c] - (float)mean * scl;
  }
}

__global__ __launch_bounds__(256) void final_kernel(const float* __restrict__ y3,
                                                    const float* __restrict__ sc, const float* __restrict__ sh,
                                                    float* __restrict__ out) {
  const int gid = blockIdx.x * 256 + threadIdx.x;  // 8192 = 16 batches x 512 ch
  const int b = gid >> 9;
  const int c = gid & 511;
  const float scv = sc[c], shv = sh[c];
  float mx = -3.402823466e+38f;
  for (int m = 0; m < 128; ++m) {
    const float v = fmaxf(fmaf(y3[((size_t)(b * 128 + m)) * 512 + c], scv, shv), 0.f);
    mx = fmaxf(mx, v);
  }
  out[gid] = mx;
  if (gid < 48) out[8192 + gid] = 0.f;  // pos_out zeros
}

extern "C" void kernel_launch(void* const* d_in, const int* in_sizes, int n_in,
                              void* d_out, int out_size, void* d_ws, size_t ws_size,
                              hipStream_t stream) {
  const float* x    = (const float*)d_in[0];
  const float* pos  = (const float*)d_in[1];
  const float* W00  = (const float*)d_in[2];
  const float* b00  = (const float*)d_in[3];
  const float* g00  = (const float*)d_in[4];
  const float* be00 = (const float*)d_in[5];
  const float* W01  = (const float*)d_in[6];
  const float* b01  = (const float*)d_in[7];
  const float* g01  = (const float*)d_in[8];
  const float* be01 = (const float*)d_in[9];
  const float* W02  = (const float*)d_in[10];
  const float* b02  = (const float*)d_in[11];
  const float* g02  = (const float*)d_in[12];
  const float* be02 = (const float*)d_in[13];
  const float* W10  = (const float*)d_in[14];
  const float* b10  = (const float*)d_in[15];
  const float* g10  = (const float*)d_in[16];
  const float* be10 = (const float*)d_in[17];
  const float* W11  = (const float*)d_in[18];
  const float* b11  = (const float*)d_in[19];
  const float* g11  = (const float*)d_in[20];
  const float* be11 = (const float*)d_in[21];
  const float* W12  = (const float*)d_in[22];
  const float* b12  = (const float*)d_in[23];
  const float* g12  = (const float*)d_in[24];
  const float* be12 = (const float*)d_in[25];

  float* w = (float*)d_ws;
  float* sp    = w;                  // 16*128*3          = 6144
  float* gf0   = sp + 6144;          // 16*128*64*6       = 786432
  float* sqsel = gf0 + 786432;       // 16*128*64         = 131072
  float* x1    = sqsel + 131072;     // 16*128*128        = 262144
  float* parts = x1 + 262144;        // 128*2048*2        = 524288
  float* psum  = parts;              // [c][blk]
  float* psq   = parts + 128 * NBLK; // [c][blk]
  float* st    = parts + 524288;     // stats area        = 2048
  float* sc1 = st + 0,    *sh1 = st + 64;
  float* sc2 = st + 128,  *sh2 = st + 192;
  float* sc3 = st + 256,  *sh3 = st + 384;
  float* t1sc = st + 512, *t1sh = st + 640;
  float* t2sc = st + 768, *t2sh = st + 896;
  float* t3sc = st + 1024, *t3sh = st + 1536;
  float* y1s = st + 2048;            // 2048*128 = 262144
  float* y2s = y1s + 262144;         // 2048*128 = 262144
  float* y3s = y2s + 262144;         // 2048*512 = 1048576
  const size_t Z2OFF = 3284992;      // end of the base layout (floats)
  const size_t Z2LEN = (size_t)NBLK * 4096;  // 8.39M floats = 33.5MB
  const bool cache_ok = ws_size >= (Z2OFF + Z2LEN) * sizeof(float);
  float* z2 = cache_ok ? (w + Z2OFF) : nullptr;

  fps_kernel<<<BATCH, 512, 0, stream>>>(pos, sp);
  knn_kernel<<<BATCH * MS, 256, 0, stream>>>(pos, x, sp, gf0, sqsel);

  const float invN0 = 1.0f / (float)(NBLK * KNB);  // 1/131072
  chain_kernel<1><<<NBLK, 256, 0, stream>>>(gf0, W00, b00, W01, b01, W02, b02,
                                            sc1, sh1, sc2, sh2, sc3, sh3, sqsel, psum, psq, x1, nullptr);
  p_stats<<<64, 256, 0, stream>>>(psum, psq, invN0, g00, be00, sc1, sh1);
  chain_kernel<2><<<NBLK, 256, 0, stream>>>(gf0, W00, b00, W01, b01, W02, b02,
                                            sc1, sh1, sc2, sh2, sc3, sh3, sqsel, psum, psq, x1, nullptr);
  p_stats<<<64, 256, 0, stream>>>(psum, psq, invN0, g01, be01, sc2, sh2);
  chain_kernel<3><<<NBLK, 256, 0, stream>>>(gf0, W00, b00, W01, b01, W02, b02,
                                            sc1, sh1, sc2, sh2, sc3, sh3, sqsel, psum, psq, x1, z2);
  p_stats<<<128, 256, 0, stream>>>(psum, psq, invN0, g02, be02, sc3, sh3);
  if (cache_ok) {
    chain4c_kernel<<<NBLK, 256, 0, stream>>>(z2, W02, b02, sc3, sh3, sqsel, x1);
  } else {
    chain_kernel<4><<<NBLK, 256, 0, stream>>>(gf0, W00, b00, W01, b01, W02, b02,
                                              sc1, sh1, sc2, sh2, sc3, sh3, sqsel, psum, psq, x1, nullptr);
  }

  s1_kernel<<<NBLK, 128, 0, stream>>>(sp, x1, W10, b10, y1s);
  s_stats<<<128, 256, 0, stream>>>(y1s, 128, NBLK, g10, be10, t1sc, t1sh);
  s2_kernel<<<NBLK, 128, 0, stream>>>(y1s, t1sc, t1sh, W11, b11, y2s);
  s_stats<<<128, 256, 0, stream>>>(y2s, 128, NBLK, g11, be11, t2sc, t2sh);
  s3_kernel<<<NBLK, 256, 0, stream>>>(y2s, t2sc, t2sh, W12, b12, y3s);
  s_stats<<<512, 256, 0, stream>>>(y3s, 512, NBLK, g12, be12, t3sc, t3sh);
  final_kernel<<<32, 256, 0, stream>>>(y3s, t3sc, t3sh, (float*)d_out);
}

// Round 6
// 512.310 us; speedup vs baseline: 4.4435x; 1.1105x over previous
//
#include <hip/hip_runtime.h>
#include <cstdint>
#include <cstddef>

#define NPTS 8192
#define BATCH 16
#define MS 128
#define KNB 64
#define NBLK (BATCH * MS)   // 2048

// ---------------- DPP wave reductions (VALU-speed, no LDS crossbar) ----------
// Sequences per LLVM AMDGPUAtomicOptimizer gfx9: row_shr 1,2,4,8 then
// row_bcast15 (rm 0xa), row_bcast31 (rm 0xc); result valid in lane 63.
// Row variants (row_shr 1,2,4,8): result valid in lane 15 of each row.

__device__ __forceinline__ float dpp_wave_max_f32(float v) {
  v = fmaxf(v, __int_as_float(__builtin_amdgcn_update_dpp((int)0xff800000, __float_as_int(v), 0x111, 0xf, 0xf, false)));
  v = fmaxf(v, __int_as_float(__builtin_amdgcn_update_dpp((int)0xff800000, __float_as_int(v), 0x112, 0xf, 0xf, false)));
  v = fmaxf(v, __int_as_float(__builtin_amdgcn_update_dpp((int)0xff800000, __float_as_int(v), 0x114, 0xf, 0xf, false)));
  v = fmaxf(v, __int_as_float(__builtin_amdgcn_update_dpp((int)0xff800000, __float_as_int(v), 0x118, 0xf, 0xf, false)));
  v = fmaxf(v, __int_as_float(__builtin_amdgcn_update_dpp((int)0xff800000, __float_as_int(v), 0x142, 0xa, 0xf, false)));
  v = fmaxf(v, __int_as_float(__builtin_amdgcn_update_dpp((int)0xff800000, __float_as_int(v), 0x143, 0xc, 0xf, false)));
  return v;  // lane 63
}

__device__ __forceinline__ float dpp_wave_min_f32(float v) {
  v = fminf(v, __int_as_float(__builtin_amdgcn_update_dpp(0x7f800000, __float_as_int(v), 0x111, 0xf, 0xf, false)));
  v = fminf(v, __int_as_float(__builtin_amdgcn_update_dpp(0x7f800000, __float_as_int(v), 0x112, 0xf, 0xf, false)));
  v = fminf(v, __int_as_float(__builtin_amdgcn_update_dpp(0x7f800000, __float_as_int(v), 0x114, 0xf, 0xf, false)));
  v = fminf(v, __int_as_float(__builtin_amdgcn_update_dpp(0x7f800000, __float_as_int(v), 0x118, 0xf, 0xf, false)));
  v = fminf(v, __int_as_float(__builtin_amdgcn_update_dpp(0x7f800000, __float_as_int(v), 0x142, 0xa, 0xf, false)));
  v = fminf(v, __int_as_float(__builtin_amdgcn_update_dpp(0x7f800000, __float_as_int(v), 0x143, 0xc, 0xf, false)));
  return v;  // lane 63
}

__device__ __forceinline__ unsigned dpp_wave_min_u32(unsigned v) {
  unsigned o;
  o = (unsigned)__builtin_amdgcn_update_dpp((int)0xffffffffu, (int)v, 0x111, 0xf, 0xf, false); v = (o < v) ? o : v;
  o = (unsigned)__builtin_amdgcn_update_dpp((int)0xffffffffu, (int)v, 0x112, 0xf, 0xf, false); v = (o < v) ? o : v;
  o = (unsigned)__builtin_amdgcn_update_dpp((int)0xffffffffu, (int)v, 0x114, 0xf, 0xf, false); v = (o < v) ? o : v;
  o = (unsigned)__builtin_amdgcn_update_dpp((int)0xffffffffu, (int)v, 0x118, 0xf, 0xf, false); v = (o < v) ? o : v;
  o = (unsigned)__builtin_amdgcn_update_dpp((int)0xffffffffu, (int)v, 0x142, 0xa, 0xf, false); v = (o < v) ? o : v;
  o = (unsigned)__builtin_amdgcn_update_dpp((int)0xffffffffu, (int)v, 0x143, 0xc, 0xf, false); v = (o < v) ? o : v;
  return v;  // lane 63
}

__device__ __forceinline__ float dpp_row_max_f32(float v) {  // lane 15 of each row
  v = fmaxf(v, __int_as_float(__builtin_amdgcn_update_dpp((int)0xff800000, __float_as_int(v), 0x111, 0xf, 0xf, false)));
  v = fmaxf(v, __int_as_float(__builtin_amdgcn_update_dpp((int)0xff800000, __float_as_int(v), 0x112, 0xf, 0xf, false)));
  v = fmaxf(v, __int_as_float(__builtin_amdgcn_update_dpp((int)0xff800000, __float_as_int(v), 0x114, 0xf, 0xf, false)));
  v = fmaxf(v, __int_as_float(__builtin_amdgcn_update_dpp((int)0xff800000, __float_as_int(v), 0x118, 0xf, 0xf, false)));
  return v;
}

__device__ __forceinline__ unsigned dpp_row_min_u32(unsigned v) {  // lane 15 of each row
  unsigned o;
  o = (unsigned)__builtin_amdgcn_update_dpp((int)0xffffffffu, (int)v, 0x111, 0xf, 0xf, false); v = (o < v) ? o : v;
  o = (unsigned)__builtin_amdgcn_update_dpp((int)0xffffffffu, (int)v, 0x112, 0xf, 0xf, false); v = (o < v) ? o : v;
  o = (unsigned)__builtin_amdgcn_update_dpp((int)0xffffffffu, (int)v, 0x114, 0xf, 0xf, false); v = (o < v) ? o : v;
  o = (unsigned)__builtin_amdgcn_update_dpp((int)0xffffffffu, (int)v, 0x118, 0xf, 0xf, false); v = (o < v) ? o : v;
  return v;
}

__device__ __forceinline__ float dpp_quad_min_f32(float v) {  // lane 3 of each row (4 slots)
  v = fminf(v, __int_as_float(__builtin_amdgcn_update_dpp(0x7f800000, __float_as_int(v), 0x111, 0xf, 0xf, false)));
  v = fminf(v, __int_as_float(__builtin_amdgcn_update_dpp(0x7f800000, __float_as_int(v), 0x112, 0xf, 0xf, false)));
  return v;
}

__device__ __forceinline__ unsigned dpp_quad_min_u32(unsigned v) {  // lane 3
  unsigned o;
  o = (unsigned)__builtin_amdgcn_update_dpp((int)0xffffffffu, (int)v, 0x111, 0xf, 0xf, false); v = (o < v) ? o : v;
  o = (unsigned)__builtin_amdgcn_update_dpp((int)0xffffffffu, (int)v, 0x112, 0xf, 0xf, false); v = (o < v) ? o : v;
  return v;
}

// ---------------------------------------------------------------- FPS
// One block per batch, 1024 threads x 8 pts in registers. Value-only hot loop
// (bit-identical arithmetic). Per iter: DPP wave max -> tie rescan -> DPP u32
// index min; lane0 publishes (val,idx) to parity-buffered 16-slot LDS; ONE
// barrier; all lanes fold 16 slots via DPP row reduce (value max, tie -> min
// index == first occurrence); seed coords via one ds_read_b128 broadcast.
__global__ __launch_bounds__(1024) void fps_kernel(const float* __restrict__ pos,
                                                   float* __restrict__ sp) {
#pragma clang fp contract(off)
  extern __shared__ float4 pts4[];  // 8192 * 16B = 128KB dynamic
  __shared__ float wval[2][16];
  __shared__ unsigned widx[2][16];
  const int b = blockIdx.x;
  const float* P = pos + (size_t)b * NPTS * 3;
  const int t = threadIdx.x;
  const int wave = t >> 6;
  const int lane = t & 63;
  float X[8], Y[8], Z[8], md[8];
#pragma unroll
  for (int j = 0; j < 8; ++j) {
    const int i = j * 1024 + t;
    const float a = P[i * 3 + 0];
    const float c = P[i * 3 + 1];
    const float d = P[i * 3 + 2];
    pts4[i] = make_float4(a, c, d, 0.f);
    X[j] = a; Y[j] = c; Z[j] = d;
    md[j] = 1e10f;
  }
  float lx = P[0], ly = P[1], lz = P[2];
  __syncthreads();
  for (int it = 0; it < MS; ++it) {
    if (t == 0) {
      sp[((size_t)b * MS + it) * 3 + 0] = lx;
      sp[((size_t)b * MS + it) * 3 + 1] = ly;
      sp[((size_t)b * MS + it) * 3 + 2] = lz;
    }
    float bv = -1.0f;
#pragma unroll
    for (int j = 0; j < 8; ++j) {
      const float dx = X[j] - lx;
      const float dy = Y[j] - ly;
      const float dz = Z[j] - lz;
      const float d = dx * dx + dy * dy + dz * dz;  // contract off: same order as ref
      float m = md[j];
      m = (d < m) ? d : m;
      md[j] = m;
      bv = (m > bv) ? m : bv;
    }
    // wave max value (DPP) -> uniform via readlane 63
    const float wv = __int_as_float(
        __builtin_amdgcn_readlane(__float_as_int(dpp_wave_max_f32(bv)), 63));
    // tie threads resolve smallest flat idx; DPP u32 min
    unsigned best = 0xffffffffu;
    if (bv == wv) {
#pragma unroll
      for (int j = 7; j >= 0; --j)
        if (md[j] == wv) best = (unsigned)(j * 1024 + t);
    }
    const unsigned wi =
        (unsigned)__builtin_amdgcn_readlane((int)dpp_wave_min_u32(best), 63);
    const int par = it & 1;
    if (lane == 0) { wval[par][wave] = wv; widx[par][wave] = wi; }
    __syncthreads();
    // block fold over 16 wave slots (DPP row reduce), then coord broadcast
    const float a = wval[par][lane & 15];
    const float M = __int_as_float(
        __builtin_amdgcn_readlane(__float_as_int(dpp_row_max_f32(a)), 15));
    const unsigned c2 = (a == M) ? widx[par][lane & 15] : 0xffffffffu;
    const unsigned idx =
        (unsigned)__builtin_amdgcn_readlane((int)dpp_row_min_u32(c2), 15);
    const float4 c = pts4[idx];
    lx = c.x; ly = c.y; lz = c.z;
  }
}

// ---------------------------------------------------------------- kNN top-64
// Tournament selection, candidates in registers, DPP reductions, ONE barrier
// per round. Selection order: min distance, tie -> smaller index == exactly
// lax.top_k's stable selection set (proven semantics from earlier rounds).
__global__ __launch_bounds__(256) void knn_kernel(const float* __restrict__ pos,
                                                  const float* __restrict__ xf,
                                                  const float* __restrict__ sp,
                                                  float* __restrict__ gf0,
                                                  float* __restrict__ sqsel) {
#pragma clang fp contract(off)
  __shared__ float sqv[NPTS];
  __shared__ float wval[2][4];
  __shared__ unsigned widx[2][4];
  __shared__ int sel_i[KNB];
  __shared__ float sel_v[KNB];
  const int bm = blockIdx.x;
  const int b = bm >> 7;
  const float* P = pos + (size_t)b * NPTS * 3;
  const float sx = sp[bm * 3 + 0], sy = sp[bm * 3 + 1], sz = sp[bm * 3 + 2];
  const float nsp = sx * sx + sy * sy + sz * sz;
  const int t = threadIdx.x;
  const int wave = t >> 6;
  const int lane = t & 63;
  for (int j = 0; j < 32; ++j) {
    const int i = j * 256 + t;
    const float qx = P[i * 3 + 0], qy = P[i * 3 + 1], qz = P[i * 3 + 2];
    const float npos = qx * qx + qy * qy + qz * qz;
    const float dt = sx * qx + sy * qy + sz * qz;
    float sq = (nsp + npos) - 2.0f * dt;  // matches ||a||^2+||b||^2-2ab order
    sq = fmaxf(sq, 0.0f);
    sqv[i] = sq;
  }
  __syncthreads();
  // per-thread candidate (value, idx) over its 32-element column, in registers
  float cv;
  unsigned ci;
  {
    unsigned long long k0 = ~0ULL;
    for (int j = 0; j < 32; ++j) {
      const int i = j * 256 + t;
      const unsigned long long key =
          ((unsigned long long)__float_as_uint(sqv[i]) << 32) | (unsigned)i;
      if (key < k0) k0 = key;
    }
    cv = __uint_as_float((unsigned)(k0 >> 32));
    ci = (unsigned)k0;
  }
  for (int round = 0; round < KNB; ++round) {
    // wave min (value), tie -> min idx
    const float wv = __int_as_float(
        __builtin_amdgcn_readlane(__float_as_int(dpp_wave_min_f32(cv)), 63));
    const unsigned sel = (cv == wv) ? ci : 0xffffffffu;
    const unsigned wi =
        (unsigned)__builtin_amdgcn_readlane((int)dpp_wave_min_u32(sel), 63);
    const int par = round & 1;
    if (lane == 0) { wval[par][wave] = wv; widx[par][wave] = wi; }
    __syncthreads();
    // block fold over 4 wave slots
    const float a = wval[par][lane & 3];
    const float M = __int_as_float(
        __builtin_amdgcn_readlane(__float_as_int(dpp_quad_min_f32(a)), 3));
    const unsigned c2 = (a == M) ? widx[par][lane & 3] : 0xffffffffu;
    const unsigned idx =
        (unsigned)__builtin_amdgcn_readlane((int)dpp_quad_min_u32(c2), 3);
    const int col = (int)(idx & 255u);
    if (t == col) {
      sel_i[round] = (int)idx;
      sel_v[round] = M;
      sqv[idx] = __uint_as_float(0x7f800000u);  // consumed (visible next round)
    }
    // winner's wave rescans the consumed column (consumed elem masked locally)
    if (wave == (col >> 6)) {
      float v = __uint_as_float(0x7f800000u);
      unsigned ii = 0xffffffffu;
      if (lane < 32) {
        const int i = lane * 256 + col;
        v = sqv[i];
        if (i == (int)idx) v = __uint_as_float(0x7f800000u);
        ii = (unsigned)i;
      }
      const float mv = __int_as_float(
          __builtin_amdgcn_readlane(__float_as_int(dpp_wave_min_f32(v)), 63));
      const unsigned s2 = (v == mv) ? ii : 0xffffffffu;
      const unsigned mi =
          (unsigned)__builtin_amdgcn_readlane((int)dpp_wave_min_u32(s2), 63);
      if (t == col) { cv = mv; ci = mi; }
    }
  }
  __syncthreads();
  if (t < KNB) {
    const int i = sel_i[t];
    const float* X = xf + (size_t)b * NPTS * 3;
    const size_t base = ((size_t)bm * KNB + t) * 6;
    gf0[base + 0] = P[i * 3 + 0] - sx;
    gf0[base + 1] = P[i * 3 + 1] - sy;
    gf0[base + 2] = P[i * 3 + 2] - sz;
    gf0[base + 3] = X[i * 3 + 0];
    gf0[base + 4] = X[i * 3 + 1];
    gf0[base + 5] = X[i * 3 + 2];
    sqsel[(size_t)bm * KNB + t] = sel_v[t];
  }
}

// ---------------------------------------------------------------- stage-0 conv chain
// One block per (b, sample) 64x6 tile. Recomputes the conv chain to the target
// depth each pass (BN needs global stats between layers; FLOPs are tiny).
// MODE 1: y1 stats   MODE 2: y2 stats   MODE 3: y3 stats (+ optional z2 dump)
// MODE 4: masked max -> x1 (fallback when ws too small for the z2 cache).
// Stats partials are written [channel][block] (coalesced for p_stats).
template <int MODE>
__global__ __launch_bounds__(256) void chain_kernel(
    const float* __restrict__ gf0,
    const float* __restrict__ W0, const float* __restrict__ B0,
    const float* __restrict__ W1, const float* __restrict__ B1,
    const float* __restrict__ W2, const float* __restrict__ B2,
    const float* __restrict__ sc1, const float* __restrict__ sh1,
    const float* __restrict__ sc2, const float* __restrict__ sh2,
    const float* __restrict__ sc3, const float* __restrict__ sh3,
    const float* __restrict__ sqsel,
    float* __restrict__ psum, float* __restrict__ psq, float* __restrict__ x1,
    float* __restrict__ z2out) {
  __shared__ float tA[64 * 65];  // +1 pad: kills stride-64 bank conflicts on row reads
  __shared__ float tB[64 * 65];
  __shared__ float wbuf[64 * 64];
  __shared__ float in6[64 * 8];
  __shared__ float sqs[64];
  const int blk = blockIdx.x;
  const int t = threadIdx.x;
  {
    const float* G = gf0 + (size_t)blk * 64 * 6;
    for (int i = t; i < 384; i += 256) in6[(i / 6) * 8 + (i % 6)] = G[i];
    for (int i = t; i < 384; i += 256) wbuf[i] = W0[i];
    if (MODE == 4 && t < 64) sqs[t] = sqsel[(size_t)blk * 64 + t];
  }
  __syncthreads();
  const int r = t >> 2;
  const int c0 = (t & 3) * 16;
  float acc[16];
  // L1: 6 -> 64
#pragma unroll
  for (int j = 0; j < 16; ++j) acc[j] = B0[c0 + j];
  for (int cin = 0; cin < 6; ++cin) {
    const float a = in6[r * 8 + cin];
#pragma unroll
    for (int j = 0; j < 16; ++j) acc[j] = fmaf(a, wbuf[cin * 64 + c0 + j], acc[j]);
  }
  if (MODE == 1) {
#pragma unroll
    for (int j = 0; j < 16; ++j) tA[r * 65 + c0 + j] = acc[j];
    __syncthreads();
    if (t < 64) {
      float s = 0.f, q = 0.f;
      for (int r2 = 0; r2 < 64; ++r2) { const float v = tA[r2 * 65 + t]; s += v; q += v * v; }
      psum[(size_t)t * NBLK + blk] = s;
      psq[(size_t)t * NBLK + blk] = q;
    }
    return;
  }
#pragma unroll
  for (int j = 0; j < 16; ++j) {
    const int c = c0 + j;
    tA[r * 65 + c] = fmaxf(fmaf(acc[j], sc1[c], sh1[c]), 0.f);
  }
  __syncthreads();
  for (int i = t; i < 4096; i += 256) wbuf[i] = W1[i];
  __syncthreads();
  // L2: 64 -> 64
#pragma unroll
  for (int j = 0; j < 16; ++j) acc[j] = B1[c0 + j];
  for (int cin = 0; cin < 64; ++cin) {
    const float a = tA[r * 65 + cin];
    const float4* w4 = reinterpret_cast<const float4*>(&wbuf[cin * 64 + c0]);
#pragma unroll
    for (int k = 0; k < 4; ++k) {
      const float4 w = w4[k];
      acc[k * 4 + 0] = fmaf(a, w.x, acc[k * 4 + 0]);
      acc[k * 4 + 1] = fmaf(a, w.y, acc[k * 4 + 1]);
      acc[k * 4 + 2] = fmaf(a, w.z, acc[k * 4 + 2]);
      acc[k * 4 + 3] = fmaf(a, w.w, acc[k * 4 + 3]);
    }
  }
  if (MODE == 2) {
#pragma unroll
    for (int j = 0; j < 16; ++j) tB[r * 65 + c0 + j] = acc[j];
    __syncthreads();
    if (t < 64) {
      float s = 0.f, q = 0.f;
      for (int r2 = 0; r2 < 64; ++r2) { const float v = tB[r2 * 65 + t]; s += v; q += v * v; }
      psum[(size_t)t * NBLK + blk] = s;
      psq[(size_t)t * NBLK + blk] = q;
    }
    return;
  }
#pragma unroll
  for (int j = 0; j < 16; ++j) {
    const int c = c0 + j;
    tB[r * 65 + c] = fmaxf(fmaf(acc[j], sc2[c], sh2[c]), 0.f);
  }
  // L3: 64 -> 128, processed in channel halves (wbuf holds 64x64 weight half)
  for (int hc = 0; hc < 2; ++hc) {
    __syncthreads();
    for (int i = t; i < 4096; i += 256) {
      const int cin = i >> 6, cc = i & 63;
      wbuf[i] = W2[cin * 128 + hc * 64 + cc];
    }
    if (MODE == 3 && hc == 0 && z2out != nullptr) {
      float* Zg = z2out + (size_t)blk * 4096;
      for (int i = t; i < 4096; i += 256) Zg[i] = tB[(i >> 6) * 65 + (i & 63)];
    }
    __syncthreads();
    float st_s = 0.f, st_q = 0.f, mx = -1e8f;
    for (int rh = 0; rh < 2; ++rh) {
      const int rr = rh * 32 + (t >> 3);
      const int cc0 = (t & 7) * 8;
      float a3[8];
#pragma unroll
      for (int j = 0; j < 8; ++j) a3[j] = B2[hc * 64 + cc0 + j];
      for (int cin = 0; cin < 64; ++cin) {
        const float a = tB[rr * 65 + cin];
        const float4* w4 = reinterpret_cast<const float4*>(&wbuf[cin * 64 + cc0]);
#pragma unroll
        for (int k = 0; k < 2; ++k) {
          const float4 w = w4[k];
          a3[k * 4 + 0] = fmaf(a, w.x, a3[k * 4 + 0]);
          a3[k * 4 + 1] = fmaf(a, w.y, a3[k * 4 + 1]);
          a3[k * 4 + 2] = fmaf(a, w.z, a3[k * 4 + 2]);
          a3[k * 4 + 3] = fmaf(a, w.w, a3[k * 4 + 3]);
        }
      }
      __syncthreads();
#pragma unroll
      for (int j = 0; j < 8; ++j) tA[(t >> 3) * 65 + cc0 + j] = a3[j];
      __syncthreads();
      if (t < 64) {
        if (MODE == 3) {
          for (int q2 = 0; q2 < 32; ++q2) { const float v = tA[q2 * 65 + t]; st_s += v; st_q += v * v; }
        } else {
          const float scv = sc3[hc * 64 + t], shv = sh3[hc * 64 + t];
          for (int q2 = 0; q2 < 32; ++q2) {
            const int kidx = rh * 32 + q2;
            const float y = tA[q2 * 65 + t];
            const float act = fmaxf(fmaf(y, scv, shv), 0.f);
            const float v = (sqs[kidx] <= 0.16f) ? act : -1e8f;
            mx = fmaxf(mx, v);
          }
        }
      }
      __syncthreads();
    }
    if (t < 64) {
      if (MODE == 3) {
        psum[(size_t)(hc * 64 + t) * NBLK + blk] = st_s;
        psq[(size_t)(hc * 64 + t) * NBLK + blk] = st_q;
      } else if (MODE == 4) {
        x1[(size_t)blk * 128 + hc * 64 + t] = mx;
      }
    }
  }
}

// Cached final pass: reads post-BN2 z2 (written by chain<3>), runs only
// L3 + BN3 + radius-masked max. Skips the L1+L2 recompute.
__global__ __launch_bounds__(256) void chain4c_kernel(
    const float* __restrict__ z2, const float* __restrict__ W2, const float* __restrict__ B2,
    const float* __restrict__ sc3, const float* __restrict__ sh3,
    const float* __restrict__ sqsel, float* __restrict__ x1) {
  __shared__ float tA[64 * 65];
  __shared__ float tB[64 * 65];
  __shared__ float wbuf[64 * 64];
  __shared__ float sqs[64];
  const int blk = blockIdx.x;
  const int t = threadIdx.x;
  const float* Zg = z2 + (size_t)blk * 4096;
  for (int i = t; i < 4096; i += 256) tB[(i >> 6) * 65 + (i & 63)] = Zg[i];
  if (t < 64) sqs[t] = sqsel[(size_t)blk * 64 + t];
  for (int hc = 0; hc < 2; ++hc) {
    __syncthreads();
    for (int i = t; i < 4096; i += 256) {
      const int cin = i >> 6, cc = i & 63;
      wbuf[i] = W2[cin * 128 + hc * 64 + cc];
    }
    __syncthreads();
    float mx = -1e8f;
    for (int rh = 0; rh < 2; ++rh) {
      const int rr = rh * 32 + (t >> 3);
      const int cc0 = (t & 7) * 8;
      float a3[8];
#pragma unroll
      for (int j = 0; j < 8; ++j) a3[j] = B2[hc * 64 + cc0 + j];
      for (int cin = 0; cin < 64; ++cin) {
        const float a = tB[rr * 65 + cin];
        const float4* w4 = reinterpret_cast<const float4*>(&wbuf[cin * 64 + cc0]);
#pragma unroll
        for (int k = 0; k < 2; ++k) {
          const float4 w = w4[k];
          a3[k * 4 + 0] = fmaf(a, w.x, a3[k * 4 + 0]);
          a3[k * 4 + 1] = fmaf(a, w.y, a3[k * 4 + 1]);
          a3[k * 4 + 2] = fmaf(a, w.z, a3[k * 4 + 2]);
          a3[k * 4 + 3] = fmaf(a, w.w, a3[k * 4 + 3]);
        }
      }
      __syncthreads();
#pragma unroll
      for (int j = 0; j < 8; ++j) tA[(t >> 3) * 65 + cc0 + j] = a3[j];
      __syncthreads();
      if (t < 64) {
        const float scv = sc3[hc * 64 + t], shv = sh3[hc * 64 + t];
        for (int q2 = 0; q2 < 32; ++q2) {
          const int kidx = rh * 32 + q2;
          const float y = tA[q2 * 65 + t];
          const float act = fmaxf(fmaf(y, scv, shv), 0.f);
          const float v = (sqs[kidx] <= 0.16f) ? act : -1e8f;
          mx = fmaxf(mx, v);
        }
      }
      __syncthreads();
    }
    if (t < 64) x1[(size_t)blk * 128 + hc * 64 + t] = mx;
  }
}

// Parallel deterministic stats reduce: one block per channel, coalesced reads,
// f64 LDS tree.
__global__ __launch_bounds__(256) void p_stats(const float* __restrict__ psum,
                                               const float* __restrict__ psq,
                                               float invN,
                                               const float* __restrict__ g,
                                               const float* __restrict__ be,
                                               float* __restrict__ sc,
                                               float* __restrict__ sh) {
  const int c = blockIdx.x;
  const int t = threadIdx.x;
  double s = 0.0, q = 0.0;
  for (int k = t; k < NBLK; k += 256) {
    s += (double)psum[(size_t)c * NBLK + k];
    q += (double)psq[(size_t)c * NBLK + k];
  }
  __shared__ double ss[256], qq[256];
  ss[t] = s;
  qq[t] = q;
  __syncthreads();
  for (int st = 128; st > 0; st >>= 1) {
    if (t < st) { ss[t] += ss[t + st]; qq[t] += qq[t + st]; }
    __syncthreads();
  }
  if (t == 0) {
    const double mean = ss[0] * (double)invN;
    double var = qq[0] * (double)invN - mean * mean;
    if (var < 0.0) var = 0.0;
    const float scl = (float)((double)g[c] / sqrt(var + 1e-5));
    sc[c] = scl;
    sh[c] = be[c] - (float)mean * scl;
  }
}

// ---------------------------------------------------------------- stage 1 (2048 rows)
__global__ __launch_bounds__(128) void s1_kernel(const float* __restrict__ sp,
                                                 const float* __restrict__ x1,
                                                 const float* __restrict__ W,
                                                 const float* __restrict__ bia,
                                                 float* __restrict__ y1) {
  __shared__ float row[132];
  const int rowid = blockIdx.x;
  const int t = threadIdx.x;
  if (t < 3) row[t] = sp[(size_t)rowid * 3 + t];
  row[3 + t] = x1[(size_t)rowid * 128 + t];
  __syncthreads();
  float acc = bia[t];
  for (int cin = 0; cin < 131; ++cin) acc = fmaf(row[cin], W[(size_t)cin * 128 + t], acc);
  y1[(size_t)rowid * 128 + t] = acc;
}

__global__ __launch_bounds__(128) void s2_kernel(const float* __restrict__ y1,
                                                 const float* __restrict__ sc, const float* __restrict__ sh,
                                                 const float* __restrict__ W, const float* __restrict__ bia,
                                                 float* __restrict__ y2) {
  __shared__ float row[128];
  const int rowid = blockIdx.x;
  const int t = threadIdx.x;
  row[t] = fmaxf(fmaf(y1[(size_t)rowid * 128 + t], sc[t], sh[t]), 0.f);
  __syncthreads();
  float acc = bia[t];
  for (int cin = 0; cin < 128; ++cin) acc = fmaf(row[cin], W[(size_t)cin * 128 + t], acc);
  y2[(size_t)rowid * 128 + t] = acc;
}

__global__ __launch_bounds__(256) void s3_kernel(const float* __restrict__ y2,
                                                 const float* __restrict__ sc, const float* __restrict__ sh,
                                                 const float* __restrict__ W, const float* __restrict__ bia,
                                                 float* __restrict__ y3) {
  __shared__ float row[128];
  const int rowid = blockIdx.x;
  const int t = threadIdx.x;
  if (t < 128) row[t] = fmaxf(fmaf(y2[(size_t)rowid * 128 + t], sc[t], sh[t]), 0.f);
  __syncthreads();
  for (int h = 0; h < 2; ++h) {
    const int c = h * 256 + t;
    float acc = bia[c];
    for (int cin = 0; cin < 128; ++cin) acc = fmaf(row[cin], W[(size_t)cin * 512 + c], acc);
    y3[(size_t)rowid * 512 + c] = acc;
  }
}

// Deterministic per-channel stats over rows (block per channel, tree reduce).
__global__ __launch_bounds__(256) void s_stats(const float* __restrict__ y, int C, int rows,
                                               const float* __restrict__ g, const float* __restrict__ be,
                                               float* __restrict__ sc, float* __restrict__ sh) {
  const int c = blockIdx.x;
  const int t = threadIdx.x;
  double s = 0.0, q = 0.0;
  for (int r2 = t; r2 < rows; r2 += 256) {
    const double v = (double)y[(size_t)r2 * C + c];
    s += v;
    q += v * v;
  }
  __shared__ double ss[256], qq[256];
  ss[t] = s;
  qq[t] = q;
  __syncthreads();
  for (int st = 128; st > 0; st >>= 1) {
    if (t < st) { ss[t] += ss[t + st]; qq[t] += qq[t + st]; }
    __syncthreads();
  }
  if (t == 0) {
    const double mean = ss[0] / rows;
    double var = qq[0] / rows - mean * mean;
    if (var < 0.0) var = 0.0;
    const float scl = (float)((double)g[c] / sqrt(var + 1e-5));
    sc[c] = scl;
    sh[c] = be[c] - (float)mean * scl;
  }
}

__global__ __launch_bounds__(256) void final_kernel(const float* __restrict__ y3,
                                                    const float* __restrict__ sc, const float* __restrict__ sh,
                                                    float* __restrict__ out) {
  const int gid = blockIdx.x * 256 + threadIdx.x;  // 8192 = 16 batches x 512 ch
  const int b = gid >> 9;
  const int c = gid & 511;
  const float scv = sc[c], shv = sh[c];
  float mx = -3.402823466e+38f;
  for (int m = 0; m < 128; ++m) {
    const float v = fmaxf(fmaf(y3[((size_t)(b * 128 + m)) * 512 + c], scv, shv), 0.f);
    mx = fmaxf(mx, v);
  }
  out[gid] = mx;
  if (gid < 48) out[8192 + gid] = 0.f;  // pos_out zeros
}

extern "C" void kernel_launch(void* const* d_in, const int* in_sizes, int n_in,
                              void* d_out, int out_size, void* d_ws, size_t ws_size,
                              hipStream_t stream) {
  const float* x    = (const float*)d_in[0];
  const float* pos  = (const float*)d_in[1];
  const float* W00  = (const float*)d_in[2];
  const float* b00  = (const float*)d_in[3];
  const float* g00  = (const float*)d_in[4];
  const float* be00 = (const float*)d_in[5];
  const float* W01  = (const float*)d_in[6];
  const float* b01  = (const float*)d_in[7];
  const float* g01  = (const float*)d_in[8];
  const float* be01 = (const float*)d_in[9];
  const float* W02  = (const float*)d_in[10];
  const float* b02  = (const float*)d_in[11];
  const float* g02  = (const float*)d_in[12];
  const float* be02 = (const float*)d_in[13];
  const float* W10  = (const float*)d_in[14];
  const float* b10  = (const float*)d_in[15];
  const float* g10  = (const float*)d_in[16];
  const float* be10 = (const float*)d_in[17];
  const float* W11  = (const float*)d_in[18];
  const float* b11  = (const float*)d_in[19];
  const float* g11  = (const float*)d_in[20];
  const float* be11 = (const float*)d_in[21];
  const float* W12  = (const float*)d_in[22];
  const float* b12  = (const float*)d_in[23];
  const float* g12  = (const float*)d_in[24];
  const float* be12 = (const float*)d_in[25];

  float* w = (float*)d_ws;
  float* sp    = w;                  // 16*128*3          = 6144
  float* gf0   = sp + 6144;          // 16*128*64*6       = 786432
  float* sqsel = gf0 + 786432;       // 16*128*64         = 131072
  float* x1    = sqsel + 131072;     // 16*128*128        = 262144
  float* parts = x1 + 262144;        // 128*2048*2        = 524288
  float* psum  = parts;              // [c][blk]
  float* psq   = parts + 128 * NBLK; // [c][blk]
  float* st    = parts + 524288;     // stats area        = 2048
  float* sc1 = st + 0,    *sh1 = st + 64;
  float* sc2 = st + 128,  *sh2 = st + 192;
  float* sc3 = st + 256,  *sh3 = st + 384;
  float* t1sc = st + 512, *t1sh = st + 640;
  float* t2sc = st + 768, *t2sh = st + 896;
  float* t3sc = st + 1024, *t3sh = st + 1536;
  float* y1s = st + 2048;            // 2048*128 = 262144
  float* y2s = y1s + 262144;         // 2048*128 = 262144
  float* y3s = y2s + 262144;         // 2048*512 = 1048576
  const size_t Z2OFF = 3284992;      // end of the base layout (floats)
  const size_t Z2LEN = (size_t)NBLK * 4096;  // 8.39M floats = 33.5MB
  const bool cache_ok = ws_size >= (Z2OFF + Z2LEN) * sizeof(float);
  float* z2 = cache_ok ? (w + Z2OFF) : nullptr;

  fps_kernel<<<BATCH, 1024, NPTS * sizeof(float4), stream>>>(pos, sp);
  knn_kernel<<<BATCH * MS, 256, 0, stream>>>(pos, x, sp, gf0, sqsel);

  const float invN0 = 1.0f / (float)(NBLK * KNB);  // 1/131072
  chain_kernel<1><<<NBLK, 256, 0, stream>>>(gf0, W00, b00, W01, b01, W02, b02,
                                            sc1, sh1, sc2, sh2, sc3, sh3, sqsel, psum, psq, x1, nullptr);
  p_stats<<<64, 256, 0, stream>>>(psum, psq, invN0, g00, be00, sc1, sh1);
  chain_kernel<2><<<NBLK, 256, 0, stream>>>(gf0, W00, b00, W01, b01, W02, b02,
                                            sc1, sh1, sc2, sh2, sc3, sh3, sqsel, psum, psq, x1, nullptr);
  p_stats<<<64, 256, 0, stream>>>(psum, psq, invN0, g01, be01, sc2, sh2);
  chain_kernel<3><<<NBLK, 256, 0, stream>>>(gf0, W00, b00, W01, b01, W02, b02,
                                            sc1, sh1, sc2, sh2, sc3, sh3, sqsel, psum, psq, x1, z2);
  p_stats<<<128, 256, 0, stream>>>(psum, psq, invN0, g02, be02, sc3, sh3);
  if (cache_ok) {
    chain4c_kernel<<<NBLK, 256, 0, stream>>>(z2, W02, b02, sc3, sh3, sqsel, x1);
  } else {
    chain_kernel<4><<<NBLK, 256, 0, stream>>>(gf0, W00, b00, W01, b01, W02, b02,
                                              sc1, sh1, sc2, sh2, sc3, sh3, sqsel, psum, psq, x1, nullptr);
  }

  s1_kernel<<<NBLK, 128, 0, stream>>>(sp, x1, W10, b10, y1s);
  s_stats<<<128, 256, 0, stream>>>(y1s, 128, NBLK, g10, be10, t1sc, t1sh);
  s2_kernel<<<NBLK, 128, 0, stream>>>(y1s, t1sc, t1sh, W11, b11, y2s);
  s_stats<<<128, 256, 0, stream>>>(y2s, 128, NBLK, g11, be11, t2sc, t2sh);
  s3_kernel<<<NBLK, 256, 0, stream>>>(y2s, t2sc, t2sh, W12, b12, y3s);
  s_stats<<<512, 256, 0, stream>>>(y3s, 512, NBLK, g12, be12, t3sc, t3sh);
  final_kernel<<<32, 256, 0, stream>>>(y3s, t3sc, t3sh, (float*)d_out);
}

// Round 7
// 510.481 us; speedup vs baseline: 4.4594x; 1.0036x over previous
//
#include <hip/hip_runtime.h>
#include <cstdint>
#include <cstddef>

#define NPTS 8192
#define BATCH 16
#define MS 128
#define KNB 64
#define NBLK (BATCH * MS)   // 2048

// ---------------- DPP wave reductions (VALU-speed, no LDS crossbar) ----------
// Sequences per LLVM AMDGPUAtomicOptimizer gfx9: row_shr 1,2,4,8 then
// row_bcast15 (rm 0xa), row_bcast31 (rm 0xc); result valid in lane 63.
// Row variants (row_shr 1,2,4,8): result valid in lane 15 of each row.

__device__ __forceinline__ float dpp_wave_max_f32(float v) {
  v = fmaxf(v, __int_as_float(__builtin_amdgcn_update_dpp((int)0xff800000, __float_as_int(v), 0x111, 0xf, 0xf, false)));
  v = fmaxf(v, __int_as_float(__builtin_amdgcn_update_dpp((int)0xff800000, __float_as_int(v), 0x112, 0xf, 0xf, false)));
  v = fmaxf(v, __int_as_float(__builtin_amdgcn_update_dpp((int)0xff800000, __float_as_int(v), 0x114, 0xf, 0xf, false)));
  v = fmaxf(v, __int_as_float(__builtin_amdgcn_update_dpp((int)0xff800000, __float_as_int(v), 0x118, 0xf, 0xf, false)));
  v = fmaxf(v, __int_as_float(__builtin_amdgcn_update_dpp((int)0xff800000, __float_as_int(v), 0x142, 0xa, 0xf, false)));
  v = fmaxf(v, __int_as_float(__builtin_amdgcn_update_dpp((int)0xff800000, __float_as_int(v), 0x143, 0xc, 0xf, false)));
  return v;  // lane 63
}

__device__ __forceinline__ float dpp_wave_min_f32(float v) {
  v = fminf(v, __int_as_float(__builtin_amdgcn_update_dpp(0x7f800000, __float_as_int(v), 0x111, 0xf, 0xf, false)));
  v = fminf(v, __int_as_float(__builtin_amdgcn_update_dpp(0x7f800000, __float_as_int(v), 0x112, 0xf, 0xf, false)));
  v = fminf(v, __int_as_float(__builtin_amdgcn_update_dpp(0x7f800000, __float_as_int(v), 0x114, 0xf, 0xf, false)));
  v = fminf(v, __int_as_float(__builtin_amdgcn_update_dpp(0x7f800000, __float_as_int(v), 0x118, 0xf, 0xf, false)));
  v = fminf(v, __int_as_float(__builtin_amdgcn_update_dpp(0x7f800000, __float_as_int(v), 0x142, 0xa, 0xf, false)));
  v = fminf(v, __int_as_float(__builtin_amdgcn_update_dpp(0x7f800000, __float_as_int(v), 0x143, 0xc, 0xf, false)));
  return v;  // lane 63
}

__device__ __forceinline__ unsigned dpp_wave_min_u32(unsigned v) {
  unsigned o;
  o = (unsigned)__builtin_amdgcn_update_dpp((int)0xffffffffu, (int)v, 0x111, 0xf, 0xf, false); v = (o < v) ? o : v;
  o = (unsigned)__builtin_amdgcn_update_dpp((int)0xffffffffu, (int)v, 0x112, 0xf, 0xf, false); v = (o < v) ? o : v;
  o = (unsigned)__builtin_amdgcn_update_dpp((int)0xffffffffu, (int)v, 0x114, 0xf, 0xf, false); v = (o < v) ? o : v;
  o = (unsigned)__builtin_amdgcn_update_dpp((int)0xffffffffu, (int)v, 0x118, 0xf, 0xf, false); v = (o < v) ? o : v;
  o = (unsigned)__builtin_amdgcn_update_dpp((int)0xffffffffu, (int)v, 0x142, 0xa, 0xf, false); v = (o < v) ? o : v;
  o = (unsigned)__builtin_amdgcn_update_dpp((int)0xffffffffu, (int)v, 0x143, 0xc, 0xf, false); v = (o < v) ? o : v;
  return v;  // lane 63
}

__device__ __forceinline__ float dpp_row_max_f32(float v) {  // lane 15 of each row
  v = fmaxf(v, __int_as_float(__builtin_amdgcn_update_dpp((int)0xff800000, __float_as_int(v), 0x111, 0xf, 0xf, false)));
  v = fmaxf(v, __int_as_float(__builtin_amdgcn_update_dpp((int)0xff800000, __float_as_int(v), 0x112, 0xf, 0xf, false)));
  v = fmaxf(v, __int_as_float(__builtin_amdgcn_update_dpp((int)0xff800000, __float_as_int(v), 0x114, 0xf, 0xf, false)));
  v = fmaxf(v, __int_as_float(__builtin_amdgcn_update_dpp((int)0xff800000, __float_as_int(v), 0x118, 0xf, 0xf, false)));
  return v;
}

__device__ __forceinline__ unsigned dpp_row_min_u32(unsigned v) {  // lane 15 of each row
  unsigned o;
  o = (unsigned)__builtin_amdgcn_update_dpp((int)0xffffffffu, (int)v, 0x111, 0xf, 0xf, false); v = (o < v) ? o : v;
  o = (unsigned)__builtin_amdgcn_update_dpp((int)0xffffffffu, (int)v, 0x112, 0xf, 0xf, false); v = (o < v) ? o : v;
  o = (unsigned)__builtin_amdgcn_update_dpp((int)0xffffffffu, (int)v, 0x114, 0xf, 0xf, false); v = (o < v) ? o : v;
  o = (unsigned)__builtin_amdgcn_update_dpp((int)0xffffffffu, (int)v, 0x118, 0xf, 0xf, false); v = (o < v) ? o : v;
  return v;
}

__device__ __forceinline__ float dpp_quad_min_f32(float v) {  // lane 3 of each row (4 slots)
  v = fminf(v, __int_as_float(__builtin_amdgcn_update_dpp(0x7f800000, __float_as_int(v), 0x111, 0xf, 0xf, false)));
  v = fminf(v, __int_as_float(__builtin_amdgcn_update_dpp(0x7f800000, __float_as_int(v), 0x112, 0xf, 0xf, false)));
  return v;
}

__device__ __forceinline__ unsigned dpp_quad_min_u32(unsigned v) {  // lane 3
  unsigned o;
  o = (unsigned)__builtin_amdgcn_update_dpp((int)0xffffffffu, (int)v, 0x111, 0xf, 0xf, false); v = (o < v) ? o : v;
  o = (unsigned)__builtin_amdgcn_update_dpp((int)0xffffffffu, (int)v, 0x112, 0xf, 0xf, false); v = (o < v) ? o : v;
  return v;
}

// ---------------------------------------------------------------- FPS
// One block per batch, 1024 threads x 8 pts. Point state in NAMED SCALARS
// (round-6 profile showed VGPR_Count=28 -> the X/Y/Z/md arrays were scratch-
// spilled; ~164KB scratch traffic/iter/CU matched the 2900cyc/iter exactly).
// __launch_bounds__(1024,4): one block/CU, 128-VGPR budget. Same DPP reduce
// and bit-identical arithmetic / selection semantics as round 6.
#define FPS_LOAD(J)                                                        \
  float X##J, Y##J, Z##J, md##J;                                           \
  {                                                                        \
    const int i = J * 1024 + t;                                            \
    X##J = P[i * 3 + 0]; Y##J = P[i * 3 + 1]; Z##J = P[i * 3 + 2];         \
    md##J = 1e10f;                                                         \
    pts4[i] = make_float4(X##J, Y##J, Z##J, 0.f);                          \
  }

#define FPS_STEP(J)                                                        \
  {                                                                        \
    const float dx = X##J - lx;                                            \
    const float dy = Y##J - ly;                                            \
    const float dz = Z##J - lz;                                            \
    const float d = dx * dx + dy * dy + dz * dz;                           \
    md##J = (d < md##J) ? d : md##J;                                       \
    bv = (md##J > bv) ? md##J : bv;                                        \
  }

#define FPS_RESCAN(J)                                                      \
  if (md##J == wv) best = (unsigned)(J * 1024 + t);

__global__ __launch_bounds__(1024, 4) void fps_kernel(const float* __restrict__ pos,
                                                      float* __restrict__ sp) {
#pragma clang fp contract(off)
  extern __shared__ float4 pts4[];  // 8192 * 16B = 128KB dynamic
  __shared__ float wval[2][16];
  __shared__ unsigned widx[2][16];
  const int b = blockIdx.x;
  const float* P = pos + (size_t)b * NPTS * 3;
  const int t = threadIdx.x;
  const int wave = t >> 6;
  const int lane = t & 63;
  FPS_LOAD(0) FPS_LOAD(1) FPS_LOAD(2) FPS_LOAD(3)
  FPS_LOAD(4) FPS_LOAD(5) FPS_LOAD(6) FPS_LOAD(7)
  float lx = P[0], ly = P[1], lz = P[2];
  __syncthreads();
  for (int it = 0; it < MS; ++it) {
    if (t == 0) {
      sp[((size_t)b * MS + it) * 3 + 0] = lx;
      sp[((size_t)b * MS + it) * 3 + 1] = ly;
      sp[((size_t)b * MS + it) * 3 + 2] = lz;
    }
    float bv = -1.0f;
    FPS_STEP(0) FPS_STEP(1) FPS_STEP(2) FPS_STEP(3)
    FPS_STEP(4) FPS_STEP(5) FPS_STEP(6) FPS_STEP(7)
    // wave max value (DPP) -> uniform via readlane 63
    const float wv = __int_as_float(
        __builtin_amdgcn_readlane(__float_as_int(dpp_wave_max_f32(bv)), 63));
    // tie threads resolve smallest flat idx (descending J -> smallest wins)
    unsigned best = 0xffffffffu;
    if (bv == wv) {
      FPS_RESCAN(7) FPS_RESCAN(6) FPS_RESCAN(5) FPS_RESCAN(4)
      FPS_RESCAN(3) FPS_RESCAN(2) FPS_RESCAN(1) FPS_RESCAN(0)
    }
    const unsigned wi =
        (unsigned)__builtin_amdgcn_readlane((int)dpp_wave_min_u32(best), 63);
    const int par = it & 1;
    if (lane == 0) { wval[par][wave] = wv; widx[par][wave] = wi; }
    __syncthreads();
    // block fold over 16 wave slots (DPP row reduce), then coord broadcast
    const float a = wval[par][lane & 15];
    const float M = __int_as_float(
        __builtin_amdgcn_readlane(__float_as_int(dpp_row_max_f32(a)), 15));
    const unsigned c2 = (a == M) ? widx[par][lane & 15] : 0xffffffffu;
    const unsigned idx =
        (unsigned)__builtin_amdgcn_readlane((int)dpp_row_min_u32(c2), 15);
    const float4 c = pts4[idx];
    lx = c.x; ly = c.y; lz = c.z;
  }
}

// ---------------------------------------------------------------- kNN top-64
// Tournament selection, candidates in registers, DPP reductions, ONE barrier
// per round. Selection order: min distance, tie -> smaller index == exactly
// lax.top_k's stable selection set (proven semantics from earlier rounds).
__global__ __launch_bounds__(256) void knn_kernel(const float* __restrict__ pos,
                                                  const float* __restrict__ xf,
                                                  const float* __restrict__ sp,
                                                  float* __restrict__ gf0,
                                                  float* __restrict__ sqsel) {
#pragma clang fp contract(off)
  __shared__ float sqv[NPTS];
  __shared__ float wval[2][4];
  __shared__ unsigned widx[2][4];
  __shared__ int sel_i[KNB];
  __shared__ float sel_v[KNB];
  const int bm = blockIdx.x;
  const int b = bm >> 7;
  const float* P = pos + (size_t)b * NPTS * 3;
  const float sx = sp[bm * 3 + 0], sy = sp[bm * 3 + 1], sz = sp[bm * 3 + 2];
  const float nsp = sx * sx + sy * sy + sz * sz;
  const int t = threadIdx.x;
  const int wave = t >> 6;
  const int lane = t & 63;
  for (int j = 0; j < 32; ++j) {
    const int i = j * 256 + t;
    const float qx = P[i * 3 + 0], qy = P[i * 3 + 1], qz = P[i * 3 + 2];
    const float npos = qx * qx + qy * qy + qz * qz;
    const float dt = sx * qx + sy * qy + sz * qz;
    float sq = (nsp + npos) - 2.0f * dt;  // matches ||a||^2+||b||^2-2ab order
    sq = fmaxf(sq, 0.0f);
    sqv[i] = sq;
  }
  __syncthreads();
  // per-thread candidate (value, idx) over its 32-element column, in registers
  float cv;
  unsigned ci;
  {
    unsigned long long k0 = ~0ULL;
    for (int j = 0; j < 32; ++j) {
      const int i = j * 256 + t;
      const unsigned long long key =
          ((unsigned long long)__float_as_uint(sqv[i]) << 32) | (unsigned)i;
      if (key < k0) k0 = key;
    }
    cv = __uint_as_float((unsigned)(k0 >> 32));
    ci = (unsigned)k0;
  }
  for (int round = 0; round < KNB; ++round) {
    // wave min (value), tie -> min idx
    const float wv = __int_as_float(
        __builtin_amdgcn_readlane(__float_as_int(dpp_wave_min_f32(cv)), 63));
    const unsigned sel = (cv == wv) ? ci : 0xffffffffu;
    const unsigned wi =
        (unsigned)__builtin_amdgcn_readlane((int)dpp_wave_min_u32(sel), 63);
    const int par = round & 1;
    if (lane == 0) { wval[par][wave] = wv; widx[par][wave] = wi; }
    __syncthreads();
    // block fold over 4 wave slots
    const float a = wval[par][lane & 3];
    const float M = __int_as_float(
        __builtin_amdgcn_readlane(__float_as_int(dpp_quad_min_f32(a)), 3));
    const unsigned c2 = (a == M) ? widx[par][lane & 3] : 0xffffffffu;
    const unsigned idx =
        (unsigned)__builtin_amdgcn_readlane((int)dpp_quad_min_u32(c2), 3);
    const int col = (int)(idx & 255u);
    if (t == col) {
      sel_i[round] = (int)idx;
      sel_v[round] = M;
      sqv[idx] = __uint_as_float(0x7f800000u);  // consumed (visible next round)
    }
    // winner's wave rescans the consumed column (consumed elem masked locally)
    if (wave == (col >> 6)) {
      float v = __uint_as_float(0x7f800000u);
      unsigned ii = 0xffffffffu;
      if (lane < 32) {
        const int i = lane * 256 + col;
        v = sqv[i];
        if (i == (int)idx) v = __uint_as_float(0x7f800000u);
        ii = (unsigned)i;
      }
      const float mv = __int_as_float(
          __builtin_amdgcn_readlane(__float_as_int(dpp_wave_min_f32(v)), 63));
      const unsigned s2 = (v == mv) ? ii : 0xffffffffu;
      const unsigned mi =
          (unsigned)__builtin_amdgcn_readlane((int)dpp_wave_min_u32(s2), 63);
      if (t == col) { cv = mv; ci = mi; }
    }
  }
  __syncthreads();
  if (t < KNB) {
    const int i = sel_i[t];
    const float* X = xf + (size_t)b * NPTS * 3;
    const size_t base = ((size_t)bm * KNB + t) * 6;
    gf0[base + 0] = P[i * 3 + 0] - sx;
    gf0[base + 1] = P[i * 3 + 1] - sy;
    gf0[base + 2] = P[i * 3 + 2] - sz;
    gf0[base + 3] = X[i * 3 + 0];
    gf0[base + 4] = X[i * 3 + 1];
    gf0[base + 5] = X[i * 3 + 2];
    sqsel[(size_t)bm * KNB + t] = sel_v[t];
  }
}

// ---------------------------------------------------------------- stage-0 conv chain
// One block per (b, sample) 64x6 tile. Recomputes the conv chain to the target
// depth each pass (BN needs global stats between layers; FLOPs are tiny).
// MODE 1: y1 stats   MODE 2: y2 stats   MODE 3: y3 stats (+ optional z2 dump)
// MODE 4: masked max -> x1 (fallback when ws too small for the z2 cache).
// Stats partials are written [channel][block] (coalesced for p_stats).
template <int MODE>
__global__ __launch_bounds__(256) void chain_kernel(
    const float* __restrict__ gf0,
    const float* __restrict__ W0, const float* __restrict__ B0,
    const float* __restrict__ W1, const float* __restrict__ B1,
    const float* __restrict__ W2, const float* __restrict__ B2,
    const float* __restrict__ sc1, const float* __restrict__ sh1,
    const float* __restrict__ sc2, const float* __restrict__ sh2,
    const float* __restrict__ sc3, const float* __restrict__ sh3,
    const float* __restrict__ sqsel,
    float* __restrict__ psum, float* __restrict__ psq, float* __restrict__ x1,
    float* __restrict__ z2out) {
  __shared__ float tA[64 * 65];  // +1 pad: kills stride-64 bank conflicts on row reads
  __shared__ float tB[64 * 65];
  __shared__ float wbuf[64 * 64];
  __shared__ float in6[64 * 8];
  __shared__ float sqs[64];
  const int blk = blockIdx.x;
  const int t = threadIdx.x;
  {
    const float* G = gf0 + (size_t)blk * 64 * 6;
    for (int i = t; i < 384; i += 256) in6[(i / 6) * 8 + (i % 6)] = G[i];
    for (int i = t; i < 384; i += 256) wbuf[i] = W0[i];
    if (MODE == 4 && t < 64) sqs[t] = sqsel[(size_t)blk * 64 + t];
  }
  __syncthreads();
  const int r = t >> 2;
  const int c0 = (t & 3) * 16;
  float acc[16];
  // L1: 6 -> 64
#pragma unroll
  for (int j = 0; j < 16; ++j) acc[j] = B0[c0 + j];
  for (int cin = 0; cin < 6; ++cin) {
    const float a = in6[r * 8 + cin];
#pragma unroll
    for (int j = 0; j < 16; ++j) acc[j] = fmaf(a, wbuf[cin * 64 + c0 + j], acc[j]);
  }
  if (MODE == 1) {
#pragma unroll
    for (int j = 0; j < 16; ++j) tA[r * 65 + c0 + j] = acc[j];
    __syncthreads();
    if (t < 64) {
      float s = 0.f, q = 0.f;
      for (int r2 = 0; r2 < 64; ++r2) { const float v = tA[r2 * 65 + t]; s += v; q += v * v; }
      psum[(size_t)t * NBLK + blk] = s;
      psq[(size_t)t * NBLK + blk] = q;
    }
    return;
  }
#pragma unroll
  for (int j = 0; j < 16; ++j) {
    const int c = c0 + j;
    tA[r * 65 + c] = fmaxf(fmaf(acc[j], sc1[c], sh1[c]), 0.f);
  }
  __syncthreads();
  for (int i = t; i < 4096; i += 256) wbuf[i] = W1[i];
  __syncthreads();
  // L2: 64 -> 64
#pragma unroll
  for (int j = 0; j < 16; ++j) acc[j] = B1[c0 + j];
  for (int cin = 0; cin < 64; ++cin) {
    const float a = tA[r * 65 + cin];
    const float4* w4 = reinterpret_cast<const float4*>(&wbuf[cin * 64 + c0]);
#pragma unroll
    for (int k = 0; k < 4; ++k) {
      const float4 w = w4[k];
      acc[k * 4 + 0] = fmaf(a, w.x, acc[k * 4 + 0]);
      acc[k * 4 + 1] = fmaf(a, w.y, acc[k * 4 + 1]);
      acc[k * 4 + 2] = fmaf(a, w.z, acc[k * 4 + 2]);
      acc[k * 4 + 3] = fmaf(a, w.w, acc[k * 4 + 3]);
    }
  }
  if (MODE == 2) {
#pragma unroll
    for (int j = 0; j < 16; ++j) tB[r * 65 + c0 + j] = acc[j];
    __syncthreads();
    if (t < 64) {
      float s = 0.f, q = 0.f;
      for (int r2 = 0; r2 < 64; ++r2) { const float v = tB[r2 * 65 + t]; s += v; q += v * v; }
      psum[(size_t)t * NBLK + blk] = s;
      psq[(size_t)t * NBLK + blk] = q;
    }
    return;
  }
#pragma unroll
  for (int j = 0; j < 16; ++j) {
    const int c = c0 + j;
    tB[r * 65 + c] = fmaxf(fmaf(acc[j], sc2[c], sh2[c]), 0.f);
  }
  // L3: 64 -> 128, processed in channel halves (wbuf holds 64x64 weight half)
  for (int hc = 0; hc < 2; ++hc) {
    __syncthreads();
    for (int i = t; i < 4096; i += 256) {
      const int cin = i >> 6, cc = i & 63;
      wbuf[i] = W2[cin * 128 + hc * 64 + cc];
    }
    if (MODE == 3 && hc == 0 && z2out != nullptr) {
      float* Zg = z2out + (size_t)blk * 4096;
      for (int i = t; i < 4096; i += 256) Zg[i] = tB[(i >> 6) * 65 + (i & 63)];
    }
    __syncthreads();
    float st_s = 0.f, st_q = 0.f, mx = -1e8f;
    for (int rh = 0; rh < 2; ++rh) {
      const int rr = rh * 32 + (t >> 3);
      const int cc0 = (t & 7) * 8;
      float a3[8];
#pragma unroll
      for (int j = 0; j < 8; ++j) a3[j] = B2[hc * 64 + cc0 + j];
      for (int cin = 0; cin < 64; ++cin) {
        const float a = tB[rr * 65 + cin];
        const float4* w4 = reinterpret_cast<const float4*>(&wbuf[cin * 64 + cc0]);
#pragma unroll
        for (int k = 0; k < 2; ++k) {
          const float4 w = w4[k];
          a3[k * 4 + 0] = fmaf(a, w.x, a3[k * 4 + 0]);
          a3[k * 4 + 1] = fmaf(a, w.y, a3[k * 4 + 1]);
          a3[k * 4 + 2] = fmaf(a, w.z, a3[k * 4 + 2]);
          a3[k * 4 + 3] = fmaf(a, w.w, a3[k * 4 + 3]);
        }
      }
      __syncthreads();
#pragma unroll
      for (int j = 0; j < 8; ++j) tA[(t >> 3) * 65 + cc0 + j] = a3[j];
      __syncthreads();
      if (t < 64) {
        if (MODE == 3) {
          for (int q2 = 0; q2 < 32; ++q2) { const float v = tA[q2 * 65 + t]; st_s += v; st_q += v * v; }
        } else {
          const float scv = sc3[hc * 64 + t], shv = sh3[hc * 64 + t];
          for (int q2 = 0; q2 < 32; ++q2) {
            const int kidx = rh * 32 + q2;
            const float y = tA[q2 * 65 + t];
            const float act = fmaxf(fmaf(y, scv, shv), 0.f);
            const float v = (sqs[kidx] <= 0.16f) ? act : -1e8f;
            mx = fmaxf(mx, v);
          }
        }
      }
      __syncthreads();
    }
    if (t < 64) {
      if (MODE == 3) {
        psum[(size_t)(hc * 64 + t) * NBLK + blk] = st_s;
        psq[(size_t)(hc * 64 + t) * NBLK + blk] = st_q;
      } else if (MODE == 4) {
        x1[(size_t)blk * 128 + hc * 64 + t] = mx;
      }
    }
  }
}

// Cached final pass: reads post-BN2 z2 (written by chain<3>), runs only
// L3 + BN3 + radius-masked max. Skips the L1+L2 recompute.
__global__ __launch_bounds__(256) void chain4c_kernel(
    const float* __restrict__ z2, const float* __restrict__ W2, const float* __restrict__ B2,
    const float* __restrict__ sc3, const float* __restrict__ sh3,
    const float* __restrict__ sqsel, float* __restrict__ x1) {
  __shared__ float tA[64 * 65];
  __shared__ float tB[64 * 65];
  __shared__ float wbuf[64 * 64];
  __shared__ float sqs[64];
  const int blk = blockIdx.x;
  const int t = threadIdx.x;
  const float* Zg = z2 + (size_t)blk * 4096;
  for (int i = t; i < 4096; i += 256) tB[(i >> 6) * 65 + (i & 63)] = Zg[i];
  if (t < 64) sqs[t] = sqsel[(size_t)blk * 64 + t];
  for (int hc = 0; hc < 2; ++hc) {
    __syncthreads();
    for (int i = t; i < 4096; i += 256) {
      const int cin = i >> 6, cc = i & 63;
      wbuf[i] = W2[cin * 128 + hc * 64 + cc];
    }
    __syncthreads();
    float mx = -1e8f;
    for (int rh = 0; rh < 2; ++rh) {
      const int rr = rh * 32 + (t >> 3);
      const int cc0 = (t & 7) * 8;
      float a3[8];
#pragma unroll
      for (int j = 0; j < 8; ++j) a3[j] = B2[hc * 64 + cc0 + j];
      for (int cin = 0; cin < 64; ++cin) {
        const float a = tB[rr * 65 + cin];
        const float4* w4 = reinterpret_cast<const float4*>(&wbuf[cin * 64 + cc0]);
#pragma unroll
        for (int k = 0; k < 2; ++k) {
          const float4 w = w4[k];
          a3[k * 4 + 0] = fmaf(a, w.x, a3[k * 4 + 0]);
          a3[k * 4 + 1] = fmaf(a, w.y, a3[k * 4 + 1]);
          a3[k * 4 + 2] = fmaf(a, w.z, a3[k * 4 + 2]);
          a3[k * 4 + 3] = fmaf(a, w.w, a3[k * 4 + 3]);
        }
      }
      __syncthreads();
#pragma unroll
      for (int j = 0; j < 8; ++j) tA[(t >> 3) * 65 + cc0 + j] = a3[j];
      __syncthreads();
      if (t < 64) {
        const float scv = sc3[hc * 64 + t], shv = sh3[hc * 64 + t];
        for (int q2 = 0; q2 < 32; ++q2) {
          const int kidx = rh * 32 + q2;
          const float y = tA[q2 * 65 + t];
          const float act = fmaxf(fmaf(y, scv, shv), 0.f);
          const float v = (sqs[kidx] <= 0.16f) ? act : -1e8f;
          mx = fmaxf(mx, v);
        }
      }
      __syncthreads();
    }
    if (t < 64) x1[(size_t)blk * 128 + hc * 64 + t] = mx;
  }
}

// Parallel deterministic stats reduce: one block per channel, coalesced reads,
// f64 LDS tree.
__global__ __launch_bounds__(256) void p_stats(const float* __restrict__ psum,
                                               const float* __restrict__ psq,
                                               float invN,
                                               const float* __restrict__ g,
                                               const float* __restrict__ be,
                                               float* __restrict__ sc,
                                               float* __restrict__ sh) {
  const int c = blockIdx.x;
  const int t = threadIdx.x;
  double s = 0.0, q = 0.0;
  for (int k = t; k < NBLK; k += 256) {
    s += (double)psum[(size_t)c * NBLK + k];
    q += (double)psq[(size_t)c * NBLK + k];
  }
  __shared__ double ss[256], qq[256];
  ss[t] = s;
  qq[t] = q;
  __syncthreads();
  for (int st = 128; st > 0; st >>= 1) {
    if (t < st) { ss[t] += ss[t + st]; qq[t] += qq[t + st]; }
    __syncthreads();
  }
  if (t == 0) {
    const double mean = ss[0] * (double)invN;
    double var = qq[0] * (double)invN - mean * mean;
    if (var < 0.0) var = 0.0;
    const float scl = (float)((double)g[c] / sqrt(var + 1e-5));
    sc[c] = scl;
    sh[c] = be[c] - (float)mean * scl;
  }
}

// ---------------------------------------------------------------- stage 1 (2048 rows)
__global__ __launch_bounds__(128) void s1_kernel(const float* __restrict__ sp,
                                                 const float* __restrict__ x1,
                                                 const float* __restrict__ W,
                                                 const float* __restrict__ bia,
                                                 float* __restrict__ y1) {
  __shared__ float row[132];
  const int rowid = blockIdx.x;
  const int t = threadIdx.x;
  if (t < 3) row[t] = sp[(size_t)rowid * 3 + t];
  row[3 + t] = x1[(size_t)rowid * 128 + t];
  __syncthreads();
  float acc = bia[t];
  for (int cin = 0; cin < 131; ++cin) acc = fmaf(row[cin], W[(size_t)cin * 128 + t], acc);
  y1[(size_t)rowid * 128 + t] = acc;
}

__global__ __launch_bounds__(128) void s2_kernel(const float* __restrict__ y1,
                                                 const float* __restrict__ sc, const float* __restrict__ sh,
                                                 const float* __restrict__ W, const float* __restrict__ bia,
                                                 float* __restrict__ y2) {
  __shared__ float row[128];
  const int rowid = blockIdx.x;
  const int t = threadIdx.x;
  row[t] = fmaxf(fmaf(y1[(size_t)rowid * 128 + t], sc[t], sh[t]), 0.f);
  __syncthreads();
  float acc = bia[t];
  for (int cin = 0; cin < 128; ++cin) acc = fmaf(row[cin], W[(size_t)cin * 128 + t], acc);
  y2[(size_t)rowid * 128 + t] = acc;
}

__global__ __launch_bounds__(256) void s3_kernel(const float* __restrict__ y2,
                                                 const float* __restrict__ sc, const float* __restrict__ sh,
                                                 const float* __restrict__ W, const float* __restrict__ bia,
                                                 float* __restrict__ y3) {
  __shared__ float row[128];
  const int rowid = blockIdx.x;
  const int t = threadIdx.x;
  if (t < 128) row[t] = fmaxf(fmaf(y2[(size_t)rowid * 128 + t], sc[t], sh[t]), 0.f);
  __syncthreads();
  for (int h = 0; h < 2; ++h) {
    const int c = h * 256 + t;
    float acc = bia[c];
    for (int cin = 0; cin < 128; ++cin) acc = fmaf(row[cin], W[(size_t)cin * 512 + c], acc);
    y3[(size_t)rowid * 512 + c] = acc;
  }
}

// Deterministic per-channel stats over rows (block per channel, tree reduce).
__global__ __launch_bounds__(256) void s_stats(const float* __restrict__ y, int C, int rows,
                                               const float* __restrict__ g, const float* __restrict__ be,
                                               float* __restrict__ sc, float* __restrict__ sh) {
  const int c = blockIdx.x;
  const int t = threadIdx.x;
  double s = 0.0, q = 0.0;
  for (int r2 = t; r2 < rows; r2 += 256) {
    const double v = (double)y[(size_t)r2 * C + c];
    s += v;
    q += v * v;
  }
  __shared__ double ss[256], qq[256];
  ss[t] = s;
  qq[t] = q;
  __syncthreads();
  for (int st = 128; st > 0; st >>= 1) {
    if (t < st) { ss[t] += ss[t + st]; qq[t] += qq[t + st]; }
    __syncthreads();
  }
  if (t == 0) {
    const double mean = ss[0] / rows;
    double var = qq[0] / rows - mean * mean;
    if (var < 0.0) var = 0.0;
    const float scl = (float)((double)g[c] / sqrt(var + 1e-5));
    sc[c] = scl;
    sh[c] = be[c] - (float)mean * scl;
  }
}

__global__ __launch_bounds__(256) void final_kernel(const float* __restrict__ y3,
                                                    const float* __restrict__ sc, const float* __restrict__ sh,
                                                    float* __restrict__ out) {
  const int gid = blockIdx.x * 256 + threadIdx.x;  // 8192 = 16 batches x 512 ch
  const int b = gid >> 9;
  const int c = gid & 511;
  const float scv = sc[c], shv = sh[c];
  float mx = -3.402823466e+38f;
  for (int m = 0; m < 128; ++m) {
    const float v = fmaxf(fmaf(y3[((size_t)(b * 128 + m)) * 512 + c], scv, shv), 0.f);
    mx = fmaxf(mx, v);
  }
  out[gid] = mx;
  if (gid < 48) out[8192 + gid] = 0.f;  // pos_out zeros
}

extern "C" void kernel_launch(void* const* d_in, const int* in_sizes, int n_in,
                              void* d_out, int out_size, void* d_ws, size_t ws_size,
                              hipStream_t stream) {
  const float* x    = (const float*)d_in[0];
  const float* pos  = (const float*)d_in[1];
  const float* W00  = (const float*)d_in[2];
  const float* b00  = (const float*)d_in[3];
  const float* g00  = (const float*)d_in[4];
  const float* be00 = (const float*)d_in[5];
  const float* W01  = (const float*)d_in[6];
  const float* b01  = (const float*)d_in[7];
  const float* g01  = (const float*)d_in[8];
  const float* be01 = (const float*)d_in[9];
  const float* W02  = (const float*)d_in[10];
  const float* b02  = (const float*)d_in[11];
  const float* g02  = (const float*)d_in[12];
  const float* be02 = (const float*)d_in[13];
  const float* W10  = (const float*)d_in[14];
  const float* b10  = (const float*)d_in[15];
  const float* g10  = (const float*)d_in[16];
  const float* be10 = (const float*)d_in[17];
  const float* W11  = (const float*)d_in[18];
  const float* b11  = (const float*)d_in[19];
  const float* g11  = (const float*)d_in[20];
  const float* be11 = (const float*)d_in[21];
  const float* W12  = (const float*)d_in[22];
  const float* b12  = (const float*)d_in[23];
  const float* g12  = (const float*)d_in[24];
  const float* be12 = (const float*)d_in[25];

  float* w = (float*)d_ws;
  float* sp    = w;                  // 16*128*3          = 6144
  float* gf0   = sp + 6144;          // 16*128*64*6       = 786432
  float* sqsel = gf0 + 786432;       // 16*128*64         = 131072
  float* x1    = sqsel + 131072;     // 16*128*128        = 262144
  float* parts = x1 + 262144;        // 128*2048*2        = 524288
  float* psum  = parts;              // [c][blk]
  float* psq   = parts + 128 * NBLK; // [c][blk]
  float* st    = parts + 524288;     // stats area        = 2048
  float* sc1 = st + 0,    *sh1 = st + 64;
  float* sc2 = st + 128,  *sh2 = st + 192;
  float* sc3 = st + 256,  *sh3 = st + 384;
  float* t1sc = st + 512, *t1sh = st + 640;
  float* t2sc = st + 768, *t2sh = st + 896;
  float* t3sc = st + 1024, *t3sh = st + 1536;
  float* y1s = st + 2048;            // 2048*128 = 262144
  float* y2s = y1s + 262144;         // 2048*128 = 262144
  float* y3s = y2s + 262144;         // 2048*512 = 1048576
  const size_t Z2OFF = 3284992;      // end of the base layout (floats)
  const size_t Z2LEN = (size_t)NBLK * 4096;  // 8.39M floats = 33.5MB
  const bool cache_ok = ws_size >= (Z2OFF + Z2LEN) * sizeof(float);
  float* z2 = cache_ok ? (w + Z2OFF) : nullptr;

  fps_kernel<<<BATCH, 1024, NPTS * sizeof(float4), stream>>>(pos, sp);
  knn_kernel<<<BATCH * MS, 256, 0, stream>>>(pos, x, sp, gf0, sqsel);

  const float invN0 = 1.0f / (float)(NBLK * KNB);  // 1/131072
  chain_kernel<1><<<NBLK, 256, 0, stream>>>(gf0, W00, b00, W01, b01, W02, b02,
                                            sc1, sh1, sc2, sh2, sc3, sh3, sqsel, psum, psq, x1, nullptr);
  p_stats<<<64, 256, 0, stream>>>(psum, psq, invN0, g00, be00, sc1, sh1);
  chain_kernel<2><<<NBLK, 256, 0, stream>>>(gf0, W00, b00, W01, b01, W02, b02,
                                            sc1, sh1, sc2, sh2, sc3, sh3, sqsel, psum, psq, x1, nullptr);
  p_stats<<<64, 256, 0, stream>>>(psum, psq, invN0, g01, be01, sc2, sh2);
  chain_kernel<3><<<NBLK, 256, 0, stream>>>(gf0, W00, b00, W01, b01, W02, b02,
                                            sc1, sh1, sc2, sh2, sc3, sh3, sqsel, psum, psq, x1, z2);
  p_stats<<<128, 256, 0, stream>>>(psum, psq, invN0, g02, be02, sc3, sh3);
  if (cache_ok) {
    chain4c_kernel<<<NBLK, 256, 0, stream>>>(z2, W02, b02, sc3, sh3, sqsel, x1);
  } else {
    chain_kernel<4><<<NBLK, 256, 0, stream>>>(gf0, W00, b00, W01, b01, W02, b02,
                                              sc1, sh1, sc2, sh2, sc3, sh3, sqsel, psum, psq, x1, nullptr);
  }

  s1_kernel<<<NBLK, 128, 0, stream>>>(sp, x1, W10, b10, y1s);
  s_stats<<<128, 256, 0, stream>>>(y1s, 128, NBLK, g10, be10, t1sc, t1sh);
  s2_kernel<<<NBLK, 128, 0, stream>>>(y1s, t1sc, t1sh, W11, b11, y2s);
  s_stats<<<128, 256, 0, stream>>>(y2s, 128, NBLK, g11, be11, t2sc, t2sh);
  s3_kernel<<<NBLK, 256, 0, stream>>>(y2s, t2sc, t2sh, W12, b12, y3s);
  s_stats<<<512, 256, 0, stream>>>(y3s, 512, NBLK, g12, be12, t3sc, t3sh);
  final_kernel<<<32, 256, 0, stream>>>(y3s, t3sc, t3sh, (float*)d_out);
}